// Round 6
// baseline (680.112 us; speedup 1.0000x reference)
//
#include <hip/hip_runtime.h>

#define NN   50000
#define IN_F 128
#define HF   256
#define COUT 64
#define MLPH 128
#define EG   600000
#define EK   800000
#define BN_EPS 1e-5f

typedef __attribute__((ext_vector_type(8))) short short8;
typedef __attribute__((ext_vector_type(8))) unsigned short ushort8;
typedef __attribute__((ext_vector_type(4))) float f32x4;

__device__ __forceinline__ unsigned short f2bf(float f) {
  union { float f; unsigned int u; } v; v.f = f;
  unsigned int r = v.u + 0x7FFFu + ((v.u >> 16) & 1u);
  return (unsigned short)(r >> 16);
}
__device__ __forceinline__ float bf2f(unsigned short s) {
  union { unsigned int u; float f; } v; v.u = ((unsigned int)s) << 16;
  return v.f;
}

struct WDesc { const float* src; int rows; int cshift; int kofs; int ldk; int dofs; };
struct WPack { WDesc d[12]; };

// ---------------- prep: feat->bf16, weight transpose, degree counts ----------------
__global__ __launch_bounds__(256) void prep_kernel(const float* __restrict__ feat,
                                                   unsigned short* __restrict__ featbf,
                                                   WPack p, unsigned short* __restrict__ wts,
                                                   const int* __restrict__ g_dst,
                                                   const int* __restrict__ k_dst,
                                                   int* __restrict__ cnt_g,
                                                   int* __restrict__ cnt_k) {
  int b = blockIdx.x;
  if (b < 3126) {
    int i = b * 256 + threadIdx.x;
    if (i < NN * IN_F / 8) {
      float4 a = *reinterpret_cast<const float4*>(&feat[i * 8]);
      float4 c = *reinterpret_cast<const float4*>(&feat[i * 8 + 4]);
      ushort8 o;
      o[0] = f2bf(a.x); o[1] = f2bf(a.y); o[2] = f2bf(a.z); o[3] = f2bf(a.w);
      o[4] = f2bf(c.x); o[5] = f2bf(c.y); o[6] = f2bf(c.z); o[7] = f2bf(c.w);
      *reinterpret_cast<ushort8*>(&featbf[i * 8]) = o;
    }
  } else if (b < 3510) {
    int wb = b - 3126;
    WDesc w = p.d[wb >> 5];
    int xb = wb & 31;
    int total = w.rows << w.cshift;
    int cmask = (1 << w.cshift) - 1;
    for (int idx = xb * 256 + threadIdx.x; idx < total; idx += 32 * 256) {
      int r = idx >> w.cshift, c = idx & cmask;
      wts[w.dofs + (size_t)c * w.ldk + w.kofs + r] = f2bf(w.src[idx]);
    }
  } else {
    int e = (b - 3510) * 256 + threadIdx.x;
    if (e < EG) atomicAdd(&cnt_g[g_dst[e]], 1);
    else if (e < EG + EK) atomicAdd(&cnt_k[k_dst[e - EG]], 1);
  }
}

// ---------------- parallel scans for both graphs ----------------
__global__ __launch_bounds__(256) void scan_partial2(const int* __restrict__ cnt_g,
                                                     const int* __restrict__ cnt_k,
                                                     int* __restrict__ part, int n) {
  const int* cnt = blockIdx.y ? cnt_k : cnt_g;
  int* pp = part + blockIdx.y * 256;
  int i = blockIdx.x * 256 + threadIdx.x;
  int v = (i < n) ? cnt[i] : 0;
  __shared__ int ws[4];
  int lane = threadIdx.x & 63, wid = threadIdx.x >> 6;
  int x = v;
#pragma unroll
  for (int d = 1; d < 64; d <<= 1) { int y = __shfl_up(x, d, 64); if (lane >= d) x += y; }
  if (lane == 63) ws[wid] = x;
  __syncthreads();
  if (threadIdx.x == 0) pp[blockIdx.x] = ws[0] + ws[1] + ws[2] + ws[3];
}

__global__ __launch_bounds__(256) void scan_block2(int* __restrict__ part, int np) {
  int* pp = part + blockIdx.x * 256;
  __shared__ int ws[4];
  int tid = threadIdx.x, lane = tid & 63, wid = tid >> 6;
  int v = (tid < np) ? pp[tid] : 0;
  int x = v;
#pragma unroll
  for (int d = 1; d < 64; d <<= 1) { int y = __shfl_up(x, d, 64); if (lane >= d) x += y; }
  if (lane == 63) ws[wid] = x;
  __syncthreads();
  int add = 0;
#pragma unroll
  for (int k = 0; k < 4; ++k) if (k < wid) add += ws[k];
  if (tid < np) pp[tid] = x - v + add;
}

__global__ __launch_bounds__(256) void scan_final2(const int* __restrict__ cnt_g,
                                                   const int* __restrict__ cnt_k,
                                                   const int* __restrict__ part,
                                                   int* __restrict__ off_g,
                                                   int* __restrict__ off_k,
                                                   float* __restrict__ invg,
                                                   float* __restrict__ invk, int n) {
  const int* cnt = blockIdx.y ? cnt_k : cnt_g;
  const int* pp = part + blockIdx.y * 256;
  int* off = blockIdx.y ? off_k : off_g;
  float* inv = blockIdx.y ? invk : invg;
  int total = blockIdx.y ? EK : EG;
  int i = blockIdx.x * 256 + threadIdx.x;
  int v = (i < n) ? cnt[i] : 0;
  __shared__ int ws[4];
  int lane = threadIdx.x & 63, wid = threadIdx.x >> 6;
  int x = v;
#pragma unroll
  for (int d = 1; d < 64; d <<= 1) { int y = __shfl_up(x, d, 64); if (lane >= d) x += y; }
  if (lane == 63) ws[wid] = x;
  __syncthreads();
  int add = pp[blockIdx.x];
#pragma unroll
  for (int k = 0; k < 4; ++k) if (k < wid) add += ws[k];
  if (i < n) {
    off[i] = x - v + add;
    inv[i] = 1.0f / fmaxf((float)v, 1.0f);
  }
  if (i == 0) off[n] = total;
}

__global__ __launch_bounds__(256) void fill2(const int* __restrict__ g_src,
                                             const int* __restrict__ g_dst,
                                             const int* __restrict__ k_src,
                                             const int* __restrict__ k_dst,
                                             const int* __restrict__ off_g,
                                             const int* __restrict__ off_k,
                                             int* __restrict__ cur_g, int* __restrict__ cur_k,
                                             int* __restrict__ esrc_g,
                                             int* __restrict__ esrc_k) {
  int e = blockIdx.x * 256 + threadIdx.x;
  if (e < EG) {
    int d = g_dst[e];
    int pz = atomicAdd(&cur_g[d], 1);
    esrc_g[off_g[d] + pz] = g_src[e];
  } else if (e < EG + EK) {
    int e2 = e - EG;
    int d = k_dst[e2];
    int pz = atomicAdd(&cur_k[d], 1);
    esrc_k[off_k[d] + pz] = k_src[e2];
  }
}

// ---------------- CSR mean-aggregation body (bf16 in/out) ----------------
template <int DLOG2>
__device__ __forceinline__ void agg_body(int bid, const unsigned short* __restrict__ h,
                                         const int* __restrict__ off,
                                         const int* __restrict__ esrc,
                                         const float* __restrict__ inv,
                                         unsigned short* __restrict__ out) {
  constexpr int TPN = (1 << DLOG2) / 8;
  constexpr int NPB = 256 / TPN;
  int node = bid * NPB + ((int)threadIdx.x / TPN);
  int lane = threadIdx.x & (TPN - 1);
  if (node >= NN) return;
  int s = off[node], e = off[node + 1];
  float acc[8] = {0.f, 0.f, 0.f, 0.f, 0.f, 0.f, 0.f, 0.f};
  int j = s;
  for (; j + 3 < e; j += 4) {
    int s0 = esrc[j], s1 = esrc[j + 1], s2 = esrc[j + 2], s3 = esrc[j + 3];
    ushort8 v0 = *reinterpret_cast<const ushort8*>(&h[((size_t)s0 << DLOG2) + lane * 8]);
    ushort8 v1 = *reinterpret_cast<const ushort8*>(&h[((size_t)s1 << DLOG2) + lane * 8]);
    ushort8 v2 = *reinterpret_cast<const ushort8*>(&h[((size_t)s2 << DLOG2) + lane * 8]);
    ushort8 v3 = *reinterpret_cast<const ushort8*>(&h[((size_t)s3 << DLOG2) + lane * 8]);
#pragma unroll
    for (int i = 0; i < 8; ++i) acc[i] += bf2f(v0[i]);
#pragma unroll
    for (int i = 0; i < 8; ++i) acc[i] += bf2f(v1[i]);
#pragma unroll
    for (int i = 0; i < 8; ++i) acc[i] += bf2f(v2[i]);
#pragma unroll
    for (int i = 0; i < 8; ++i) acc[i] += bf2f(v3[i]);
  }
  for (; j < e; ++j) {
    int s0 = esrc[j];
    ushort8 v0 = *reinterpret_cast<const ushort8*>(&h[((size_t)s0 << DLOG2) + lane * 8]);
#pragma unroll
    for (int i = 0; i < 8; ++i) acc[i] += bf2f(v0[i]);
  }
  float sc = inv[node];
  ushort8 o;
#pragma unroll
  for (int i = 0; i < 8; ++i) o[i] = f2bf(acc[i] * sc);
  *reinterpret_cast<ushort8*>(&out[((size_t)node << DLOG2) + lane * 8]) = o;
}

template <int DLOG2>
__global__ __launch_bounds__(256) void agg_kernel(const unsigned short* __restrict__ h,
                                                  const int* __restrict__ off,
                                                  const int* __restrict__ esrc,
                                                  const float* __restrict__ inv,
                                                  unsigned short* __restrict__ out) {
  agg_body<DLOG2>(blockIdx.x, h, off, esrc, inv, out);
}

// ---------------- MFMA GEMM body, BM=128 x BN=64, BK=64, 4 waves ----------------
template <int K1, int K2, bool RELU, bool OUT_BF16, bool ACCUM>
__device__ __forceinline__ void gemm_body(
    int bx, int by, const unsigned short* __restrict__ A1,
    const unsigned short* __restrict__ A2, const unsigned short* __restrict__ Bt,
    int ldb, int kofsB, const float* __restrict__ bias, void* __restrict__ outv,
    int ldo, int nrows, char* smem) {
  constexpr int KTOT = K1 + K2;
  constexpr int KT = KTOT / 64;
  constexpr int LDT = 72;
  constexpr int LDC = 68;
  unsigned short* As = (unsigned short*)smem;  // [128][LDT]
  unsigned short* Bs = As + 128 * LDT;         // [64][LDT]
  float* Co = (float*)smem;                    // [128][LDC] epilogue

  const int t = threadIdx.x;
  const int lane = t & 63;
  const int w = t >> 6;
  const int wm = w * 32;
  const int row0 = by * 128;
  const int n0 = bx * 64;

  const int arow = t >> 1, akb = (t & 1) * 32;
  const int brow = t >> 2, bkb = (t & 3) * 16;
  int rg = row0 + arow;
  if (rg >= nrows) rg = nrows - 1;

  f32x4 acc[2][4] = {};

  for (int kt = 0; kt < KT; ++kt) {
    const int kbase = kt * 64;
    const unsigned short* ab = (kbase < K1)
        ? (A1 + (size_t)rg * K1 + kbase + akb)
        : (A2 + (size_t)rg * K2 + (kbase - K1) + akb);
#pragma unroll
    for (int c = 0; c < 4; ++c) {
      int4 p = *reinterpret_cast<const int4*>(ab + c * 8);
      *reinterpret_cast<int4*>(&As[arow * LDT + akb + c * 8]) = p;
    }
    {
      const unsigned short* bb = Bt + (size_t)(n0 + brow) * ldb + kofsB + kbase + bkb;
      int4 p0 = *reinterpret_cast<const int4*>(bb);
      int4 p1 = *reinterpret_cast<const int4*>(bb + 8);
      *reinterpret_cast<int4*>(&Bs[brow * LDT + bkb]) = p0;
      *reinterpret_cast<int4*>(&Bs[brow * LDT + bkb + 8]) = p1;
    }
    __syncthreads();
#pragma unroll
    for (int kk = 0; kk < 2; ++kk) {
      const int ko = kk * 32 + (lane >> 4) * 8;
      short8 a0 = *reinterpret_cast<const short8*>(&As[(wm + (lane & 15)) * LDT + ko]);
      short8 a1 = *reinterpret_cast<const short8*>(&As[(wm + 16 + (lane & 15)) * LDT + ko]);
      short8 b0 = *reinterpret_cast<const short8*>(&Bs[((lane & 15)) * LDT + ko]);
      short8 b1 = *reinterpret_cast<const short8*>(&Bs[(16 + (lane & 15)) * LDT + ko]);
      short8 b2 = *reinterpret_cast<const short8*>(&Bs[(32 + (lane & 15)) * LDT + ko]);
      short8 b3 = *reinterpret_cast<const short8*>(&Bs[(48 + (lane & 15)) * LDT + ko]);
      acc[0][0] = __builtin_amdgcn_mfma_f32_16x16x32_bf16(a0, b0, acc[0][0], 0, 0, 0);
      acc[0][1] = __builtin_amdgcn_mfma_f32_16x16x32_bf16(a0, b1, acc[0][1], 0, 0, 0);
      acc[0][2] = __builtin_amdgcn_mfma_f32_16x16x32_bf16(a0, b2, acc[0][2], 0, 0, 0);
      acc[0][3] = __builtin_amdgcn_mfma_f32_16x16x32_bf16(a0, b3, acc[0][3], 0, 0, 0);
      acc[1][0] = __builtin_amdgcn_mfma_f32_16x16x32_bf16(a1, b0, acc[1][0], 0, 0, 0);
      acc[1][1] = __builtin_amdgcn_mfma_f32_16x16x32_bf16(a1, b1, acc[1][1], 0, 0, 0);
      acc[1][2] = __builtin_amdgcn_mfma_f32_16x16x32_bf16(a1, b2, acc[1][2], 0, 0, 0);
      acc[1][3] = __builtin_amdgcn_mfma_f32_16x16x32_bf16(a1, b3, acc[1][3], 0, 0, 0);
    }
    __syncthreads();
  }

#pragma unroll
  for (int mi = 0; mi < 2; ++mi)
#pragma unroll
    for (int ni = 0; ni < 4; ++ni) {
      int col = ni * 16 + (lane & 15);
      int rowb = wm + mi * 16 + (lane >> 4) * 4;
#pragma unroll
      for (int j = 0; j < 4; ++j) Co[(rowb + j) * LDC + col] = acc[mi][ni][j];
    }
  __syncthreads();
  {
    const int sr = t >> 1, cb = (t & 1) * 32;
    int r = row0 + sr;
    if (r < nrows) {
      float v[32];
#pragma unroll
      for (int i = 0; i < 32; ++i) {
        v[i] = Co[sr * LDC + cb + i] + (bias ? bias[n0 + cb + i] : 0.f);
        if (RELU) v[i] = fmaxf(v[i], 0.f);
      }
      if (OUT_BF16) {
        unsigned short* dst = (unsigned short*)outv + (size_t)r * ldo + n0 + cb;
#pragma unroll
        for (int q = 0; q < 4; ++q) {
          ushort8 o;
#pragma unroll
          for (int i = 0; i < 8; ++i) o[i] = f2bf(v[q * 8 + i]);
          *reinterpret_cast<ushort8*>(dst + q * 8) = o;
        }
      } else {
        float* dst = (float*)outv + (size_t)r * ldo + n0 + cb;
#pragma unroll
        for (int q = 0; q < 8; ++q) {
          float4 o = make_float4(v[4 * q], v[4 * q + 1], v[4 * q + 2], v[4 * q + 3]);
          if (ACCUM) {
            float4 d = *reinterpret_cast<const float4*>(dst + 4 * q);
            o.x += d.x; o.y += d.y; o.z += d.z; o.w += d.w;
          }
          *reinterpret_cast<float4*>(dst + 4 * q) = o;
        }
      }
    }
  }
}

// ---------------- fused aggregation + GEMM (Bresenham block interleave) ----------------
template <int DLOG2, int K1, int K2, bool RELU>
__global__ __launch_bounds__(256) void fused_agg_gemm(
    const unsigned short* __restrict__ hA, const int* __restrict__ aoff,
    const int* __restrict__ aesrc, const float* __restrict__ ainv,
    unsigned short* __restrict__ aout, int nAgg,
    const unsigned short* __restrict__ A1, const unsigned short* __restrict__ A2,
    const unsigned short* __restrict__ Bt, const float* __restrict__ bias,
    unsigned short* __restrict__ gout, int ldo, int nGemm, int gx) {
  __shared__ char smem[34816];
  long long bid = blockIdx.x;
  long long tot = nAgg + nGemm;
  int before = (int)((bid * nAgg) / tot);
  int after = (int)(((bid + 1) * nAgg) / tot);
  if (after > before) {
    agg_body<DLOG2>(before, hA, aoff, aesrc, ainv, aout);
  } else {
    int gid = (int)(bid - before);
    gemm_body<K1, K2, RELU, true, false>(gid % gx, gid / gx, A1, A2, Bt, K1 + K2, 0,
                                         bias, gout, ldo, NN, smem);
  }
}

// ---------------- S6: gemm_l2 || head-global ----------------
__global__ __launch_bounds__(256) void fused_gemm2_s6(
    const unsigned short* __restrict__ A1a, const unsigned short* __restrict__ A2a,
    const unsigned short* __restrict__ Bta, const float* __restrict__ biasa,
    unsigned short* __restrict__ outa,
    const unsigned short* __restrict__ A1b, const unsigned short* __restrict__ Btb,
    const float* __restrict__ biasb, float* __restrict__ outb, int nA) {
  __shared__ char smem[34816];
  int bid = blockIdx.x;
  if (bid < nA) {
    gemm_body<256, 256, false, true, false>(bid & 3, bid >> 2, A1a, A2a, Bta, 512, 0,
                                            biasa, outa, HF, NN, smem);
  } else {
    int b = bid - nA;
    gemm_body<256, 0, false, false, false>(b & 1, b >> 1, A1b, nullptr, Btb, 512, 256,
                                           biasb, outb, MLPH, NN, smem);
  }
}

// ---------------- S7: head-local, accumulate into xf32 ----------------
__global__ __launch_bounds__(256) void gemm_head_local(const unsigned short* __restrict__ A1,
                                                       const unsigned short* __restrict__ Bt,
                                                       float* __restrict__ outv) {
  __shared__ char smem[34816];
  gemm_body<256, 0, false, false, true>(blockIdx.x & 1, blockIdx.x >> 1, A1, nullptr, Bt,
                                        512, 0, nullptr, outv, MLPH, NN, smem);
}

// ---------------- BN ----------------
__global__ __launch_bounds__(256) void bn_stats_kernel(const float* __restrict__ x,
                                                       float* __restrict__ sums,
                                                       float* __restrict__ sumsq) {
  int c = threadIdx.x & 127;
  int rbase = (blockIdx.x * 256 + threadIdx.x) >> 7;
  int stride = (gridDim.x * 256) >> 7;
  float s = 0.f, s2 = 0.f;
  for (int r = rbase; r < NN; r += stride) {
    float v = x[(size_t)r * 128 + c];
    s += v;
    s2 += v * v;
  }
  __shared__ float ls[256], ls2[256];
  ls[threadIdx.x] = s;
  ls2[threadIdx.x] = s2;
  __syncthreads();
  if (threadIdx.x < 128) {
    s = ls[threadIdx.x] + ls[threadIdx.x + 128];
    s2 = ls2[threadIdx.x] + ls2[threadIdx.x + 128];
    atomicAdd(&sums[c], s);
    atomicAdd(&sumsq[c], s2);
  }
}

__global__ __launch_bounds__(128) void bn_finalize_kernel(float* __restrict__ stats,
                                                          const float* __restrict__ gamma,
                                                          const float* __restrict__ beta) {
  int c = threadIdx.x;
  float mu = stats[c] * (1.0f / NN);
  float var = stats[128 + c] * (1.0f / NN) - mu * mu;
  var = fmaxf(var, 0.f);
  float sc = gamma[c] * rsqrtf(var + BN_EPS);
  stats[256 + c] = sc;
  stats[384 + c] = beta[c] - mu * sc;
}

// ---------------- final head GEMM with fused BN+ReLU on A-load (64x64) ----------------
template <int K1, bool RELU>
__global__ __launch_bounds__(256) void gemm_mfma_bn(
    const float* __restrict__ A1v, const unsigned short* __restrict__ Bt,
    const float* __restrict__ bias, const float* __restrict__ bnscale,
    const float* __restrict__ bnshift, float* __restrict__ outv, int ldo, int nrows) {
  constexpr int KT = K1 / 64;
  constexpr int LDT = 72;
  __shared__ char smem[2 * 64 * LDT * 2];
  unsigned short* As = (unsigned short*)smem;
  unsigned short* Bs = As + 64 * LDT;
  float* Co = (float*)smem;
  constexpr int LDC = 68;

  const int t = threadIdx.x;
  const int lane = t & 63;
  const int w = t >> 6;
  const int wm = (w & 1) * 32, wn = (w >> 1) * 32;
  const int row0 = blockIdx.y * 64;
  const int n0 = blockIdx.x * 64;

  const int sr = t >> 2;
  const int skc = (t & 3) * 16;
  int rg = row0 + sr;
  if (rg >= nrows) rg = nrows - 1;

  f32x4 acc[2][2] = {};

  for (int kt = 0; kt < KT; ++kt) {
    const int kbase = kt * 64;
    {
      const float* xb = A1v + (size_t)rg * K1 + kbase + skc;
      ushort8 o0, o1;
#pragma unroll
      for (int i = 0; i < 8; ++i) {
        float v = xb[i] * bnscale[kbase + skc + i] + bnshift[kbase + skc + i];
        o0[i] = f2bf(fmaxf(v, 0.f));
      }
#pragma unroll
      for (int i = 0; i < 8; ++i) {
        float v = xb[8 + i] * bnscale[kbase + skc + 8 + i] + bnshift[kbase + skc + 8 + i];
        o1[i] = f2bf(fmaxf(v, 0.f));
      }
      *reinterpret_cast<ushort8*>(&As[sr * LDT + skc]) = o0;
      *reinterpret_cast<ushort8*>(&As[sr * LDT + skc + 8]) = o1;
    }
    {
      const unsigned short* bb = Bt + (size_t)(n0 + sr) * K1 + kbase + skc;
      int4 p0 = *reinterpret_cast<const int4*>(bb);
      int4 p1 = *reinterpret_cast<const int4*>(bb + 8);
      *reinterpret_cast<int4*>(&Bs[sr * LDT + skc]) = p0;
      *reinterpret_cast<int4*>(&Bs[sr * LDT + skc + 8]) = p1;
    }
    __syncthreads();
#pragma unroll
    for (int kk = 0; kk < 2; ++kk) {
      const int ko = kk * 32 + (lane >> 4) * 8;
      short8 a0 = *reinterpret_cast<const short8*>(&As[(wm + (lane & 15)) * LDT + ko]);
      short8 a1 = *reinterpret_cast<const short8*>(&As[(wm + 16 + (lane & 15)) * LDT + ko]);
      short8 b0 = *reinterpret_cast<const short8*>(&Bs[(wn + (lane & 15)) * LDT + ko]);
      short8 b1 = *reinterpret_cast<const short8*>(&Bs[(wn + 16 + (lane & 15)) * LDT + ko]);
      acc[0][0] = __builtin_amdgcn_mfma_f32_16x16x32_bf16(a0, b0, acc[0][0], 0, 0, 0);
      acc[0][1] = __builtin_amdgcn_mfma_f32_16x16x32_bf16(a0, b1, acc[0][1], 0, 0, 0);
      acc[1][0] = __builtin_amdgcn_mfma_f32_16x16x32_bf16(a1, b0, acc[1][0], 0, 0, 0);
      acc[1][1] = __builtin_amdgcn_mfma_f32_16x16x32_bf16(a1, b1, acc[1][1], 0, 0, 0);
    }
    __syncthreads();
  }

#pragma unroll
  for (int mi = 0; mi < 2; ++mi)
#pragma unroll
    for (int ni = 0; ni < 2; ++ni) {
      int col = wn + ni * 16 + (lane & 15);
      int rowb = wm + mi * 16 + (lane >> 4) * 4;
#pragma unroll
      for (int j = 0; j < 4; ++j) Co[(rowb + j) * LDC + col] = acc[mi][ni][j];
    }
  __syncthreads();
  {
    int r = row0 + sr;
    if (r < nrows) {
      float v[16];
#pragma unroll
      for (int i = 0; i < 16; ++i) {
        v[i] = Co[sr * LDC + skc + i] + bias[n0 + skc + i];
        if (RELU) v[i] = fmaxf(v[i], 0.f);
      }
      float* dst = outv + (size_t)r * ldo + n0 + skc;
#pragma unroll
      for (int i = 0; i < 4; ++i) {
        float4 o = make_float4(v[4 * i], v[4 * i + 1], v[4 * i + 2], v[4 * i + 3]);
        *reinterpret_cast<float4*>(dst + 4 * i) = o;
      }
    }
  }
}

// ---------------- launch ----------------
extern "C" void kernel_launch(void* const* d_in, const int* in_sizes, int n_in,
                              void* d_out, int out_size, void* d_ws, size_t ws_size,
                              hipStream_t stream) {
  const float* feat = (const float*)d_in[0];
  const int* g_src = (const int*)d_in[1];
  const int* g_dst = (const int*)d_in[2];
  const int* k_src = (const int*)d_in[3];
  const int* k_dst = (const int*)d_in[4];
  const float* lb_0 = (const float*)d_in[7];
  const float* lb_1 = (const float*)d_in[10];
  const float* lb_2 = (const float*)d_in[13];
  const float* gb_0 = (const float*)d_in[16];
  const float* gb_1 = (const float*)d_in[19];
  const float* mlp_b1 = (const float*)d_in[21];
  const float* bn_gamma = (const float*)d_in[22];
  const float* bn_beta = (const float*)d_in[23];
  const float* mlp_b2 = (const float*)d_in[25];
  float* out = (float*)d_out;

  // workspace layout (16B-aligned sections)
  float* xf32 = (float*)d_ws;                         // N*128 f32
  int* cnt_g = (int*)(xf32 + (size_t)NN * 128);       // N
  int* cnt_k = cnt_g + NN;                            // N
  int* cur_g = cnt_k + NN;                            // N
  int* cur_k = cur_g + NN;                            // N
  float* stats = (float*)(cur_k + NN);                // 512 (zeroed with cnt/cur)
  float* invg = stats + 512;                          // N
  float* invk = invg + NN;                            // N
  int* off_g = (int*)(invk + NN);                     // N+4 (padded for alignment)
  int* off_k = off_g + NN + 4;                        // N+4
  int* part = off_k + NN + 4;                         // 512
  int* esrc_g = part + 512;                           // EG
  int* esrc_k = esrc_g + EG;                          // EK
  unsigned short* featbf = (unsigned short*)(esrc_k + EK);  // N*128
  unsigned short* wts = featbf + (size_t)NN * IN_F;         // 598016
  unsigned short* bufP = wts + 598016;                // N*256 (local h0; later global_emb)
  unsigned short* bufQ = bufP + (size_t)NN * HF;      // N*256 (global h0; later local_emb)
  unsigned short* bufR = bufQ + (size_t)NN * HF;      // N*256 (local h1)
  unsigned short* aggG = bufR + (size_t)NN * HF;      // N*256
  unsigned short* aggK = aggG + (size_t)NN * HF;      // N*256

  const int wL0 = 0, wL1 = 65536, wL2 = 196608, wG0 = 327680, wG1 = 393216,
            wH1 = 524288, wH2 = 589824;

  dim3 blk(256);
  const int NB = (NN + 255) / 256;  // 196
  const int GX = 4, NG_H = 4 * ((NN + 127) / 128);   // 1564 blocks for 256-col GEMM
  const int NG_M = 2 * ((NN + 127) / 128);           // 782 for 128-col
  const int NA128 = (NN + 15) / 16;                  // 3125 agg blocks, D=128
  const int NA256 = (NN + 7) / 8;                    // 6250 agg blocks, D=256

  // one memset covers cnt_g, cnt_k, cur_g, cur_k, stats
  hipMemsetAsync(cnt_g, 0, (size_t)(4 * NN) * sizeof(int) + 512 * sizeof(float), stream);

  WPack p;
  p.d[0] = {(const float*)d_in[5], 128, 8, 0, 256, wL0};
  p.d[1] = {(const float*)d_in[6], 128, 8, 128, 256, wL0};
  p.d[2] = {(const float*)d_in[8], 256, 8, 0, 512, wL1};
  p.d[3] = {(const float*)d_in[9], 256, 8, 256, 512, wL1};
  p.d[4] = {(const float*)d_in[11], 256, 8, 0, 512, wL2};
  p.d[5] = {(const float*)d_in[12], 256, 8, 256, 512, wL2};
  p.d[6] = {(const float*)d_in[14], 128, 8, 0, 256, wG0};
  p.d[7] = {(const float*)d_in[15], 128, 8, 128, 256, wG0};
  p.d[8] = {(const float*)d_in[17], 256, 8, 0, 512, wG1};
  p.d[9] = {(const float*)d_in[18], 256, 8, 256, 512, wG1};
  p.d[10] = {(const float*)d_in[20], 512, 7, 0, 512, wH1};
  p.d[11] = {(const float*)d_in[24], 128, 6, 0, 128, wH2};
  prep_kernel<<<8979, blk, 0, stream>>>(feat, featbf, p, wts, g_dst, k_dst, cnt_g, cnt_k);

  scan_partial2<<<dim3(NB, 2), blk, 0, stream>>>(cnt_g, cnt_k, part, NN);
  scan_block2<<<2, blk, 0, stream>>>(part, NB);
  scan_final2<<<dim3(NB, 2), blk, 0, stream>>>(cnt_g, cnt_k, part, off_g, off_k, invg, invk, NN);
  fill2<<<(EG + EK + 255) / 256, blk, 0, stream>>>(g_src, g_dst, k_src, k_dst, off_g, off_k,
                                                   cur_g, cur_k, esrc_g, esrc_k);

  // S1: agg_g(feat) -> aggG
  agg_kernel<7><<<NA128, blk, 0, stream>>>(featbf, off_g, esrc_g, invg, aggG);
  // S2: gemm_l0 (feat,aggG -> bufP) || agg_k(feat) -> aggK
  fused_agg_gemm<7, 128, 128, true><<<NA128 + NG_H, blk, 0, stream>>>(
      featbf, off_k, esrc_k, invk, aggK, NA128,
      featbf, aggG, wts + wL0, lb_0, bufP, HF, NG_H, GX);
  // S3: agg_g(bufP) -> aggG || gemm_g0 (feat,aggK -> bufQ)
  fused_agg_gemm<8, 128, 128, true><<<NA256 + NG_H, blk, 0, stream>>>(
      bufP, off_g, esrc_g, invg, aggG, NA256,
      featbf, aggK, wts + wG0, gb_0, bufQ, HF, NG_H, GX);
  // S4: agg_k(bufQ) -> aggK || gemm_l1 (bufP,aggG -> bufR)
  fused_agg_gemm<8, 256, 256, true><<<NA256 + NG_H, blk, 0, stream>>>(
      bufQ, off_k, esrc_k, invk, aggK, NA256,
      bufP, aggG, wts + wL1, lb_1, bufR, HF, NG_H, GX);
  // S5: agg_g(bufR) -> aggG || gemm_g1 (bufQ,aggK -> bufP = global_emb)
  fused_agg_gemm<8, 256, 256, false><<<NA256 + NG_H, blk, 0, stream>>>(
      bufR, off_g, esrc_g, invg, aggG, NA256,
      bufQ, aggK, wts + wG1, gb_1, bufP, HF, NG_H, GX);
  // S6: gemm_l2 (bufR,aggG -> bufQ = local_emb) || head-global (bufP -> xf32, +b1)
  fused_gemm2_s6<<<NG_H + NG_M, blk, 0, stream>>>(
      bufR, aggG, wts + wL2, lb_2, bufQ,
      bufP, wts + wH1, mlp_b1, xf32, NG_H);
  // S7: head-local (bufQ) accumulate into xf32
  gemm_head_local<<<NG_M, blk, 0, stream>>>(bufQ, wts + wH1, xf32);

  // BN
  bn_stats_kernel<<<256, blk, 0, stream>>>(xf32, stats, stats + 128);
  bn_finalize_kernel<<<1, 128, 0, stream>>>(stats, bn_gamma, bn_beta);

  // final head GEMM with fused BN+ReLU
  gemm_mfma_bn<128, false><<<dim3(1, (NN + 63) / 64), blk, 0, stream>>>(
      xf32, wts + wH2, mlp_b2, stats + 256, stats + 384, out, COUT, NN);
}

// Round 7
// 622.061 us; speedup vs baseline: 1.0933x; 1.0933x over previous
//
#include <hip/hip_runtime.h>

#define NN   50000
#define IN_F 128
#define HF   256
#define COUT 64
#define MLPH 128
#define EG   600000
#define EK   800000
#define BN_EPS 1e-5f

typedef __attribute__((ext_vector_type(8))) short short8;
typedef __attribute__((ext_vector_type(8))) unsigned short ushort8;
typedef __attribute__((ext_vector_type(4))) float f32x4;

__device__ __forceinline__ unsigned short f2bf(float f) {
  union { float f; unsigned int u; } v; v.f = f;
  unsigned int r = v.u + 0x7FFFu + ((v.u >> 16) & 1u);
  return (unsigned short)(r >> 16);
}
__device__ __forceinline__ float bf2f(unsigned short s) {
  union { unsigned int u; float f; } v; v.u = ((unsigned int)s) << 16;
  return v.f;
}

// async global->LDS, 16B per lane; LDS dest must be wave-uniform base
__device__ __forceinline__ void gload_lds16(const void* g, void* l) {
  __builtin_amdgcn_global_load_lds((const __attribute__((address_space(1))) void*)g,
                                   (__attribute__((address_space(3))) void*)l, 16, 0, 0);
}

struct WDesc { const float* src; int rows; int cshift; int kofs; int ldk; int dofs; };
struct WPack { WDesc d[12]; };

// ---------------- prep: feat->bf16, weight transpose, degree counts ----------------
__global__ __launch_bounds__(256) void prep_kernel(const float* __restrict__ feat,
                                                   unsigned short* __restrict__ featbf,
                                                   WPack p, unsigned short* __restrict__ wts,
                                                   const int* __restrict__ g_dst,
                                                   const int* __restrict__ k_dst,
                                                   int* __restrict__ cnt_g,
                                                   int* __restrict__ cnt_k) {
  int b = blockIdx.x;
  if (b < 3126) {
    int i = b * 256 + threadIdx.x;
    if (i < NN * IN_F / 8) {
      float4 a = *reinterpret_cast<const float4*>(&feat[i * 8]);
      float4 c = *reinterpret_cast<const float4*>(&feat[i * 8 + 4]);
      ushort8 o;
      o[0] = f2bf(a.x); o[1] = f2bf(a.y); o[2] = f2bf(a.z); o[3] = f2bf(a.w);
      o[4] = f2bf(c.x); o[5] = f2bf(c.y); o[6] = f2bf(c.z); o[7] = f2bf(c.w);
      *reinterpret_cast<ushort8*>(&featbf[i * 8]) = o;
    }
  } else if (b < 3510) {
    int wb = b - 3126;
    WDesc w = p.d[wb >> 5];
    int xb = wb & 31;
    int total = w.rows << w.cshift;
    int cmask = (1 << w.cshift) - 1;
    for (int idx = xb * 256 + threadIdx.x; idx < total; idx += 32 * 256) {
      int r = idx >> w.cshift, c = idx & cmask;
      wts[w.dofs + (size_t)c * w.ldk + w.kofs + r] = f2bf(w.src[idx]);
    }
  } else {
    int e = (b - 3510) * 256 + threadIdx.x;
    if (e < EG) atomicAdd(&cnt_g[g_dst[e]], 1);
    else if (e < EG + EK) atomicAdd(&cnt_k[k_dst[e - EG]], 1);
  }
}

// ---------------- parallel scans for both graphs ----------------
__global__ __launch_bounds__(256) void scan_partial2(const int* __restrict__ cnt_g,
                                                     const int* __restrict__ cnt_k,
                                                     int* __restrict__ part, int n) {
  const int* cnt = blockIdx.y ? cnt_k : cnt_g;
  int* pp = part + blockIdx.y * 256;
  int i = blockIdx.x * 256 + threadIdx.x;
  int v = (i < n) ? cnt[i] : 0;
  __shared__ int ws[4];
  int lane = threadIdx.x & 63, wid = threadIdx.x >> 6;
  int x = v;
#pragma unroll
  for (int d = 1; d < 64; d <<= 1) { int y = __shfl_up(x, d, 64); if (lane >= d) x += y; }
  if (lane == 63) ws[wid] = x;
  __syncthreads();
  if (threadIdx.x == 0) pp[blockIdx.x] = ws[0] + ws[1] + ws[2] + ws[3];
}

__global__ __launch_bounds__(256) void scan_block2(int* __restrict__ part, int np) {
  int* pp = part + blockIdx.x * 256;
  __shared__ int ws[4];
  int tid = threadIdx.x, lane = tid & 63, wid = tid >> 6;
  int v = (tid < np) ? pp[tid] : 0;
  int x = v;
#pragma unroll
  for (int d = 1; d < 64; d <<= 1) { int y = __shfl_up(x, d, 64); if (lane >= d) x += y; }
  if (lane == 63) ws[wid] = x;
  __syncthreads();
  int add = 0;
#pragma unroll
  for (int k = 0; k < 4; ++k) if (k < wid) add += ws[k];
  if (tid < np) pp[tid] = x - v + add;
}

__global__ __launch_bounds__(256) void scan_final2(const int* __restrict__ cnt_g,
                                                   const int* __restrict__ cnt_k,
                                                   const int* __restrict__ part,
                                                   int* __restrict__ off_g,
                                                   int* __restrict__ off_k,
                                                   float* __restrict__ invg,
                                                   float* __restrict__ invk, int n) {
  const int* cnt = blockIdx.y ? cnt_k : cnt_g;
  const int* pp = part + blockIdx.y * 256;
  int* off = blockIdx.y ? off_k : off_g;
  float* inv = blockIdx.y ? invk : invg;
  int total = blockIdx.y ? EK : EG;
  int i = blockIdx.x * 256 + threadIdx.x;
  int v = (i < n) ? cnt[i] : 0;
  __shared__ int ws[4];
  int lane = threadIdx.x & 63, wid = threadIdx.x >> 6;
  int x = v;
#pragma unroll
  for (int d = 1; d < 64; d <<= 1) { int y = __shfl_up(x, d, 64); if (lane >= d) x += y; }
  if (lane == 63) ws[wid] = x;
  __syncthreads();
  int add = pp[blockIdx.x];
#pragma unroll
  for (int k = 0; k < 4; ++k) if (k < wid) add += ws[k];
  if (i < n) {
    off[i] = x - v + add;
    inv[i] = 1.0f / fmaxf((float)v, 1.0f);
  }
  if (i == 0) off[n] = total;
}

__global__ __launch_bounds__(256) void fill2(const int* __restrict__ g_src,
                                             const int* __restrict__ g_dst,
                                             const int* __restrict__ k_src,
                                             const int* __restrict__ k_dst,
                                             const int* __restrict__ off_g,
                                             const int* __restrict__ off_k,
                                             int* __restrict__ cur_g, int* __restrict__ cur_k,
                                             int* __restrict__ esrc_g,
                                             int* __restrict__ esrc_k) {
  int e = blockIdx.x * 256 + threadIdx.x;
  if (e < EG) {
    int d = g_dst[e];
    int pz = atomicAdd(&cur_g[d], 1);
    esrc_g[off_g[d] + pz] = g_src[e];
  } else if (e < EG + EK) {
    int e2 = e - EG;
    int d = k_dst[e2];
    int pz = atomicAdd(&cur_k[d], 1);
    esrc_k[off_k[d] + pz] = k_src[e2];
  }
}

// ---------------- CSR mean-aggregation (bf16 in/out), unroll-4 ----------------
template <int DLOG2>
__global__ __launch_bounds__(256) void csr_aggregate(const unsigned short* __restrict__ h,
                                                     const int* __restrict__ off,
                                                     const int* __restrict__ esrc,
                                                     const float* __restrict__ inv,
                                                     unsigned short* __restrict__ out) {
  constexpr int TPN = (1 << DLOG2) / 8;
  constexpr int NPB = 256 / TPN;
  int node = blockIdx.x * NPB + ((int)threadIdx.x / TPN);
  int lane = threadIdx.x & (TPN - 1);
  if (node >= NN) return;
  int s = off[node], e = off[node + 1];
  float acc[8] = {0.f, 0.f, 0.f, 0.f, 0.f, 0.f, 0.f, 0.f};
  int j = s;
  for (; j + 3 < e; j += 4) {
    int s0 = esrc[j], s1 = esrc[j + 1], s2 = esrc[j + 2], s3 = esrc[j + 3];
    ushort8 v0 = *reinterpret_cast<const ushort8*>(&h[((size_t)s0 << DLOG2) + lane * 8]);
    ushort8 v1 = *reinterpret_cast<const ushort8*>(&h[((size_t)s1 << DLOG2) + lane * 8]);
    ushort8 v2 = *reinterpret_cast<const ushort8*>(&h[((size_t)s2 << DLOG2) + lane * 8]);
    ushort8 v3 = *reinterpret_cast<const ushort8*>(&h[((size_t)s3 << DLOG2) + lane * 8]);
#pragma unroll
    for (int i = 0; i < 8; ++i) acc[i] += bf2f(v0[i]);
#pragma unroll
    for (int i = 0; i < 8; ++i) acc[i] += bf2f(v1[i]);
#pragma unroll
    for (int i = 0; i < 8; ++i) acc[i] += bf2f(v2[i]);
#pragma unroll
    for (int i = 0; i < 8; ++i) acc[i] += bf2f(v3[i]);
  }
  for (; j < e; ++j) {
    int s0 = esrc[j];
    ushort8 v0 = *reinterpret_cast<const ushort8*>(&h[((size_t)s0 << DLOG2) + lane * 8]);
#pragma unroll
    for (int i = 0; i < 8; ++i) acc[i] += bf2f(v0[i]);
  }
  float sc = inv[node];
  ushort8 o;
#pragma unroll
  for (int i = 0; i < 8; ++i) o[i] = f2bf(acc[i] * sc);
  *reinterpret_cast<ushort8*>(&out[((size_t)node << DLOG2) + lane * 8]) = o;
}

// ---------------- MFMA GEMM, BM=128 x BN=128, BK=64, global_load_lds staging ----------------
// out[m][n] = act( sum_{k<K1} A1[m][k] Bt[n][k] + sum_{k<K2} A2[m][k] Bt[n][K1+k] + bias[n] )
template <int K1, int K2, bool RELU, bool OUT_BF16>
__global__ __launch_bounds__(256) void gemm_gl(
    const unsigned short* __restrict__ A1, const unsigned short* __restrict__ A2,
    const unsigned short* __restrict__ Bt, const float* __restrict__ bias,
    void* __restrict__ outv, int ldo, int nrows) {
  constexpr int KTOT = K1 + K2;
  constexpr int KT = KTOT / 64;
  __shared__ char smem[32768];                       // A[128][64] + B[128][64] bf16, linear
  unsigned short* sA = (unsigned short*)smem;        // 8192 elems
  unsigned short* sB = sA + 8192;

  const int t = threadIdx.x;
  const int lane = t & 63;
  const int w = t >> 6;
  const int wm = (w & 1) * 64, wn = (w >> 1) * 64;
  const int row0 = blockIdx.y * 128;
  const int n0 = blockIdx.x * 128;

  const int srow = (w << 5) + (lane >> 3);   // staged row within 32-row wave span
  const int schunk = (lane & 7) << 3;        // element offset (8 bf16 = 16B)

  f32x4 acc[4][4] = {};

  for (int kt = 0; kt < KT; ++kt) {
    const int kbase = kt * 64;
    const unsigned short* Asrc = (kbase < K1) ? A1 : A2;
    const int kA = (kbase < K1) ? kbase : (kbase - K1);
    const int lda = (kbase < K1) ? K1 : K2;
#pragma unroll
    for (int q = 0; q < 4; ++q) {
      int rA = srow + q * 8;
      int rowg = row0 + rA;
      if (rowg >= nrows) rowg = nrows - 1;
      gload_lds16(Asrc + (size_t)rowg * lda + kA + schunk,
                  sA + ((w << 5) + q * 8) * 64);
      gload_lds16(Bt + (size_t)(n0 + rA) * KTOT + kbase + schunk,
                  sB + ((w << 5) + q * 8) * 64);
    }
    __syncthreads();
#pragma unroll
    for (int kk = 0; kk < 2; ++kk) {
      const int ko = kk * 32 + (lane >> 4) * 8;
      short8 a[4], b[4];
#pragma unroll
      for (int mi = 0; mi < 4; ++mi)
        a[mi] = *reinterpret_cast<const short8*>(&sA[(wm + mi * 16 + (lane & 15)) * 64 + ko]);
#pragma unroll
      for (int ni = 0; ni < 4; ++ni)
        b[ni] = *reinterpret_cast<const short8*>(&sB[(wn + ni * 16 + (lane & 15)) * 64 + ko]);
#pragma unroll
      for (int mi = 0; mi < 4; ++mi)
#pragma unroll
        for (int ni = 0; ni < 4; ++ni)
          acc[mi][ni] = __builtin_amdgcn_mfma_f32_16x16x32_bf16(a[mi], b[ni], acc[mi][ni], 0, 0, 0);
    }
    __syncthreads();
  }

  // ---- epilogue: two 64-col halves through LDS (reuse smem as Co[128][64] f32) ----
  float* Co = (float*)smem;
#pragma unroll
  for (int h = 0; h < 2; ++h) {
    __syncthreads();
    if ((w >> 1) == h) {
#pragma unroll
      for (int mi = 0; mi < 4; ++mi)
#pragma unroll
        for (int ni = 0; ni < 4; ++ni) {
          int col = ni * 16 + (lane & 15);
          int rowb = wm + mi * 16 + (lane >> 4) * 4;
#pragma unroll
          for (int j = 0; j < 4; ++j) Co[(rowb + j) * 64 + col] = acc[mi][ni][j];
        }
    }
    __syncthreads();
    int sr = t >> 1, cb = (t & 1) * 32;
    int r = row0 + sr;
    if (r < nrows) {
      float v[32];
#pragma unroll
      for (int i = 0; i < 32; ++i) {
        v[i] = Co[sr * 64 + cb + i] + bias[n0 + h * 64 + cb + i];
        if (RELU) v[i] = fmaxf(v[i], 0.f);
      }
      if (OUT_BF16) {
        unsigned short* dst = (unsigned short*)outv + (size_t)r * ldo + n0 + h * 64 + cb;
#pragma unroll
        for (int q = 0; q < 4; ++q) {
          ushort8 o;
#pragma unroll
          for (int i = 0; i < 8; ++i) o[i] = f2bf(v[q * 8 + i]);
          *reinterpret_cast<ushort8*>(dst + q * 8) = o;
        }
      } else {
        float* dst = (float*)outv + (size_t)r * ldo + n0 + h * 64 + cb;
#pragma unroll
        for (int q = 0; q < 8; ++q) {
          float4 o = make_float4(v[4 * q], v[4 * q + 1], v[4 * q + 2], v[4 * q + 3]);
          *reinterpret_cast<float4*>(dst + 4 * q) = o;
        }
      }
    }
  }
}

// ---------------- BN ----------------
__global__ __launch_bounds__(256) void bn_stats_kernel(const float* __restrict__ x,
                                                       float* __restrict__ sums,
                                                       float* __restrict__ sumsq) {
  int c = threadIdx.x & 127;
  int rbase = (blockIdx.x * 256 + threadIdx.x) >> 7;
  int stride = (gridDim.x * 256) >> 7;
  float s = 0.f, s2 = 0.f;
  for (int r = rbase; r < NN; r += stride) {
    float v = x[(size_t)r * 128 + c];
    s += v;
    s2 += v * v;
  }
  __shared__ float ls[256], ls2[256];
  ls[threadIdx.x] = s;
  ls2[threadIdx.x] = s2;
  __syncthreads();
  if (threadIdx.x < 128) {
    s = ls[threadIdx.x] + ls[threadIdx.x + 128];
    s2 = ls2[threadIdx.x] + ls2[threadIdx.x + 128];
    atomicAdd(&sums[c], s);
    atomicAdd(&sumsq[c], s2);
  }
}

__global__ __launch_bounds__(128) void bn_finalize_kernel(float* __restrict__ stats,
                                                          const float* __restrict__ gamma,
                                                          const float* __restrict__ beta) {
  int c = threadIdx.x;
  float mu = stats[c] * (1.0f / NN);
  float var = stats[128 + c] * (1.0f / NN) - mu * mu;
  var = fmaxf(var, 0.f);
  float sc = gamma[c] * rsqrtf(var + BN_EPS);
  stats[256 + c] = sc;
  stats[384 + c] = beta[c] - mu * sc;
}

// ---------------- final head GEMM with fused BN+ReLU on A-load (64x64) ----------------
template <int K1, bool RELU>
__global__ __launch_bounds__(256) void gemm_mfma_bn(
    const float* __restrict__ A1v, const unsigned short* __restrict__ Bt,
    const float* __restrict__ bias, const float* __restrict__ bnscale,
    const float* __restrict__ bnshift, float* __restrict__ outv, int ldo, int nrows) {
  constexpr int KT = K1 / 64;
  constexpr int LDT = 72;
  __shared__ char smem[2 * 64 * LDT * 2];
  unsigned short* As = (unsigned short*)smem;
  unsigned short* Bs = As + 64 * LDT;
  float* Co = (float*)smem;
  constexpr int LDC = 68;

  const int t = threadIdx.x;
  const int lane = t & 63;
  const int w = t >> 6;
  const int wm = (w & 1) * 32, wn = (w >> 1) * 32;
  const int row0 = blockIdx.y * 64;
  const int n0 = blockIdx.x * 64;

  const int sr = t >> 2;
  const int skc = (t & 3) * 16;
  int rg = row0 + sr;
  if (rg >= nrows) rg = nrows - 1;

  f32x4 acc[2][2] = {};

  for (int kt = 0; kt < KT; ++kt) {
    const int kbase = kt * 64;
    {
      const float* xb = A1v + (size_t)rg * K1 + kbase + skc;
      ushort8 o0, o1;
#pragma unroll
      for (int i = 0; i < 8; ++i) {
        float v = xb[i] * bnscale[kbase + skc + i] + bnshift[kbase + skc + i];
        o0[i] = f2bf(fmaxf(v, 0.f));
      }
#pragma unroll
      for (int i = 0; i < 8; ++i) {
        float v = xb[8 + i] * bnscale[kbase + skc + 8 + i] + bnshift[kbase + skc + 8 + i];
        o1[i] = f2bf(fmaxf(v, 0.f));
      }
      *reinterpret_cast<ushort8*>(&As[sr * LDT + skc]) = o0;
      *reinterpret_cast<ushort8*>(&As[sr * LDT + skc + 8]) = o1;
    }
    {
      const unsigned short* bb = Bt + (size_t)(n0 + sr) * K1 + kbase + skc;
      int4 p0 = *reinterpret_cast<const int4*>(bb);
      int4 p1 = *reinterpret_cast<const int4*>(bb + 8);
      *reinterpret_cast<int4*>(&Bs[sr * LDT + skc]) = p0;
      *reinterpret_cast<int4*>(&Bs[sr * LDT + skc + 8]) = p1;
    }
    __syncthreads();
#pragma unroll
    for (int kk = 0; kk < 2; ++kk) {
      const int ko = kk * 32 + (lane >> 4) * 8;
      short8 a0 = *reinterpret_cast<const short8*>(&As[(wm + (lane & 15)) * LDT + ko]);
      short8 a1 = *reinterpret_cast<const short8*>(&As[(wm + 16 + (lane & 15)) * LDT + ko]);
      short8 b0 = *reinterpret_cast<const short8*>(&Bs[(wn + (lane & 15)) * LDT + ko]);
      short8 b1 = *reinterpret_cast<const short8*>(&Bs[(wn + 16 + (lane & 15)) * LDT + ko]);
      acc[0][0] = __builtin_amdgcn_mfma_f32_16x16x32_bf16(a0, b0, acc[0][0], 0, 0, 0);
      acc[0][1] = __builtin_amdgcn_mfma_f32_16x16x32_bf16(a0, b1, acc[0][1], 0, 0, 0);
      acc[1][0] = __builtin_amdgcn_mfma_f32_16x16x32_bf16(a1, b0, acc[1][0], 0, 0, 0);
      acc[1][1] = __builtin_amdgcn_mfma_f32_16x16x32_bf16(a1, b1, acc[1][1], 0, 0, 0);
    }
    __syncthreads();
  }

#pragma unroll
  for (int mi = 0; mi < 2; ++mi)
#pragma unroll
    for (int ni = 0; ni < 2; ++ni) {
      int col = wn + ni * 16 + (lane & 15);
      int rowb = wm + mi * 16 + (lane >> 4) * 4;
#pragma unroll
      for (int j = 0; j < 4; ++j) Co[(rowb + j) * LDC + col] = acc[mi][ni][j];
    }
  __syncthreads();
  {
    int r = row0 + sr;
    if (r < nrows) {
      float v[16];
#pragma unroll
      for (int i = 0; i < 16; ++i) {
        v[i] = Co[sr * LDC + skc + i] + bias[n0 + skc + i];
        if (RELU) v[i] = fmaxf(v[i], 0.f);
      }
      float* dst = outv + (size_t)r * ldo + n0 + skc;
#pragma unroll
      for (int i = 0; i < 4; ++i) {
        float4 o = make_float4(v[4 * i], v[4 * i + 1], v[4 * i + 2], v[4 * i + 3]);
        *reinterpret_cast<float4*>(dst + 4 * i) = o;
      }
    }
  }
}

// ---------------- launch ----------------
extern "C" void kernel_launch(void* const* d_in, const int* in_sizes, int n_in,
                              void* d_out, int out_size, void* d_ws, size_t ws_size,
                              hipStream_t stream) {
  const float* feat = (const float*)d_in[0];
  const int* g_src = (const int*)d_in[1];
  const int* g_dst = (const int*)d_in[2];
  const int* k_src = (const int*)d_in[3];
  const int* k_dst = (const int*)d_in[4];
  const float* lb_0 = (const float*)d_in[7];
  const float* lb_1 = (const float*)d_in[10];
  const float* lb_2 = (const float*)d_in[13];
  const float* gb_0 = (const float*)d_in[16];
  const float* gb_1 = (const float*)d_in[19];
  const float* mlp_b1 = (const float*)d_in[21];
  const float* bn_gamma = (const float*)d_in[22];
  const float* bn_beta = (const float*)d_in[23];
  const float* mlp_b2 = (const float*)d_in[25];
  float* out = (float*)d_out;

  // workspace layout
  float* xf32 = (float*)d_ws;                         // N*128 f32
  int* cnt_g = (int*)(xf32 + (size_t)NN * 128);       // N
  int* cnt_k = cnt_g + NN;                            // N
  int* cur_g = cnt_k + NN;                            // N
  int* cur_k = cur_g + NN;                            // N
  float* stats = (float*)(cur_k + NN);                // 512 (zeroed with cnt/cur)
  float* invg = stats + 512;                          // N
  float* invk = invg + NN;                            // N
  int* off_g = (int*)(invk + NN);                     // N+4
  int* off_k = off_g + NN + 4;                        // N+4
  int* part = off_k + NN + 4;                         // 512
  int* esrc_g = part + 512;                           // EG
  int* esrc_k = esrc_g + EG;                          // EK
  unsigned short* featbf = (unsigned short*)(esrc_k + EK);  // N*128
  unsigned short* wts = featbf + (size_t)NN * IN_F;         // 598016
  unsigned short* bfA = wts + 598016;                 // N*256
  unsigned short* bfB = bfA + (size_t)NN * HF;        // N*256
  unsigned short* bfAgg = bfB + (size_t)NN * HF;      // N*256
  unsigned short* bfD = bfAgg + (size_t)NN * HF;      // N*256 (local_emb)

  const int wL0 = 0, wL1 = 65536, wL2 = 196608, wG0 = 327680, wG1 = 393216,
            wH1 = 524288, wH2 = 589824;

  dim3 blk(256);
  const int NB = (NN + 255) / 256;        // 196
  const int MB = (NN + 127) / 128;        // 391
  const dim3 gridH(2, MB);                // 256-col out, BM=128 BN=128
  const dim3 gridM(1, MB);                // 128-col out
  const int agg128_blocks = (NN + 15) / 16;
  const int agg256_blocks = (NN + 7) / 8;

  // zero cnt_g, cnt_k, cur_g, cur_k, stats in one go
  hipMemsetAsync(cnt_g, 0, (size_t)(4 * NN) * sizeof(int) + 512 * sizeof(float), stream);

  WPack p;
  p.d[0] = {(const float*)d_in[5], 128, 8, 0, 256, wL0};
  p.d[1] = {(const float*)d_in[6], 128, 8, 128, 256, wL0};
  p.d[2] = {(const float*)d_in[8], 256, 8, 0, 512, wL1};
  p.d[3] = {(const float*)d_in[9], 256, 8, 256, 512, wL1};
  p.d[4] = {(const float*)d_in[11], 256, 8, 0, 512, wL2};
  p.d[5] = {(const float*)d_in[12], 256, 8, 256, 512, wL2};
  p.d[6] = {(const float*)d_in[14], 128, 8, 0, 256, wG0};
  p.d[7] = {(const float*)d_in[15], 128, 8, 128, 256, wG0};
  p.d[8] = {(const float*)d_in[17], 256, 8, 0, 512, wG1};
  p.d[9] = {(const float*)d_in[18], 256, 8, 256, 512, wG1};
  p.d[10] = {(const float*)d_in[20], 512, 7, 0, 512, wH1};
  p.d[11] = {(const float*)d_in[24], 128, 6, 0, 128, wH2};
  prep_kernel<<<8979, blk, 0, stream>>>(feat, featbf, p, wts, g_dst, k_dst, cnt_g, cnt_k);

  scan_partial2<<<dim3(NB, 2), blk, 0, stream>>>(cnt_g, cnt_k, part, NN);
  scan_block2<<<2, blk, 0, stream>>>(part, NB);
  scan_final2<<<dim3(NB, 2), blk, 0, stream>>>(cnt_g, cnt_k, part, off_g, off_k, invg, invk, NN);
  fill2<<<(EG + EK + 255) / 256, blk, 0, stream>>>(g_src, g_dst, k_src, k_dst, off_g, off_k,
                                                   cur_g, cur_k, esrc_g, esrc_k);

  // ---- local layer 0 ----
  csr_aggregate<7><<<agg128_blocks, blk, 0, stream>>>(featbf, off_g, esrc_g, invg, bfAgg);
  gemm_gl<128, 128, true, true><<<gridH, blk, 0, stream>>>(
      featbf, bfAgg, wts + wL0, lb_0, bfA, HF, NN);
  // ---- local layer 1 ----
  csr_aggregate<8><<<agg256_blocks, blk, 0, stream>>>(bfA, off_g, esrc_g, invg, bfAgg);
  gemm_gl<256, 256, true, true><<<gridH, blk, 0, stream>>>(
      bfA, bfAgg, wts + wL1, lb_1, bfB, HF, NN);
  // ---- local layer 2 -> local_emb ----
  csr_aggregate<8><<<agg256_blocks, blk, 0, stream>>>(bfB, off_g, esrc_g, invg, bfAgg);
  gemm_gl<256, 256, false, true><<<gridH, blk, 0, stream>>>(
      bfB, bfAgg, wts + wL2, lb_2, bfD, HF, NN);
  // ---- global layer 0 ----
  csr_aggregate<7><<<agg128_blocks, blk, 0, stream>>>(featbf, off_k, esrc_k, invk, bfAgg);
  gemm_gl<128, 128, true, true><<<gridH, blk, 0, stream>>>(
      featbf, bfAgg, wts + wG0, gb_0, bfA, HF, NN);
  // ---- global layer 1 -> global_emb ----
  csr_aggregate<8><<<agg256_blocks, blk, 0, stream>>>(bfA, off_k, esrc_k, invk, bfAgg);
  gemm_gl<256, 256, false, true><<<gridH, blk, 0, stream>>>(
      bfA, bfAgg, wts + wG1, gb_1, bfB, HF, NN);

  // ---- head GEMM1: x = [local_emb | global_emb] @ w1 + b1 (f32 out) ----
  gemm_gl<256, 256, false, false><<<gridM, blk, 0, stream>>>(
      bfD, bfB, wts + wH1, mlp_b1, xf32, MLPH, NN);

  // ---- BatchNorm ----
  bn_stats_kernel<<<256, blk, 0, stream>>>(xf32, stats, stats + 128);
  bn_finalize_kernel<<<1, 128, 0, stream>>>(stats, bn_gamma, bn_beta);

  // ---- head GEMM2 ----
  gemm_mfma_bn<128, false><<<dim3(1, (NN + 63) / 64), blk, 0, stream>>>(
      xf32, wts + wH2, mlp_b2, stats + 256, stats + 384, out, COUT, NN);
}

// Round 8
// 583.571 us; speedup vs baseline: 1.1654x; 1.0660x over previous
//
#include <hip/hip_runtime.h>

#define NN   50000
#define IN_F 128
#define HF   256
#define COUT 64
#define MLPH 128
#define EG   600000
#define EK   800000
#define BN_EPS 1e-5f

typedef __attribute__((ext_vector_type(8))) short short8;
typedef __attribute__((ext_vector_type(8))) unsigned short ushort8;
typedef __attribute__((ext_vector_type(4))) float f32x4;

__device__ __forceinline__ unsigned short f2bf(float f) {
  union { float f; unsigned int u; } v; v.f = f;
  unsigned int r = v.u + 0x7FFFu + ((v.u >> 16) & 1u);
  return (unsigned short)(r >> 16);
}
__device__ __forceinline__ float bf2f(unsigned short s) {
  union { unsigned int u; float f; } v; v.u = ((unsigned int)s) << 16;
  return v.f;
}

// async global->LDS, 16B per lane; LDS dest must be wave-uniform base
__device__ __forceinline__ void gload_lds16(const void* g, void* l) {
  __builtin_amdgcn_global_load_lds((const __attribute__((address_space(1))) void*)g,
                                   (__attribute__((address_space(3))) void*)l, 16, 0, 0);
}

struct WDesc { const float* src; int rows; int cshift; int kofs; int ldk; int dofs; };
struct WPack { WDesc d[12]; };

// ---------------- prep: feat->bf16, weight transpose, degree counts ----------------
__global__ __launch_bounds__(256) void prep_kernel(const float* __restrict__ feat,
                                                   unsigned short* __restrict__ featbf,
                                                   WPack p, unsigned short* __restrict__ wts,
                                                   const int* __restrict__ g_dst,
                                                   const int* __restrict__ k_dst,
                                                   int* __restrict__ cnt_g,
                                                   int* __restrict__ cnt_k) {
  int b = blockIdx.x;
  if (b < 3126) {
    int i = b * 256 + threadIdx.x;
    if (i < NN * IN_F / 8) {
      float4 a = *reinterpret_cast<const float4*>(&feat[i * 8]);
      float4 c = *reinterpret_cast<const float4*>(&feat[i * 8 + 4]);
      ushort8 o;
      o[0] = f2bf(a.x); o[1] = f2bf(a.y); o[2] = f2bf(a.z); o[3] = f2bf(a.w);
      o[4] = f2bf(c.x); o[5] = f2bf(c.y); o[6] = f2bf(c.z); o[7] = f2bf(c.w);
      *reinterpret_cast<ushort8*>(&featbf[i * 8]) = o;
    }
  } else if (b < 3510) {
    int wb = b - 3126;
    WDesc w = p.d[wb >> 5];
    int xb = wb & 31;
    int total = w.rows << w.cshift;
    int cmask = (1 << w.cshift) - 1;
    for (int idx = xb * 256 + threadIdx.x; idx < total; idx += 32 * 256) {
      int r = idx >> w.cshift, c = idx & cmask;
      wts[w.dofs + (size_t)c * w.ldk + w.kofs + r] = f2bf(w.src[idx]);
    }
  } else {
    int e = (b - 3510) * 256 + threadIdx.x;
    if (e < EG) atomicAdd(&cnt_g[g_dst[e]], 1);
    else if (e < EG + EK) atomicAdd(&cnt_k[k_dst[e - EG]], 1);
  }
}

// ---------------- fused head weights: wf[c][seg*256+i] = sum_o Wseg[i,o] * w1[segbase+o, c]
__global__ __launch_bounds__(128) void fuse_w_kernel(
    const float* __restrict__ wl2s, const float* __restrict__ wl2n,
    const float* __restrict__ wg1s, const float* __restrict__ wg1n,
    const float* __restrict__ w1, const float* __restrict__ bl2,
    const float* __restrict__ bg1, const float* __restrict__ b1,
    unsigned short* __restrict__ wf, float* __restrict__ bfused) {
  int b = blockIdx.x;
  int c = threadIdx.x;  // 0..127
  __shared__ float row[256];
  if (b < 1024) {
    int seg = b >> 8, i = b & 255;
    const float* W = (seg == 0) ? wl2s : (seg == 1) ? wl2n : (seg == 2) ? wg1s : wg1n;
    const float* w1b = w1 + ((seg < 2) ? 0 : 256) * MLPH;
    row[c] = W[i * 256 + c];
    row[c + 128] = W[i * 256 + 128 + c];
    __syncthreads();
    float acc = 0.f;
    for (int o = 0; o < 256; ++o) acc += row[o] * w1b[o * MLPH + c];
    wf[(size_t)c * 1024 + seg * 256 + i] = f2bf(acc);
  } else {
    float acc = b1[c];
    for (int o = 0; o < 256; ++o) acc += bl2[o] * w1[o * MLPH + c];
    for (int o = 0; o < 256; ++o) acc += bg1[o] * w1[(256 + o) * MLPH + c];
    bfused[c] = acc;
  }
}

// ---------------- parallel scans for both graphs ----------------
__global__ __launch_bounds__(256) void scan_partial2(const int* __restrict__ cnt_g,
                                                     const int* __restrict__ cnt_k,
                                                     int* __restrict__ part, int n) {
  const int* cnt = blockIdx.y ? cnt_k : cnt_g;
  int* pp = part + blockIdx.y * 256;
  int i = blockIdx.x * 256 + threadIdx.x;
  int v = (i < n) ? cnt[i] : 0;
  __shared__ int ws[4];
  int lane = threadIdx.x & 63, wid = threadIdx.x >> 6;
  int x = v;
#pragma unroll
  for (int d = 1; d < 64; d <<= 1) { int y = __shfl_up(x, d, 64); if (lane >= d) x += y; }
  if (lane == 63) ws[wid] = x;
  __syncthreads();
  if (threadIdx.x == 0) pp[blockIdx.x] = ws[0] + ws[1] + ws[2] + ws[3];
}

__global__ __launch_bounds__(256) void scan_block2(int* __restrict__ part, int np) {
  int* pp = part + blockIdx.x * 256;
  __shared__ int ws[4];
  int tid = threadIdx.x, lane = tid & 63, wid = tid >> 6;
  int v = (tid < np) ? pp[tid] : 0;
  int x = v;
#pragma unroll
  for (int d = 1; d < 64; d <<= 1) { int y = __shfl_up(x, d, 64); if (lane >= d) x += y; }
  if (lane == 63) ws[wid] = x;
  __syncthreads();
  int add = 0;
#pragma unroll
  for (int k = 0; k < 4; ++k) if (k < wid) add += ws[k];
  if (tid < np) pp[tid] = x - v + add;
}

__global__ __launch_bounds__(256) void scan_final2(const int* __restrict__ cnt_g,
                                                   const int* __restrict__ cnt_k,
                                                   const int* __restrict__ part,
                                                   int* __restrict__ off_g,
                                                   int* __restrict__ off_k,
                                                   float* __restrict__ invg,
                                                   float* __restrict__ invk, int n) {
  const int* cnt = blockIdx.y ? cnt_k : cnt_g;
  const int* pp = part + blockIdx.y * 256;
  int* off = blockIdx.y ? off_k : off_g;
  float* inv = blockIdx.y ? invk : invg;
  int total = blockIdx.y ? EK : EG;
  int i = blockIdx.x * 256 + threadIdx.x;
  int v = (i < n) ? cnt[i] : 0;
  __shared__ int ws[4];
  int lane = threadIdx.x & 63, wid = threadIdx.x >> 6;
  int x = v;
#pragma unroll
  for (int d = 1; d < 64; d <<= 1) { int y = __shfl_up(x, d, 64); if (lane >= d) x += y; }
  if (lane == 63) ws[wid] = x;
  __syncthreads();
  int add = pp[blockIdx.x];
#pragma unroll
  for (int k = 0; k < 4; ++k) if (k < wid) add += ws[k];
  if (i < n) {
    off[i] = x - v + add;
    inv[i] = 1.0f / fmaxf((float)v, 1.0f);
  }
  if (i == 0) off[n] = total;
}

__global__ __launch_bounds__(256) void fill2(const int* __restrict__ g_src,
                                             const int* __restrict__ g_dst,
                                             const int* __restrict__ k_src,
                                             const int* __restrict__ k_dst,
                                             const int* __restrict__ off_g,
                                             const int* __restrict__ off_k,
                                             int* __restrict__ cur_g, int* __restrict__ cur_k,
                                             int* __restrict__ esrc_g,
                                             int* __restrict__ esrc_k) {
  int e = blockIdx.x * 256 + threadIdx.x;
  if (e < EG) {
    int d = g_dst[e];
    int pz = atomicAdd(&cur_g[d], 1);
    esrc_g[off_g[d] + pz] = g_src[e];
  } else if (e < EG + EK) {
    int e2 = e - EG;
    int d = k_dst[e2];
    int pz = atomicAdd(&cur_k[d], 1);
    esrc_k[off_k[d] + pz] = k_src[e2];
  }
}

// ---------------- CSR mean-aggregation (bf16 in/out), unroll-4 ----------------
template <int DLOG2>
__global__ __launch_bounds__(256) void csr_aggregate(const unsigned short* __restrict__ h,
                                                     const int* __restrict__ off,
                                                     const int* __restrict__ esrc,
                                                     const float* __restrict__ inv,
                                                     unsigned short* __restrict__ out) {
  constexpr int TPN = (1 << DLOG2) / 8;
  constexpr int NPB = 256 / TPN;
  int node = blockIdx.x * NPB + ((int)threadIdx.x / TPN);
  int lane = threadIdx.x & (TPN - 1);
  if (node >= NN) return;
  int s = off[node], e = off[node + 1];
  float acc[8] = {0.f, 0.f, 0.f, 0.f, 0.f, 0.f, 0.f, 0.f};
  int j = s;
  for (; j + 3 < e; j += 4) {
    int s0 = esrc[j], s1 = esrc[j + 1], s2 = esrc[j + 2], s3 = esrc[j + 3];
    ushort8 v0 = *reinterpret_cast<const ushort8*>(&h[((size_t)s0 << DLOG2) + lane * 8]);
    ushort8 v1 = *reinterpret_cast<const ushort8*>(&h[((size_t)s1 << DLOG2) + lane * 8]);
    ushort8 v2 = *reinterpret_cast<const ushort8*>(&h[((size_t)s2 << DLOG2) + lane * 8]);
    ushort8 v3 = *reinterpret_cast<const ushort8*>(&h[((size_t)s3 << DLOG2) + lane * 8]);
#pragma unroll
    for (int i = 0; i < 8; ++i) acc[i] += bf2f(v0[i]);
#pragma unroll
    for (int i = 0; i < 8; ++i) acc[i] += bf2f(v1[i]);
#pragma unroll
    for (int i = 0; i < 8; ++i) acc[i] += bf2f(v2[i]);
#pragma unroll
    for (int i = 0; i < 8; ++i) acc[i] += bf2f(v3[i]);
  }
  for (; j < e; ++j) {
    int s0 = esrc[j];
    ushort8 v0 = *reinterpret_cast<const ushort8*>(&h[((size_t)s0 << DLOG2) + lane * 8]);
#pragma unroll
    for (int i = 0; i < 8; ++i) acc[i] += bf2f(v0[i]);
  }
  float sc = inv[node];
  ushort8 o;
#pragma unroll
  for (int i = 0; i < 8; ++i) o[i] = f2bf(acc[i] * sc);
  *reinterpret_cast<ushort8*>(&out[((size_t)node << DLOG2) + lane * 8]) = o;
}

// ---------------- MFMA GEMM, BM=128 x BN=128, BK=64, global_load_lds staging ----------------
template <int K1, int K2, bool RELU, bool OUT_BF16>
__global__ __launch_bounds__(256) void gemm_gl(
    const unsigned short* __restrict__ A1, const unsigned short* __restrict__ A2,
    const unsigned short* __restrict__ Bt, const float* __restrict__ bias,
    void* __restrict__ outv, int ldo, int nrows) {
  constexpr int KTOT = K1 + K2;
  constexpr int KT = KTOT / 64;
  __shared__ char smem[32768];
  unsigned short* sA = (unsigned short*)smem;
  unsigned short* sB = sA + 8192;

  const int t = threadIdx.x;
  const int lane = t & 63;
  const int w = t >> 6;
  const int wm = (w & 1) * 64, wn = (w >> 1) * 64;
  const int row0 = blockIdx.y * 128;
  const int n0 = blockIdx.x * 128;

  const int srow = (w << 5) + (lane >> 3);
  const int schunk = (lane & 7) << 3;

  f32x4 acc[4][4] = {};

  for (int kt = 0; kt < KT; ++kt) {
    const int kbase = kt * 64;
    const unsigned short* Asrc = (kbase < K1) ? A1 : A2;
    const int kA = (kbase < K1) ? kbase : (kbase - K1);
    const int lda = (kbase < K1) ? K1 : K2;
#pragma unroll
    for (int q = 0; q < 4; ++q) {
      int rA = srow + q * 8;
      int rowg = row0 + rA;
      if (rowg >= nrows) rowg = nrows - 1;
      gload_lds16(Asrc + (size_t)rowg * lda + kA + schunk,
                  sA + ((w << 5) + q * 8) * 64);
      gload_lds16(Bt + (size_t)(n0 + rA) * KTOT + kbase + schunk,
                  sB + ((w << 5) + q * 8) * 64);
    }
    __syncthreads();
#pragma unroll
    for (int kk = 0; kk < 2; ++kk) {
      const int ko = kk * 32 + (lane >> 4) * 8;
      short8 a[4], b[4];
#pragma unroll
      for (int mi = 0; mi < 4; ++mi)
        a[mi] = *reinterpret_cast<const short8*>(&sA[(wm + mi * 16 + (lane & 15)) * 64 + ko]);
#pragma unroll
      for (int ni = 0; ni < 4; ++ni)
        b[ni] = *reinterpret_cast<const short8*>(&sB[(wn + ni * 16 + (lane & 15)) * 64 + ko]);
#pragma unroll
      for (int mi = 0; mi < 4; ++mi)
#pragma unroll
        for (int ni = 0; ni < 4; ++ni)
          acc[mi][ni] = __builtin_amdgcn_mfma_f32_16x16x32_bf16(a[mi], b[ni], acc[mi][ni], 0, 0, 0);
    }
    __syncthreads();
  }

  float* Co = (float*)smem;
#pragma unroll
  for (int h = 0; h < 2; ++h) {
    __syncthreads();
    if ((w >> 1) == h) {
#pragma unroll
      for (int mi = 0; mi < 4; ++mi)
#pragma unroll
        for (int ni = 0; ni < 4; ++ni) {
          int col = ni * 16 + (lane & 15);
          int rowb = wm + mi * 16 + (lane >> 4) * 4;
#pragma unroll
          for (int j = 0; j < 4; ++j) Co[(rowb + j) * 64 + col] = acc[mi][ni][j];
        }
    }
    __syncthreads();
    int sr = t >> 1, cb = (t & 1) * 32;
    int r = row0 + sr;
    if (r < nrows) {
      float v[32];
#pragma unroll
      for (int i = 0; i < 32; ++i) {
        v[i] = Co[sr * 64 + cb + i] + bias[n0 + h * 64 + cb + i];
        if (RELU) v[i] = fmaxf(v[i], 0.f);
      }
      if (OUT_BF16) {
        unsigned short* dst = (unsigned short*)outv + (size_t)r * ldo + n0 + h * 64 + cb;
#pragma unroll
        for (int q = 0; q < 4; ++q) {
          ushort8 o;
#pragma unroll
          for (int i = 0; i < 8; ++i) o[i] = f2bf(v[q * 8 + i]);
          *reinterpret_cast<ushort8*>(dst + q * 8) = o;
        }
      } else {
        float* dst = (float*)outv + (size_t)r * ldo + n0 + h * 64 + cb;
#pragma unroll
        for (int q = 0; q < 8; ++q) {
          float4 o = make_float4(v[4 * q], v[4 * q + 1], v[4 * q + 2], v[4 * q + 3]);
          *reinterpret_cast<float4*>(dst + 4 * q) = o;
        }
      }
    }
  }
}

// ---------------- fused tail GEMM: 4 x K=256 A-segments, N=128, f32 out ----------------
__global__ __launch_bounds__(256) void gemm_gl4(
    const unsigned short* __restrict__ A0, const unsigned short* __restrict__ A1,
    const unsigned short* __restrict__ A2, const unsigned short* __restrict__ A3,
    const unsigned short* __restrict__ Bt, const float* __restrict__ bias,
    float* __restrict__ outv, int nrows) {
  constexpr int KTOT = 1024;
  constexpr int KT = 16;
  __shared__ char smem[32768];
  unsigned short* sA = (unsigned short*)smem;
  unsigned short* sB = sA + 8192;

  const int t = threadIdx.x;
  const int lane = t & 63;
  const int w = t >> 6;
  const int wm = (w & 1) * 64, wn = (w >> 1) * 64;
  const int row0 = blockIdx.y * 128;

  const int srow = (w << 5) + (lane >> 3);
  const int schunk = (lane & 7) << 3;

  f32x4 acc[4][4] = {};

  for (int kt = 0; kt < KT; ++kt) {
    const int seg = kt >> 2;
    const unsigned short* Asrc = (seg == 0) ? A0 : (seg == 1) ? A1 : (seg == 2) ? A2 : A3;
    const int kA = (kt & 3) * 64;
#pragma unroll
    for (int q = 0; q < 4; ++q) {
      int rA = srow + q * 8;
      int rowg = row0 + rA;
      if (rowg >= nrows) rowg = nrows - 1;
      gload_lds16(Asrc + (size_t)rowg * 256 + kA + schunk,
                  sA + ((w << 5) + q * 8) * 64);
      gload_lds16(Bt + (size_t)rA * KTOT + kt * 64 + schunk,
                  sB + ((w << 5) + q * 8) * 64);
    }
    __syncthreads();
#pragma unroll
    for (int kk = 0; kk < 2; ++kk) {
      const int ko = kk * 32 + (lane >> 4) * 8;
      short8 a[4], b[4];
#pragma unroll
      for (int mi = 0; mi < 4; ++mi)
        a[mi] = *reinterpret_cast<const short8*>(&sA[(wm + mi * 16 + (lane & 15)) * 64 + ko]);
#pragma unroll
      for (int ni = 0; ni < 4; ++ni)
        b[ni] = *reinterpret_cast<const short8*>(&sB[(wn + ni * 16 + (lane & 15)) * 64 + ko]);
#pragma unroll
      for (int mi = 0; mi < 4; ++mi)
#pragma unroll
        for (int ni = 0; ni < 4; ++ni)
          acc[mi][ni] = __builtin_amdgcn_mfma_f32_16x16x32_bf16(a[mi], b[ni], acc[mi][ni], 0, 0, 0);
    }
    __syncthreads();
  }

  float* Co = (float*)smem;
#pragma unroll
  for (int h = 0; h < 2; ++h) {
    __syncthreads();
    if ((w >> 1) == h) {
#pragma unroll
      for (int mi = 0; mi < 4; ++mi)
#pragma unroll
        for (int ni = 0; ni < 4; ++ni) {
          int col = ni * 16 + (lane & 15);
          int rowb = wm + mi * 16 + (lane >> 4) * 4;
#pragma unroll
          for (int j = 0; j < 4; ++j) Co[(rowb + j) * 64 + col] = acc[mi][ni][j];
        }
    }
    __syncthreads();
    int sr = t >> 1, cb = (t & 1) * 32;
    int r = row0 + sr;
    if (r < nrows) {
      float* dst = outv + (size_t)r * MLPH + h * 64 + cb;
#pragma unroll
      for (int q = 0; q < 8; ++q) {
        float4 o;
        o.x = Co[sr * 64 + cb + 4 * q + 0] + bias[h * 64 + cb + 4 * q + 0];
        o.y = Co[sr * 64 + cb + 4 * q + 1] + bias[h * 64 + cb + 4 * q + 1];
        o.z = Co[sr * 64 + cb + 4 * q + 2] + bias[h * 64 + cb + 4 * q + 2];
        o.w = Co[sr * 64 + cb + 4 * q + 3] + bias[h * 64 + cb + 4 * q + 3];
        *reinterpret_cast<float4*>(dst + 4 * q) = o;
      }
    }
  }
}

// ---------------- BN ----------------
__global__ __launch_bounds__(256) void bn_stats_kernel(const float* __restrict__ x,
                                                       float* __restrict__ sums,
                                                       float* __restrict__ sumsq) {
  int c = threadIdx.x & 127;
  int rbase = (blockIdx.x * 256 + threadIdx.x) >> 7;
  int stride = (gridDim.x * 256) >> 7;
  float s = 0.f, s2 = 0.f;
  for (int r = rbase; r < NN; r += stride) {
    float v = x[(size_t)r * 128 + c];
    s += v;
    s2 += v * v;
  }
  __shared__ float ls[256], ls2[256];
  ls[threadIdx.x] = s;
  ls2[threadIdx.x] = s2;
  __syncthreads();
  if (threadIdx.x < 128) {
    s = ls[threadIdx.x] + ls[threadIdx.x + 128];
    s2 = ls2[threadIdx.x] + ls2[threadIdx.x + 128];
    atomicAdd(&sums[c], s);
    atomicAdd(&sumsq[c], s2);
  }
}

__global__ __launch_bounds__(128) void bn_finalize_kernel(float* __restrict__ stats,
                                                          const float* __restrict__ gamma,
                                                          const float* __restrict__ beta) {
  int c = threadIdx.x;
  float mu = stats[c] * (1.0f / NN);
  float var = stats[128 + c] * (1.0f / NN) - mu * mu;
  var = fmaxf(var, 0.f);
  float sc = gamma[c] * rsqrtf(var + BN_EPS);
  stats[256 + c] = sc;
  stats[384 + c] = beta[c] - mu * sc;
}

// ---------------- final head GEMM with fused BN+ReLU on A-load (64x64) ----------------
template <int K1, bool RELU>
__global__ __launch_bounds__(256) void gemm_mfma_bn(
    const float* __restrict__ A1v, const unsigned short* __restrict__ Bt,
    const float* __restrict__ bias, const float* __restrict__ bnscale,
    const float* __restrict__ bnshift, float* __restrict__ outv, int ldo, int nrows) {
  constexpr int KT = K1 / 64;
  constexpr int LDT = 72;
  __shared__ char smem[2 * 64 * LDT * 2];
  unsigned short* As = (unsigned short*)smem;
  unsigned short* Bs = As + 64 * LDT;
  float* Co = (float*)smem;
  constexpr int LDC = 68;

  const int t = threadIdx.x;
  const int lane = t & 63;
  const int w = t >> 6;
  const int wm = (w & 1) * 32, wn = (w >> 1) * 32;
  const int row0 = blockIdx.y * 64;
  const int n0 = blockIdx.x * 64;

  const int sr = t >> 2;
  const int skc = (t & 3) * 16;
  int rg = row0 + sr;
  if (rg >= nrows) rg = nrows - 1;

  f32x4 acc[2][2] = {};

  for (int kt = 0; kt < KT; ++kt) {
    const int kbase = kt * 64;
    {
      const float* xb = A1v + (size_t)rg * K1 + kbase + skc;
      ushort8 o0, o1;
#pragma unroll
      for (int i = 0; i < 8; ++i) {
        float v = xb[i] * bnscale[kbase + skc + i] + bnshift[kbase + skc + i];
        o0[i] = f2bf(fmaxf(v, 0.f));
      }
#pragma unroll
      for (int i = 0; i < 8; ++i) {
        float v = xb[8 + i] * bnscale[kbase + skc + 8 + i] + bnshift[kbase + skc + 8 + i];
        o1[i] = f2bf(fmaxf(v, 0.f));
      }
      *reinterpret_cast<ushort8*>(&As[sr * LDT + skc]) = o0;
      *reinterpret_cast<ushort8*>(&As[sr * LDT + skc + 8]) = o1;
    }
    {
      const unsigned short* bb = Bt + (size_t)(n0 + sr) * K1 + kbase + skc;
      int4 p0 = *reinterpret_cast<const int4*>(bb);
      int4 p1 = *reinterpret_cast<const int4*>(bb + 8);
      *reinterpret_cast<int4*>(&Bs[sr * LDT + skc]) = p0;
      *reinterpret_cast<int4*>(&Bs[sr * LDT + skc + 8]) = p1;
    }
    __syncthreads();
#pragma unroll
    for (int kk = 0; kk < 2; ++kk) {
      const int ko = kk * 32 + (lane >> 4) * 8;
      short8 a0 = *reinterpret_cast<const short8*>(&As[(wm + (lane & 15)) * LDT + ko]);
      short8 a1 = *reinterpret_cast<const short8*>(&As[(wm + 16 + (lane & 15)) * LDT + ko]);
      short8 b0 = *reinterpret_cast<const short8*>(&Bs[(wn + (lane & 15)) * LDT + ko]);
      short8 b1 = *reinterpret_cast<const short8*>(&Bs[(wn + 16 + (lane & 15)) * LDT + ko]);
      acc[0][0] = __builtin_amdgcn_mfma_f32_16x16x32_bf16(a0, b0, acc[0][0], 0, 0, 0);
      acc[0][1] = __builtin_amdgcn_mfma_f32_16x16x32_bf16(a0, b1, acc[0][1], 0, 0, 0);
      acc[1][0] = __builtin_amdgcn_mfma_f32_16x16x32_bf16(a1, b0, acc[1][0], 0, 0, 0);
      acc[1][1] = __builtin_amdgcn_mfma_f32_16x16x32_bf16(a1, b1, acc[1][1], 0, 0, 0);
    }
    __syncthreads();
  }

#pragma unroll
  for (int mi = 0; mi < 2; ++mi)
#pragma unroll
    for (int ni = 0; ni < 2; ++ni) {
      int col = wn + ni * 16 + (lane & 15);
      int rowb = wm + mi * 16 + (lane >> 4) * 4;
#pragma unroll
      for (int j = 0; j < 4; ++j) Co[(rowb + j) * LDC + col] = acc[mi][ni][j];
    }
  __syncthreads();
  {
    int r = row0 + sr;
    if (r < nrows) {
      float v[16];
#pragma unroll
      for (int i = 0; i < 16; ++i) {
        v[i] = Co[sr * LDC + skc + i] + bias[n0 + skc + i];
        if (RELU) v[i] = fmaxf(v[i], 0.f);
      }
      float* dst = outv + (size_t)r * ldo + n0 + skc;
#pragma unroll
      for (int i = 0; i < 4; ++i) {
        float4 o = make_float4(v[4 * i], v[4 * i + 1], v[4 * i + 2], v[4 * i + 3]);
        *reinterpret_cast<float4*>(dst + 4 * i) = o;
      }
    }
  }
}

// ---------------- launch ----------------
extern "C" void kernel_launch(void* const* d_in, const int* in_sizes, int n_in,
                              void* d_out, int out_size, void* d_ws, size_t ws_size,
                              hipStream_t stream) {
  const float* feat = (const float*)d_in[0];
  const int* g_src = (const int*)d_in[1];
  const int* g_dst = (const int*)d_in[2];
  const int* k_src = (const int*)d_in[3];
  const int* k_dst = (const int*)d_in[4];
  const float* lb_0 = (const float*)d_in[7];
  const float* lb_1 = (const float*)d_in[10];
  const float* lb_2 = (const float*)d_in[13];
  const float* gb_0 = (const float*)d_in[16];
  const float* gb_1 = (const float*)d_in[19];
  const float* mlp_b1 = (const float*)d_in[21];
  const float* bn_gamma = (const float*)d_in[22];
  const float* bn_beta = (const float*)d_in[23];
  const float* mlp_b2 = (const float*)d_in[25];
  float* out = (float*)d_out;

  // workspace layout
  float* xf32 = (float*)d_ws;                         // N*128 f32
  int* cnt_g = (int*)(xf32 + (size_t)NN * 128);       // N
  int* cnt_k = cnt_g + NN;                            // N
  int* cur_g = cnt_k + NN;                            // N
  int* cur_k = cur_g + NN;                            // N
  float* stats = (float*)(cur_k + NN);                // 512 (zeroed with cnt/cur)
  float* invg = stats + 512;                          // N
  float* invk = invg + NN;                            // N
  int* off_g = (int*)(invk + NN);                     // N+4
  int* off_k = off_g + NN + 4;                        // N+4
  int* part = off_k + NN + 4;                         // 512
  int* esrc_g = part + 512;                           // EG
  int* esrc_k = esrc_g + EG;                          // EK
  unsigned short* featbf = (unsigned short*)(esrc_k + EK);  // N*128
  unsigned short* wts = featbf + (size_t)NN * IN_F;         // 598016
  unsigned short* wf = wts + 598016;                  // 131072 (fused head weights)
  float* bfused = (float*)(wf + 131072);              // 128
  unsigned short* bfA = (unsigned short*)(bfused + 128);  // N*256
  unsigned short* bfB = bfA + (size_t)NN * HF;        // N*256
  unsigned short* bfAgg = bfB + (size_t)NN * HF;      // N*256
  unsigned short* bfD = bfAgg + (size_t)NN * HF;      // N*256

  const int wL0 = 0, wL1 = 65536, wG0 = 327680, wH2 = 589824;

  dim3 blk(256);
  const int NB = (NN + 255) / 256;        // 196
  const int MB = (NN + 127) / 128;        // 391
  const dim3 gridH(2, MB);                // 256-col out, BM=128 BN=128
  const dim3 grid4(1, MB);                // fused tail: N=128, one col-block
  const int agg128_blocks = (NN + 15) / 16;
  const int agg256_blocks = (NN + 7) / 8;

  // zero cnt_g, cnt_k, cur_g, cur_k, stats in one go
  hipMemsetAsync(cnt_g, 0, (size_t)(4 * NN) * sizeof(int) + 512 * sizeof(float), stream);

  WPack p;
  p.d[0] = {(const float*)d_in[5], 128, 8, 0, 256, wL0};
  p.d[1] = {(const float*)d_in[6], 128, 8, 128, 256, wL0};
  p.d[2] = {(const float*)d_in[8], 256, 8, 0, 512, wL1};
  p.d[3] = {(const float*)d_in[9], 256, 8, 256, 512, wL1};
  p.d[4] = {(const float*)d_in[11], 256, 8, 0, 512, 196608};  // unused (folded), kept for layout
  p.d[5] = {(const float*)d_in[12], 256, 8, 256, 512, 196608};
  p.d[6] = {(const float*)d_in[14], 128, 8, 0, 256, wG0};
  p.d[7] = {(const float*)d_in[15], 128, 8, 128, 256, wG0};
  p.d[8] = {(const float*)d_in[17], 256, 8, 0, 512, 393216};  // unused (folded)
  p.d[9] = {(const float*)d_in[18], 256, 8, 256, 512, 393216};
  p.d[10] = {(const float*)d_in[20], 512, 7, 0, 512, 524288}; // unused (folded)
  p.d[11] = {(const float*)d_in[24], 128, 6, 0, 128, wH2};
  prep_kernel<<<8979, blk, 0, stream>>>(feat, featbf, p, wts, g_dst, k_dst, cnt_g, cnt_k);

  // fused head weights: wf[128][1024], bfused[128]
  fuse_w_kernel<<<1025, 128, 0, stream>>>(
      (const float*)d_in[11], (const float*)d_in[12],
      (const float*)d_in[17], (const float*)d_in[18],
      mlp_b1 - 0 + 0 == nullptr ? nullptr : (const float*)d_in[20],  // w1
      lb_2, gb_1, mlp_b1, wf, bfused);

  scan_partial2<<<dim3(NB, 2), blk, 0, stream>>>(cnt_g, cnt_k, part, NN);
  scan_block2<<<2, blk, 0, stream>>>(part, NB);
  scan_final2<<<dim3(NB, 2), blk, 0, stream>>>(cnt_g, cnt_k, part, off_g, off_k, invg, invk, NN);
  fill2<<<(EG + EK + 255) / 256, blk, 0, stream>>>(g_src, g_dst, k_src, k_dst, off_g, off_k,
                                                   cur_g, cur_k, esrc_g, esrc_k);

  // ---- local layer 0: h_l0 = relu([feat|agg] @ WL0) ----
  csr_aggregate<7><<<agg128_blocks, blk, 0, stream>>>(featbf, off_g, esrc_g, invg, bfAgg);
  gemm_gl<128, 128, true, true><<<gridH, blk, 0, stream>>>(
      featbf, bfAgg, wts + wL0, lb_0, bfA, HF, NN);
  // ---- local layer 1: h_l1 = relu([h_l0|agg] @ WL1) ----
  csr_aggregate<8><<<agg256_blocks, blk, 0, stream>>>(bfA, off_g, esrc_g, invg, bfAgg);
  gemm_gl<256, 256, true, true><<<gridH, blk, 0, stream>>>(
      bfA, bfAgg, wts + wL1, lb_1, bfB, HF, NN);
  // ---- agg for (folded) local layer 2: aggL2 = mean_g(h_l1) -> bfD ----
  csr_aggregate<8><<<agg256_blocks, blk, 0, stream>>>(bfB, off_g, esrc_g, invg, bfD);
  // ---- global layer 0: h_g0 = relu([feat|agg] @ WG0) -> bfA (h_l0 dead) ----
  csr_aggregate<7><<<agg128_blocks, blk, 0, stream>>>(featbf, off_k, esrc_k, invk, bfAgg);
  gemm_gl<128, 128, true, true><<<gridH, blk, 0, stream>>>(
      featbf, bfAgg, wts + wG0, gb_0, bfA, HF, NN);
  // ---- agg for (folded) global layer 1: aggG1 = mean_k(h_g0) -> bfAgg ----
  csr_aggregate<8><<<agg256_blocks, blk, 0, stream>>>(bfA, off_k, esrc_k, invk, bfAgg);

  // ---- fused tail: x = h_l1@Wf0 + aggL2@Wf1 + h_g0@Wf2 + aggG1@Wf3 + bfused ----
  gemm_gl4<<<grid4, blk, 0, stream>>>(bfB, bfD, bfA, bfAgg, wf, bfused, xf32, NN);

  // ---- BatchNorm ----
  bn_stats_kernel<<<256, blk, 0, stream>>>(xf32, stats, stats + 128);
  bn_finalize_kernel<<<1, 128, 0, stream>>>(stats, bn_gamma, bn_beta);

  // ---- head GEMM2: out = relu(bn(x)) @ w2 + b2 ----
  gemm_mfma_bn<128, false><<<dim3(1, (NN + 63) / 64), blk, 0, stream>>>(
      xf32, wts + wH2, mlp_b2, stats + 256, stats + 384, out, COUT, NN);
}

// Round 9
// 567.917 us; speedup vs baseline: 1.1976x; 1.0276x over previous
//
#include <hip/hip_runtime.h>

#define NN   50000
#define IN_F 128
#define HF   256
#define COUT 64
#define MLPH 128
#define EG   600000
#define EK   800000
#define BN_EPS 1e-5f

typedef __attribute__((ext_vector_type(8))) short short8;
typedef __attribute__((ext_vector_type(8))) unsigned short ushort8;
typedef __attribute__((ext_vector_type(4))) float f32x4;

__device__ __forceinline__ unsigned short f2bf(float f) {
  union { float f; unsigned int u; } v; v.f = f;
  unsigned int r = v.u + 0x7FFFu + ((v.u >> 16) & 1u);
  return (unsigned short)(r >> 16);
}
__device__ __forceinline__ float bf2f(unsigned short s) {
  union { unsigned int u; float f; } v; v.u = ((unsigned int)s) << 16;
  return v.f;
}

// async global->LDS, 16B per lane; LDS dest must be wave-uniform base
__device__ __forceinline__ void gload_lds16(const void* g, void* l) {
  __builtin_amdgcn_global_load_lds((const __attribute__((address_space(1))) void*)g,
                                   (__attribute__((address_space(3))) void*)l, 16, 0, 0);
}

struct WDesc { const float* src; int rows; int cshift; int kofs; int ldk; int dofs; };
struct WPack { WDesc d[12]; };

// ---------------- prep: feat->bf16, weight transpose, degree counts ----------------
__global__ __launch_bounds__(256) void prep_kernel(const float* __restrict__ feat,
                                                   unsigned short* __restrict__ featbf,
                                                   WPack p, unsigned short* __restrict__ wts,
                                                   const int* __restrict__ g_dst,
                                                   const int* __restrict__ k_dst,
                                                   int* __restrict__ cnt_g,
                                                   int* __restrict__ cnt_k) {
  int b = blockIdx.x;
  if (b < 3126) {
    int i = b * 256 + threadIdx.x;
    if (i < NN * IN_F / 8) {
      float4 a = *reinterpret_cast<const float4*>(&feat[i * 8]);
      float4 c = *reinterpret_cast<const float4*>(&feat[i * 8 + 4]);
      ushort8 o;
      o[0] = f2bf(a.x); o[1] = f2bf(a.y); o[2] = f2bf(a.z); o[3] = f2bf(a.w);
      o[4] = f2bf(c.x); o[5] = f2bf(c.y); o[6] = f2bf(c.z); o[7] = f2bf(c.w);
      *reinterpret_cast<ushort8*>(&featbf[i * 8]) = o;
    }
  } else if (b < 3510) {
    int wb = b - 3126;
    WDesc w = p.d[wb >> 5];
    int xb = wb & 31;
    int total = w.rows << w.cshift;
    int cmask = (1 << w.cshift) - 1;
    for (int idx = xb * 256 + threadIdx.x; idx < total; idx += 32 * 256) {
      int r = idx >> w.cshift, c = idx & cmask;
      wts[w.dofs + (size_t)c * w.ldk + w.kofs + r] = f2bf(w.src[idx]);
    }
  } else {
    int e = (b - 3510) * 256 + threadIdx.x;
    if (e < EG) atomicAdd(&cnt_g[g_dst[e]], 1);
    else if (e < EG + EK) atomicAdd(&cnt_k[k_dst[e - EG]], 1);
  }
}

// ---------------- fused head weights: wf[c][seg*256+i] = sum_o Wseg[i,o] * w1[segbase+o, c]
__global__ __launch_bounds__(128) void fuse_w_kernel(
    const float* __restrict__ wl2s, const float* __restrict__ wl2n,
    const float* __restrict__ wg1s, const float* __restrict__ wg1n,
    const float* __restrict__ w1, const float* __restrict__ bl2,
    const float* __restrict__ bg1, const float* __restrict__ b1,
    unsigned short* __restrict__ wf, float* __restrict__ bfused) {
  int b = blockIdx.x;
  int c = threadIdx.x;  // 0..127
  __shared__ float row[256];
  if (b < 1024) {
    int seg = b >> 8, i = b & 255;
    const float* W = (seg == 0) ? wl2s : (seg == 1) ? wl2n : (seg == 2) ? wg1s : wg1n;
    const float* w1b = w1 + ((seg < 2) ? 0 : 256) * MLPH;
    row[c] = W[i * 256 + c];
    row[c + 128] = W[i * 256 + 128 + c];
    __syncthreads();
    float acc = 0.f;
    for (int o = 0; o < 256; ++o) acc += row[o] * w1b[o * MLPH + c];
    wf[(size_t)c * 1024 + seg * 256 + i] = f2bf(acc);
  } else {
    float acc = b1[c];
    for (int o = 0; o < 256; ++o) acc += bl2[o] * w1[o * MLPH + c];
    for (int o = 0; o < 256; ++o) acc += bg1[o] * w1[(256 + o) * MLPH + c];
    bfused[c] = acc;
  }
}

// ---------------- parallel scans for both graphs ----------------
__global__ __launch_bounds__(256) void scan_partial2(const int* __restrict__ cnt_g,
                                                     const int* __restrict__ cnt_k,
                                                     int* __restrict__ part, int n) {
  const int* cnt = blockIdx.y ? cnt_k : cnt_g;
  int* pp = part + blockIdx.y * 256;
  int i = blockIdx.x * 256 + threadIdx.x;
  int v = (i < n) ? cnt[i] : 0;
  __shared__ int ws[4];
  int lane = threadIdx.x & 63, wid = threadIdx.x >> 6;
  int x = v;
#pragma unroll
  for (int d = 1; d < 64; d <<= 1) { int y = __shfl_up(x, d, 64); if (lane >= d) x += y; }
  if (lane == 63) ws[wid] = x;
  __syncthreads();
  if (threadIdx.x == 0) pp[blockIdx.x] = ws[0] + ws[1] + ws[2] + ws[3];
}

__global__ __launch_bounds__(256) void scan_block2(int* __restrict__ part, int np) {
  int* pp = part + blockIdx.x * 256;
  __shared__ int ws[4];
  int tid = threadIdx.x, lane = tid & 63, wid = tid >> 6;
  int v = (tid < np) ? pp[tid] : 0;
  int x = v;
#pragma unroll
  for (int d = 1; d < 64; d <<= 1) { int y = __shfl_up(x, d, 64); if (lane >= d) x += y; }
  if (lane == 63) ws[wid] = x;
  __syncthreads();
  int add = 0;
#pragma unroll
  for (int k = 0; k < 4; ++k) if (k < wid) add += ws[k];
  if (tid < np) pp[tid] = x - v + add;
}

__global__ __launch_bounds__(256) void scan_final2(const int* __restrict__ cnt_g,
                                                   const int* __restrict__ cnt_k,
                                                   const int* __restrict__ part,
                                                   int* __restrict__ off_g,
                                                   int* __restrict__ off_k,
                                                   float* __restrict__ invg,
                                                   float* __restrict__ invk, int n) {
  const int* cnt = blockIdx.y ? cnt_k : cnt_g;
  const int* pp = part + blockIdx.y * 256;
  int* off = blockIdx.y ? off_k : off_g;
  float* inv = blockIdx.y ? invk : invg;
  int total = blockIdx.y ? EK : EG;
  int i = blockIdx.x * 256 + threadIdx.x;
  int v = (i < n) ? cnt[i] : 0;
  __shared__ int ws[4];
  int lane = threadIdx.x & 63, wid = threadIdx.x >> 6;
  int x = v;
#pragma unroll
  for (int d = 1; d < 64; d <<= 1) { int y = __shfl_up(x, d, 64); if (lane >= d) x += y; }
  if (lane == 63) ws[wid] = x;
  __syncthreads();
  int add = pp[blockIdx.x];
#pragma unroll
  for (int k = 0; k < 4; ++k) if (k < wid) add += ws[k];
  if (i < n) {
    off[i] = x - v + add;
    inv[i] = 1.0f / fmaxf((float)v, 1.0f);
  }
  if (i == 0) off[n] = total;
}

// ---------------- XCD-range-partitioned CSR fill ----------------
// range r = blockIdx.x & 7 (round-robin block->XCD => one dst-range per XCD);
// each block scans an edge chunk, scattering only edges whose dst is in-range.
__global__ __launch_bounds__(256) void fill3(const int* __restrict__ g_src,
                                             const int* __restrict__ g_dst,
                                             const int* __restrict__ k_src,
                                             const int* __restrict__ k_dst,
                                             const int* __restrict__ off_g,
                                             const int* __restrict__ off_k,
                                             int* __restrict__ cur_g, int* __restrict__ cur_k,
                                             int* __restrict__ esrc_g,
                                             int* __restrict__ esrc_k, int nchunks) {
  const int r = blockIdx.x & 7;
  const int c = blockIdx.x >> 3;
  const int lo = r * (NN / 8);
  const int hi = (r == 7) ? NN : lo + (NN / 8);
  const int TOT = EG + EK;
  const int chunk = (TOT + nchunks - 1) / nchunks;
  const int e0 = c * chunk;
  int e1 = e0 + chunk;
  if (e1 > TOT) e1 = TOT;
  for (int e = e0 + (int)threadIdx.x; e < e1; e += 256) {
    if (e < EG) {
      int d = g_dst[e];
      if (d >= lo && d < hi) {
        int pz = atomicAdd(&cur_g[d], 1);
        esrc_g[off_g[d] + pz] = g_src[e];
      }
    } else {
      int e2 = e - EG;
      int d = k_dst[e2];
      if (d >= lo && d < hi) {
        int pz = atomicAdd(&cur_k[d], 1);
        esrc_k[off_k[d] + pz] = k_src[e2];
      }
    }
  }
}

// ---------------- CSR mean-aggregation (bf16 in/out), unroll-4 ----------------
template <int DLOG2>
__global__ __launch_bounds__(256) void csr_aggregate(const unsigned short* __restrict__ h,
                                                     const int* __restrict__ off,
                                                     const int* __restrict__ esrc,
                                                     const float* __restrict__ inv,
                                                     unsigned short* __restrict__ out) {
  constexpr int TPN = (1 << DLOG2) / 8;
  constexpr int NPB = 256 / TPN;
  int node = blockIdx.x * NPB + ((int)threadIdx.x / TPN);
  int lane = threadIdx.x & (TPN - 1);
  if (node >= NN) return;
  int s = off[node], e = off[node + 1];
  float acc[8] = {0.f, 0.f, 0.f, 0.f, 0.f, 0.f, 0.f, 0.f};
  int j = s;
  for (; j + 3 < e; j += 4) {
    int s0 = esrc[j], s1 = esrc[j + 1], s2 = esrc[j + 2], s3 = esrc[j + 3];
    ushort8 v0 = *reinterpret_cast<const ushort8*>(&h[((size_t)s0 << DLOG2) + lane * 8]);
    ushort8 v1 = *reinterpret_cast<const ushort8*>(&h[((size_t)s1 << DLOG2) + lane * 8]);
    ushort8 v2 = *reinterpret_cast<const ushort8*>(&h[((size_t)s2 << DLOG2) + lane * 8]);
    ushort8 v3 = *reinterpret_cast<const ushort8*>(&h[((size_t)s3 << DLOG2) + lane * 8]);
#pragma unroll
    for (int i = 0; i < 8; ++i) acc[i] += bf2f(v0[i]);
#pragma unroll
    for (int i = 0; i < 8; ++i) acc[i] += bf2f(v1[i]);
#pragma unroll
    for (int i = 0; i < 8; ++i) acc[i] += bf2f(v2[i]);
#pragma unroll
    for (int i = 0; i < 8; ++i) acc[i] += bf2f(v3[i]);
  }
  for (; j < e; ++j) {
    int s0 = esrc[j];
    ushort8 v0 = *reinterpret_cast<const ushort8*>(&h[((size_t)s0 << DLOG2) + lane * 8]);
#pragma unroll
    for (int i = 0; i < 8; ++i) acc[i] += bf2f(v0[i]);
  }
  float sc = inv[node];
  ushort8 o;
#pragma unroll
  for (int i = 0; i < 8; ++i) o[i] = f2bf(acc[i] * sc);
  *reinterpret_cast<ushort8*>(&out[((size_t)node << DLOG2) + lane * 8]) = o;
}

// ---------------- MFMA GEMM, BM=128 x BN=128, BK=64, global_load_lds staging ----------------
template <int K1, int K2, bool RELU, bool OUT_BF16>
__global__ __launch_bounds__(256) void gemm_gl(
    const unsigned short* __restrict__ A1, const unsigned short* __restrict__ A2,
    const unsigned short* __restrict__ Bt, const float* __restrict__ bias,
    void* __restrict__ outv, int ldo, int nrows) {
  constexpr int KTOT = K1 + K2;
  constexpr int KT = KTOT / 64;
  __shared__ char smem[32768];
  unsigned short* sA = (unsigned short*)smem;
  unsigned short* sB = sA + 8192;

  const int t = threadIdx.x;
  const int lane = t & 63;
  const int w = t >> 6;
  const int wm = (w & 1) * 64, wn = (w >> 1) * 64;
  const int row0 = blockIdx.y * 128;
  const int n0 = blockIdx.x * 128;

  const int srow = (w << 5) + (lane >> 3);
  const int schunk = (lane & 7) << 3;

  f32x4 acc[4][4] = {};

  for (int kt = 0; kt < KT; ++kt) {
    const int kbase = kt * 64;
    const unsigned short* Asrc = (kbase < K1) ? A1 : A2;
    const int kA = (kbase < K1) ? kbase : (kbase - K1);
    const int lda = (kbase < K1) ? K1 : K2;
#pragma unroll
    for (int q = 0; q < 4; ++q) {
      int rA = srow + q * 8;
      int rowg = row0 + rA;
      if (rowg >= nrows) rowg = nrows - 1;
      gload_lds16(Asrc + (size_t)rowg * lda + kA + schunk,
                  sA + ((w << 5) + q * 8) * 64);
      gload_lds16(Bt + (size_t)(n0 + rA) * KTOT + kbase + schunk,
                  sB + ((w << 5) + q * 8) * 64);
    }
    __syncthreads();
#pragma unroll
    for (int kk = 0; kk < 2; ++kk) {
      const int ko = kk * 32 + (lane >> 4) * 8;
      short8 a[4], b[4];
#pragma unroll
      for (int mi = 0; mi < 4; ++mi)
        a[mi] = *reinterpret_cast<const short8*>(&sA[(wm + mi * 16 + (lane & 15)) * 64 + ko]);
#pragma unroll
      for (int ni = 0; ni < 4; ++ni)
        b[ni] = *reinterpret_cast<const short8*>(&sB[(wn + ni * 16 + (lane & 15)) * 64 + ko]);
#pragma unroll
      for (int mi = 0; mi < 4; ++mi)
#pragma unroll
        for (int ni = 0; ni < 4; ++ni)
          acc[mi][ni] = __builtin_amdgcn_mfma_f32_16x16x32_bf16(a[mi], b[ni], acc[mi][ni], 0, 0, 0);
    }
    __syncthreads();
  }

  float* Co = (float*)smem;
#pragma unroll
  for (int h = 0; h < 2; ++h) {
    __syncthreads();
    if ((w >> 1) == h) {
#pragma unroll
      for (int mi = 0; mi < 4; ++mi)
#pragma unroll
        for (int ni = 0; ni < 4; ++ni) {
          int col = ni * 16 + (lane & 15);
          int rowb = wm + mi * 16 + (lane >> 4) * 4;
#pragma unroll
          for (int j = 0; j < 4; ++j) Co[(rowb + j) * 64 + col] = acc[mi][ni][j];
        }
    }
    __syncthreads();
    int sr = t >> 1, cb = (t & 1) * 32;
    int r = row0 + sr;
    if (r < nrows) {
      float v[32];
#pragma unroll
      for (int i = 0; i < 32; ++i) {
        v[i] = Co[sr * 64 + cb + i] + bias[n0 + h * 64 + cb + i];
        if (RELU) v[i] = fmaxf(v[i], 0.f);
      }
      if (OUT_BF16) {
        unsigned short* dst = (unsigned short*)outv + (size_t)r * ldo + n0 + h * 64 + cb;
#pragma unroll
        for (int q = 0; q < 4; ++q) {
          ushort8 o;
#pragma unroll
          for (int i = 0; i < 8; ++i) o[i] = f2bf(v[q * 8 + i]);
          *reinterpret_cast<ushort8*>(dst + q * 8) = o;
        }
      } else {
        float* dst = (float*)outv + (size_t)r * ldo + n0 + h * 64 + cb;
#pragma unroll
        for (int q = 0; q < 8; ++q) {
          float4 o = make_float4(v[4 * q], v[4 * q + 1], v[4 * q + 2], v[4 * q + 3]);
          *reinterpret_cast<float4*>(dst + 4 * q) = o;
        }
      }
    }
  }
}

// ---------------- fused tail GEMM: 4 x K=256 A-segments, N=128, f32 out ----------------
__global__ __launch_bounds__(256) void gemm_gl4(
    const unsigned short* __restrict__ A0, const unsigned short* __restrict__ A1,
    const unsigned short* __restrict__ A2, const unsigned short* __restrict__ A3,
    const unsigned short* __restrict__ Bt, const float* __restrict__ bias,
    float* __restrict__ outv, int nrows) {
  constexpr int KTOT = 1024;
  constexpr int KT = 16;
  __shared__ char smem[32768];
  unsigned short* sA = (unsigned short*)smem;
  unsigned short* sB = sA + 8192;

  const int t = threadIdx.x;
  const int lane = t & 63;
  const int w = t >> 6;
  const int wm = (w & 1) * 64, wn = (w >> 1) * 64;
  const int row0 = blockIdx.y * 128;

  const int srow = (w << 5) + (lane >> 3);
  const int schunk = (lane & 7) << 3;

  f32x4 acc[4][4] = {};

  for (int kt = 0; kt < KT; ++kt) {
    const int seg = kt >> 2;
    const unsigned short* Asrc = (seg == 0) ? A0 : (seg == 1) ? A1 : (seg == 2) ? A2 : A3;
    const int kA = (kt & 3) * 64;
#pragma unroll
    for (int q = 0; q < 4; ++q) {
      int rA = srow + q * 8;
      int rowg = row0 + rA;
      if (rowg >= nrows) rowg = nrows - 1;
      gload_lds16(Asrc + (size_t)rowg * 256 + kA + schunk,
                  sA + ((w << 5) + q * 8) * 64);
      gload_lds16(Bt + (size_t)rA * KTOT + kt * 64 + schunk,
                  sB + ((w << 5) + q * 8) * 64);
    }
    __syncthreads();
#pragma unroll
    for (int kk = 0; kk < 2; ++kk) {
      const int ko = kk * 32 + (lane >> 4) * 8;
      short8 a[4], b[4];
#pragma unroll
      for (int mi = 0; mi < 4; ++mi)
        a[mi] = *reinterpret_cast<const short8*>(&sA[(wm + mi * 16 + (lane & 15)) * 64 + ko]);
#pragma unroll
      for (int ni = 0; ni < 4; ++ni)
        b[ni] = *reinterpret_cast<const short8*>(&sB[(wn + ni * 16 + (lane & 15)) * 64 + ko]);
#pragma unroll
      for (int mi = 0; mi < 4; ++mi)
#pragma unroll
        for (int ni = 0; ni < 4; ++ni)
          acc[mi][ni] = __builtin_amdgcn_mfma_f32_16x16x32_bf16(a[mi], b[ni], acc[mi][ni], 0, 0, 0);
    }
    __syncthreads();
  }

  float* Co = (float*)smem;
#pragma unroll
  for (int h = 0; h < 2; ++h) {
    __syncthreads();
    if ((w >> 1) == h) {
#pragma unroll
      for (int mi = 0; mi < 4; ++mi)
#pragma unroll
        for (int ni = 0; ni < 4; ++ni) {
          int col = ni * 16 + (lane & 15);
          int rowb = wm + mi * 16 + (lane >> 4) * 4;
#pragma unroll
          for (int j = 0; j < 4; ++j) Co[(rowb + j) * 64 + col] = acc[mi][ni][j];
        }
    }
    __syncthreads();
    int sr = t >> 1, cb = (t & 1) * 32;
    int r = row0 + sr;
    if (r < nrows) {
      float* dst = outv + (size_t)r * MLPH + h * 64 + cb;
#pragma unroll
      for (int q = 0; q < 8; ++q) {
        float4 o;
        o.x = Co[sr * 64 + cb + 4 * q + 0] + bias[h * 64 + cb + 4 * q + 0];
        o.y = Co[sr * 64 + cb + 4 * q + 1] + bias[h * 64 + cb + 4 * q + 1];
        o.z = Co[sr * 64 + cb + 4 * q + 2] + bias[h * 64 + cb + 4 * q + 2];
        o.w = Co[sr * 64 + cb + 4 * q + 3] + bias[h * 64 + cb + 4 * q + 3];
        *reinterpret_cast<float4*>(dst + 4 * q) = o;
      }
    }
  }
}

// ---------------- BN ----------------
__global__ __launch_bounds__(256) void bn_stats_kernel(const float* __restrict__ x,
                                                       float* __restrict__ sums,
                                                       float* __restrict__ sumsq) {
  int c = threadIdx.x & 127;
  int rbase = (blockIdx.x * 256 + threadIdx.x) >> 7;
  int stride = (gridDim.x * 256) >> 7;
  float s = 0.f, s2 = 0.f;
  for (int r = rbase; r < NN; r += stride) {
    float v = x[(size_t)r * 128 + c];
    s += v;
    s2 += v * v;
  }
  __shared__ float ls[256], ls2[256];
  ls[threadIdx.x] = s;
  ls2[threadIdx.x] = s2;
  __syncthreads();
  if (threadIdx.x < 128) {
    s = ls[threadIdx.x] + ls[threadIdx.x + 128];
    s2 = ls2[threadIdx.x] + ls2[threadIdx.x + 128];
    atomicAdd(&sums[c], s);
    atomicAdd(&sumsq[c], s2);
  }
}

__global__ __launch_bounds__(128) void bn_finalize_kernel(float* __restrict__ stats,
                                                          const float* __restrict__ gamma,
                                                          const float* __restrict__ beta) {
  int c = threadIdx.x;
  float mu = stats[c] * (1.0f / NN);
  float var = stats[128 + c] * (1.0f / NN) - mu * mu;
  var = fmaxf(var, 0.f);
  float sc = gamma[c] * rsqrtf(var + BN_EPS);
  stats[256 + c] = sc;
  stats[384 + c] = beta[c] - mu * sc;
}

// ---------------- final head GEMM with fused BN+ReLU on A-load (64x64) ----------------
template <int K1, bool RELU>
__global__ __launch_bounds__(256) void gemm_mfma_bn(
    const float* __restrict__ A1v, const unsigned short* __restrict__ Bt,
    const float* __restrict__ bias, const float* __restrict__ bnscale,
    const float* __restrict__ bnshift, float* __restrict__ outv, int ldo, int nrows) {
  constexpr int KT = K1 / 64;
  constexpr int LDT = 72;
  __shared__ char smem[2 * 64 * LDT * 2];
  unsigned short* As = (unsigned short*)smem;
  unsigned short* Bs = As + 64 * LDT;
  float* Co = (float*)smem;
  constexpr int LDC = 68;

  const int t = threadIdx.x;
  const int lane = t & 63;
  const int w = t >> 6;
  const int wm = (w & 1) * 32, wn = (w >> 1) * 32;
  const int row0 = blockIdx.y * 64;
  const int n0 = blockIdx.x * 64;

  const int sr = t >> 2;
  const int skc = (t & 3) * 16;
  int rg = row0 + sr;
  if (rg >= nrows) rg = nrows - 1;

  f32x4 acc[2][2] = {};

  for (int kt = 0; kt < KT; ++kt) {
    const int kbase = kt * 64;
    {
      const float* xb = A1v + (size_t)rg * K1 + kbase + skc;
      ushort8 o0, o1;
#pragma unroll
      for (int i = 0; i < 8; ++i) {
        float v = xb[i] * bnscale[kbase + skc + i] + bnshift[kbase + skc + i];
        o0[i] = f2bf(fmaxf(v, 0.f));
      }
#pragma unroll
      for (int i = 0; i < 8; ++i) {
        float v = xb[8 + i] * bnscale[kbase + skc + 8 + i] + bnshift[kbase + skc + 8 + i];
        o1[i] = f2bf(fmaxf(v, 0.f));
      }
      *reinterpret_cast<ushort8*>(&As[sr * LDT + skc]) = o0;
      *reinterpret_cast<ushort8*>(&As[sr * LDT + skc + 8]) = o1;
    }
    {
      const unsigned short* bb = Bt + (size_t)(n0 + sr) * K1 + kbase + skc;
      int4 p0 = *reinterpret_cast<const int4*>(bb);
      int4 p1 = *reinterpret_cast<const int4*>(bb + 8);
      *reinterpret_cast<int4*>(&Bs[sr * LDT + skc]) = p0;
      *reinterpret_cast<int4*>(&Bs[sr * LDT + skc + 8]) = p1;
    }
    __syncthreads();
#pragma unroll
    for (int kk = 0; kk < 2; ++kk) {
      const int ko = kk * 32 + (lane >> 4) * 8;
      short8 a0 = *reinterpret_cast<const short8*>(&As[(wm + (lane & 15)) * LDT + ko]);
      short8 a1 = *reinterpret_cast<const short8*>(&As[(wm + 16 + (lane & 15)) * LDT + ko]);
      short8 b0 = *reinterpret_cast<const short8*>(&Bs[(wn + (lane & 15)) * LDT + ko]);
      short8 b1 = *reinterpret_cast<const short8*>(&Bs[(wn + 16 + (lane & 15)) * LDT + ko]);
      acc[0][0] = __builtin_amdgcn_mfma_f32_16x16x32_bf16(a0, b0, acc[0][0], 0, 0, 0);
      acc[0][1] = __builtin_amdgcn_mfma_f32_16x16x32_bf16(a0, b1, acc[0][1], 0, 0, 0);
      acc[1][0] = __builtin_amdgcn_mfma_f32_16x16x32_bf16(a1, b0, acc[1][0], 0, 0, 0);
      acc[1][1] = __builtin_amdgcn_mfma_f32_16x16x32_bf16(a1, b1, acc[1][1], 0, 0, 0);
    }
    __syncthreads();
  }

#pragma unroll
  for (int mi = 0; mi < 2; ++mi)
#pragma unroll
    for (int ni = 0; ni < 2; ++ni) {
      int col = wn + ni * 16 + (lane & 15);
      int rowb = wm + mi * 16 + (lane >> 4) * 4;
#pragma unroll
      for (int j = 0; j < 4; ++j) Co[(rowb + j) * LDC + col] = acc[mi][ni][j];
    }
  __syncthreads();
  {
    int r = row0 + sr;
    if (r < nrows) {
      float v[16];
#pragma unroll
      for (int i = 0; i < 16; ++i) {
        v[i] = Co[sr * LDC + skc + i] + bias[n0 + skc + i];
        if (RELU) v[i] = fmaxf(v[i], 0.f);
      }
      float* dst = outv + (size_t)r * ldo + n0 + skc;
#pragma unroll
      for (int i = 0; i < 4; ++i) {
        float4 o = make_float4(v[4 * i], v[4 * i + 1], v[4 * i + 2], v[4 * i + 3]);
        *reinterpret_cast<float4*>(dst + 4 * i) = o;
      }
    }
  }
}

// ---------------- launch ----------------
extern "C" void kernel_launch(void* const* d_in, const int* in_sizes, int n_in,
                              void* d_out, int out_size, void* d_ws, size_t ws_size,
                              hipStream_t stream) {
  const float* feat = (const float*)d_in[0];
  const int* g_src = (const int*)d_in[1];
  const int* g_dst = (const int*)d_in[2];
  const int* k_src = (const int*)d_in[3];
  const int* k_dst = (const int*)d_in[4];
  const float* lb_0 = (const float*)d_in[7];
  const float* lb_1 = (const float*)d_in[10];
  const float* lb_2 = (const float*)d_in[13];
  const float* gb_0 = (const float*)d_in[16];
  const float* gb_1 = (const float*)d_in[19];
  const float* mlp_b1 = (const float*)d_in[21];
  const float* bn_gamma = (const float*)d_in[22];
  const float* bn_beta = (const float*)d_in[23];
  const float* mlp_b2 = (const float*)d_in[25];
  float* out = (float*)d_out;

  // workspace layout
  float* xf32 = (float*)d_ws;                         // N*128 f32
  int* cnt_g = (int*)(xf32 + (size_t)NN * 128);       // N
  int* cnt_k = cnt_g + NN;                            // N
  int* cur_g = cnt_k + NN;                            // N
  int* cur_k = cur_g + NN;                            // N
  float* stats = (float*)(cur_k + NN);                // 512 (zeroed with cnt/cur)
  float* invg = stats + 512;                          // N
  float* invk = invg + NN;                            // N
  int* off_g = (int*)(invk + NN);                     // N+4
  int* off_k = off_g + NN + 4;                        // N+4
  int* part = off_k + NN + 4;                         // 512
  int* esrc_g = part + 512;                           // EG
  int* esrc_k = esrc_g + EG;                          // EK
  unsigned short* featbf = (unsigned short*)(esrc_k + EK);  // N*128
  unsigned short* wts = featbf + (size_t)NN * IN_F;         // 598016
  unsigned short* wf = wts + 598016;                  // 131072 (fused head weights)
  float* bfused = (float*)(wf + 131072);              // 128
  unsigned short* bfA = (unsigned short*)(bfused + 128);  // N*256
  unsigned short* bfB = bfA + (size_t)NN * HF;        // N*256
  unsigned short* bfAgg = bfB + (size_t)NN * HF;      // N*256
  unsigned short* bfD = bfAgg + (size_t)NN * HF;      // N*256

  const int wL0 = 0, wL1 = 65536, wG0 = 327680, wH2 = 589824;

  dim3 blk(256);
  const int NB = (NN + 255) / 256;        // 196
  const int MB = (NN + 127) / 128;        // 391
  const dim3 gridH(2, MB);                // 256-col out, BM=128 BN=128
  const dim3 grid4(1, MB);                // fused tail
  const int agg128_blocks = (NN + 15) / 16;
  const int agg256_blocks = (NN + 7) / 8;
  const int FILL_CHUNKS = 176;            // fill3 grid = 8 * 176

  // zero cnt_g, cnt_k, cur_g, cur_k, stats in one go
  hipMemsetAsync(cnt_g, 0, (size_t)(4 * NN) * sizeof(int) + 512 * sizeof(float), stream);

  WPack p;
  p.d[0] = {(const float*)d_in[5], 128, 8, 0, 256, wL0};
  p.d[1] = {(const float*)d_in[6], 128, 8, 128, 256, wL0};
  p.d[2] = {(const float*)d_in[8], 256, 8, 0, 512, wL1};
  p.d[3] = {(const float*)d_in[9], 256, 8, 256, 512, wL1};
  p.d[4] = {(const float*)d_in[11], 256, 8, 0, 512, 196608};  // folded; kept for layout
  p.d[5] = {(const float*)d_in[12], 256, 8, 256, 512, 196608};
  p.d[6] = {(const float*)d_in[14], 128, 8, 0, 256, wG0};
  p.d[7] = {(const float*)d_in[15], 128, 8, 128, 256, wG0};
  p.d[8] = {(const float*)d_in[17], 256, 8, 0, 512, 393216};  // folded
  p.d[9] = {(const float*)d_in[18], 256, 8, 256, 512, 393216};
  p.d[10] = {(const float*)d_in[20], 512, 7, 0, 512, 524288}; // folded
  p.d[11] = {(const float*)d_in[24], 128, 6, 0, 128, wH2};
  prep_kernel<<<8979, blk, 0, stream>>>(feat, featbf, p, wts, g_dst, k_dst, cnt_g, cnt_k);

  // fused head weights: wf[128][1024], bfused[128]
  fuse_w_kernel<<<1025, 128, 0, stream>>>(
      (const float*)d_in[11], (const float*)d_in[12],
      (const float*)d_in[17], (const float*)d_in[18],
      (const float*)d_in[20], lb_2, gb_1, mlp_b1, wf, bfused);

  scan_partial2<<<dim3(NB, 2), blk, 0, stream>>>(cnt_g, cnt_k, part, NN);
  scan_block2<<<2, blk, 0, stream>>>(part, NB);
  scan_final2<<<dim3(NB, 2), blk, 0, stream>>>(cnt_g, cnt_k, part, off_g, off_k, invg, invk, NN);
  fill3<<<8 * FILL_CHUNKS, blk, 0, stream>>>(g_src, g_dst, k_src, k_dst, off_g, off_k,
                                             cur_g, cur_k, esrc_g, esrc_k, FILL_CHUNKS);

  // ---- local layer 0: h_l0 = relu([feat|agg] @ WL0) ----
  csr_aggregate<7><<<agg128_blocks, blk, 0, stream>>>(featbf, off_g, esrc_g, invg, bfAgg);
  gemm_gl<128, 128, true, true><<<gridH, blk, 0, stream>>>(
      featbf, bfAgg, wts + wL0, lb_0, bfA, HF, NN);
  // ---- local layer 1: h_l1 = relu([h_l0|agg] @ WL1) ----
  csr_aggregate<8><<<agg256_blocks, blk, 0, stream>>>(bfA, off_g, esrc_g, invg, bfAgg);
  gemm_gl<256, 256, true, true><<<gridH, blk, 0, stream>>>(
      bfA, bfAgg, wts + wL1, lb_1, bfB, HF, NN);
  // ---- agg for (folded) local layer 2: aggL2 = mean_g(h_l1) -> bfD ----
  csr_aggregate<8><<<agg256_blocks, blk, 0, stream>>>(bfB, off_g, esrc_g, invg, bfD);
  // ---- global layer 0: h_g0 = relu([feat|agg] @ WG0) -> bfA ----
  csr_aggregate<7><<<agg128_blocks, blk, 0, stream>>>(featbf, off_k, esrc_k, invk, bfAgg);
  gemm_gl<128, 128, true, true><<<gridH, blk, 0, stream>>>(
      featbf, bfAgg, wts + wG0, gb_0, bfA, HF, NN);
  // ---- agg for (folded) global layer 1: aggG1 = mean_k(h_g0) -> bfAgg ----
  csr_aggregate<8><<<agg256_blocks, blk, 0, stream>>>(bfA, off_k, esrc_k, invk, bfAgg);

  // ---- fused tail: x = h_l1@Wf0 + aggL2@Wf1 + h_g0@Wf2 + aggG1@Wf3 + bfused ----
  gemm_gl4<<<grid4, blk, 0, stream>>>(bfB, bfD, bfA, bfAgg, wf, bfused, xf32, NN);

  // ---- BatchNorm ----
  bn_stats_kernel<<<256, blk, 0, stream>>>(xf32, stats, stats + 128);
  bn_finalize_kernel<<<1, 128, 0, stream>>>(stats, bn_gamma, bn_beta);

  // ---- head GEMM2: out = relu(bn(x)) @ w2 + b2 ----
  gemm_mfma_bn<128, false><<<dim3(1, (NN + 63) / 64), blk, 0, stream>>>(
      xf32, wts + wH2, mlp_b2, stats + 256, stats + 384, out, COUT, NN);
}

// Round 10
// 542.237 us; speedup vs baseline: 1.2543x; 1.0474x over previous
//
#include <hip/hip_runtime.h>

#define NN   50000
#define IN_F 128
#define HF   256
#define COUT 64
#define MLPH 128
#define EG   600000
#define EK   800000
#define RNG  6250   // NN / 8
#define BN_EPS 1e-5f

typedef __attribute__((ext_vector_type(8))) short short8;
typedef __attribute__((ext_vector_type(8))) unsigned short ushort8;
typedef __attribute__((ext_vector_type(4))) float f32x4;

__device__ __forceinline__ unsigned short f2bf(float f) {
  union { float f; unsigned int u; } v; v.f = f;
  unsigned int r = v.u + 0x7FFFu + ((v.u >> 16) & 1u);
  return (unsigned short)(r >> 16);
}
__device__ __forceinline__ float bf2f(unsigned short s) {
  union { unsigned int u; float f; } v; v.u = ((unsigned int)s) << 16;
  return v.f;
}

__device__ __forceinline__ void gload_lds16(const void* g, void* l) {
  __builtin_amdgcn_global_load_lds((const __attribute__((address_space(1))) void*)g,
                                   (__attribute__((address_space(3))) void*)l, 16, 0, 0);
}

struct WDesc { const float* src; int rows; int cshift; int kofs; int ldk; int dofs; };
struct WPack { WDesc d[12]; };

// ---------------- prep: feat->bf16, weight transpose, edge->ushort ----------------
__global__ __launch_bounds__(256) void prep_kernel(const float* __restrict__ feat,
                                                   unsigned short* __restrict__ featbf,
                                                   WPack p, unsigned short* __restrict__ wts,
                                                   const int* __restrict__ g_src,
                                                   const int* __restrict__ g_dst,
                                                   const int* __restrict__ k_src,
                                                   const int* __restrict__ k_dst,
                                                   unsigned short* __restrict__ s16g,
                                                   unsigned short* __restrict__ d16g,
                                                   unsigned short* __restrict__ s16k,
                                                   unsigned short* __restrict__ d16k) {
  int b = blockIdx.x;
  if (b < 3126) {
    int i = b * 256 + threadIdx.x;
    if (i < NN * IN_F / 8) {
      float4 a = *reinterpret_cast<const float4*>(&feat[i * 8]);
      float4 c = *reinterpret_cast<const float4*>(&feat[i * 8 + 4]);
      ushort8 o;
      o[0] = f2bf(a.x); o[1] = f2bf(a.y); o[2] = f2bf(a.z); o[3] = f2bf(a.w);
      o[4] = f2bf(c.x); o[5] = f2bf(c.y); o[6] = f2bf(c.z); o[7] = f2bf(c.w);
      *reinterpret_cast<ushort8*>(&featbf[i * 8]) = o;
    }
  } else if (b < 3510) {
    int wb = b - 3126;
    WDesc w = p.d[wb >> 5];
    int xb = wb & 31;
    int total = w.rows << w.cshift;
    int cmask = (1 << w.cshift) - 1;
    for (int idx = xb * 256 + threadIdx.x; idx < total; idx += 32 * 256) {
      int r = idx >> w.cshift, c = idx & cmask;
      wts[w.dofs + (size_t)c * w.ldk + w.kofs + r] = f2bf(w.src[idx]);
    }
  } else {
    int j = (b - 3510) * 256 + threadIdx.x;  // ushort8 group index over 4 arrays
    if (j < 350000) {
      const int* src;
      unsigned short* dst;
      int base;
      if (j < 75000)       { src = g_src; dst = s16g; base = j; }
      else if (j < 150000) { src = g_dst; dst = d16g; base = j - 75000; }
      else if (j < 250000) { src = k_src; dst = s16k; base = j - 150000; }
      else                 { src = k_dst; dst = d16k; base = j - 250000; }
      int4 a = *reinterpret_cast<const int4*>(&src[base * 8]);
      int4 c = *reinterpret_cast<const int4*>(&src[base * 8 + 4]);
      ushort8 o;
      o[0] = (unsigned short)a.x; o[1] = (unsigned short)a.y;
      o[2] = (unsigned short)a.z; o[3] = (unsigned short)a.w;
      o[4] = (unsigned short)c.x; o[5] = (unsigned short)c.y;
      o[6] = (unsigned short)c.z; o[7] = (unsigned short)c.w;
      *reinterpret_cast<ushort8*>(&dst[base * 8]) = o;
    }
  }
}

// ---------------- fused head weights ----------------
__global__ __launch_bounds__(128) void fuse_w_kernel(
    const float* __restrict__ wl2s, const float* __restrict__ wl2n,
    const float* __restrict__ wg1s, const float* __restrict__ wg1n,
    const float* __restrict__ w1, const float* __restrict__ bl2,
    const float* __restrict__ bg1, const float* __restrict__ b1,
    unsigned short* __restrict__ wf, float* __restrict__ bfused) {
  int b = blockIdx.x;
  int c = threadIdx.x;  // 0..127
  __shared__ float row[256];
  if (b < 1024) {
    int seg = b >> 8, i = b & 255;
    const float* W = (seg == 0) ? wl2s : (seg == 1) ? wl2n : (seg == 2) ? wg1s : wg1n;
    const float* w1b = w1 + ((seg < 2) ? 0 : 256) * MLPH;
    row[c] = W[i * 256 + c];
    row[c + 128] = W[i * 256 + 128 + c];
    __syncthreads();
    float acc = 0.f;
    for (int o = 0; o < 256; ++o) acc += row[o] * w1b[o * MLPH + c];
    wf[(size_t)c * 1024 + seg * 256 + i] = f2bf(acc);
  } else {
    float acc = b1[c];
    for (int o = 0; o < 256; ++o) acc += bl2[o] * w1[o * MLPH + c];
    for (int o = 0; o < 256; ++o) acc += bg1[o] * w1[(256 + o) * MLPH + c];
    bfused[c] = acc;
  }
}

// ---------------- range-partitioned LDS-histogram count ----------------
__global__ __launch_bounds__(256) void count_range(const unsigned short* __restrict__ d16g,
                                                   const unsigned short* __restrict__ d16k,
                                                   int* __restrict__ cnt_g,
                                                   int* __restrict__ cnt_k, int nchunks) {
  __shared__ int hist[RNG];
  const int x = blockIdx.x;  // 0..15
  const int r = x >> 1, gr = x & 1;
  const unsigned short* d16 = gr ? d16k : d16g;
  int* cnt = gr ? cnt_k : cnt_g;
  const int E = gr ? EK : EG;
  const unsigned lo = r * RNG;
  for (int i = threadIdx.x; i < RNG; i += 256) hist[i] = 0;
  __syncthreads();
  const int chunk8 = ((E >> 3) + nchunks - 1) / nchunks;
  int e0 = blockIdx.y * chunk8 * 8;
  int e1 = e0 + chunk8 * 8;
  if (e1 > E) e1 = E;
  for (int e = e0 + (int)threadIdx.x * 8; e < e1; e += 2048) {
    ushort8 d8 = __builtin_nontemporal_load(reinterpret_cast<const ushort8*>(&d16[e]));
#pragma unroll
    for (int i = 0; i < 8; ++i) {
      unsigned d = d8[i];
      if (d - lo < (unsigned)RNG) atomicAdd(&hist[d - lo], 1);
    }
  }
  __syncthreads();
  for (int i = threadIdx.x; i < RNG; i += 256) {
    int v = hist[i];
    if (v) atomicAdd(&cnt[lo + i], v);
  }
}

// ---------------- parallel scans for both graphs ----------------
__global__ __launch_bounds__(256) void scan_partial2(const int* __restrict__ cnt_g,
                                                     const int* __restrict__ cnt_k,
                                                     int* __restrict__ part, int n) {
  const int* cnt = blockIdx.y ? cnt_k : cnt_g;
  int* pp = part + blockIdx.y * 256;
  int i = blockIdx.x * 256 + threadIdx.x;
  int v = (i < n) ? cnt[i] : 0;
  __shared__ int ws[4];
  int lane = threadIdx.x & 63, wid = threadIdx.x >> 6;
  int x = v;
#pragma unroll
  for (int d = 1; d < 64; d <<= 1) { int y = __shfl_up(x, d, 64); if (lane >= d) x += y; }
  if (lane == 63) ws[wid] = x;
  __syncthreads();
  if (threadIdx.x == 0) pp[blockIdx.x] = ws[0] + ws[1] + ws[2] + ws[3];
}

__global__ __launch_bounds__(256) void scan_block2(int* __restrict__ part, int np) {
  int* pp = part + blockIdx.x * 256;
  __shared__ int ws[4];
  int tid = threadIdx.x, lane = tid & 63, wid = tid >> 6;
  int v = (tid < np) ? pp[tid] : 0;
  int x = v;
#pragma unroll
  for (int d = 1; d < 64; d <<= 1) { int y = __shfl_up(x, d, 64); if (lane >= d) x += y; }
  if (lane == 63) ws[wid] = x;
  __syncthreads();
  int add = 0;
#pragma unroll
  for (int k = 0; k < 4; ++k) if (k < wid) add += ws[k];
  if (tid < np) pp[tid] = x - v + add;
}

__global__ __launch_bounds__(256) void scan_final2(const int* __restrict__ cnt_g,
                                                   const int* __restrict__ cnt_k,
                                                   const int* __restrict__ part,
                                                   int* __restrict__ off_g,
                                                   int* __restrict__ off_k,
                                                   float* __restrict__ invg,
                                                   float* __restrict__ invk, int n) {
  const int* cnt = blockIdx.y ? cnt_k : cnt_g;
  const int* pp = part + blockIdx.y * 256;
  int* off = blockIdx.y ? off_k : off_g;
  float* inv = blockIdx.y ? invk : invg;
  int total = blockIdx.y ? EK : EG;
  int i = blockIdx.x * 256 + threadIdx.x;
  int v = (i < n) ? cnt[i] : 0;
  __shared__ int ws[4];
  int lane = threadIdx.x & 63, wid = threadIdx.x >> 6;
  int x = v;
#pragma unroll
  for (int d = 1; d < 64; d <<= 1) { int y = __shfl_up(x, d, 64); if (lane >= d) x += y; }
  if (lane == 63) ws[wid] = x;
  __syncthreads();
  int add = pp[blockIdx.x];
#pragma unroll
  for (int k = 0; k < 4; ++k) if (k < wid) add += ws[k];
  if (i < n) {
    off[i] = x - v + add;
    inv[i] = 1.0f / fmaxf((float)v, 1.0f);
  }
  if (i == 0) off[n] = total;
}

// ---------------- XCD-range-partitioned CSR fill (ushort, nontemporal scans) --------
__global__ __launch_bounds__(256) void fill_range(
    const unsigned short* __restrict__ s16g, const unsigned short* __restrict__ d16g,
    const unsigned short* __restrict__ s16k, const unsigned short* __restrict__ d16k,
    const int* __restrict__ off_g, const int* __restrict__ off_k,
    int* __restrict__ cur_g, int* __restrict__ cur_k,
    unsigned short* __restrict__ e16g, unsigned short* __restrict__ e16k, int nchunks) {
  const int gr = blockIdx.y;
  const unsigned short* s16 = gr ? s16k : s16g;
  const unsigned short* d16 = gr ? d16k : d16g;
  const int* off = gr ? off_k : off_g;
  int* cur = gr ? cur_k : cur_g;
  unsigned short* e16 = gr ? e16k : e16g;
  const int E = gr ? EK : EG;
  const int r = blockIdx.x & 7;
  const int c = blockIdx.x >> 3;
  const unsigned lo = r * RNG;
  const int chunk8 = ((E >> 3) + nchunks - 1) / nchunks;
  int e0 = c * chunk8 * 8;
  int e1 = e0 + chunk8 * 8;
  if (e1 > E) e1 = E;
  for (int e = e0 + (int)threadIdx.x * 8; e < e1; e += 2048) {
    ushort8 d8 = __builtin_nontemporal_load(reinterpret_cast<const ushort8*>(&d16[e]));
    ushort8 s8 = __builtin_nontemporal_load(reinterpret_cast<const ushort8*>(&s16[e]));
#pragma unroll
    for (int i = 0; i < 8; ++i) {
      unsigned d = d8[i];
      if (d - lo < (unsigned)RNG) {
        int pz = atomicAdd(&cur[d], 1);
        e16[off[d] + pz] = s8[i];
      }
    }
  }
}

// ---------------- CSR mean-aggregation (bf16 in/out, ushort esrc), unroll-4 ----------
template <int DLOG2>
__global__ __launch_bounds__(256) void csr_aggregate(const unsigned short* __restrict__ h,
                                                     const int* __restrict__ off,
                                                     const unsigned short* __restrict__ esrc,
                                                     const float* __restrict__ inv,
                                                     unsigned short* __restrict__ out) {
  constexpr int TPN = (1 << DLOG2) / 8;
  constexpr int NPB = 256 / TPN;
  int node = blockIdx.x * NPB + ((int)threadIdx.x / TPN);
  int lane = threadIdx.x & (TPN - 1);
  if (node >= NN) return;
  int s = off[node], e = off[node + 1];
  float acc[8] = {0.f, 0.f, 0.f, 0.f, 0.f, 0.f, 0.f, 0.f};
  int j = s;
  for (; j + 3 < e; j += 4) {
    int s0 = esrc[j], s1 = esrc[j + 1], s2 = esrc[j + 2], s3 = esrc[j + 3];
    ushort8 v0 = *reinterpret_cast<const ushort8*>(&h[((size_t)s0 << DLOG2) + lane * 8]);
    ushort8 v1 = *reinterpret_cast<const ushort8*>(&h[((size_t)s1 << DLOG2) + lane * 8]);
    ushort8 v2 = *reinterpret_cast<const ushort8*>(&h[((size_t)s2 << DLOG2) + lane * 8]);
    ushort8 v3 = *reinterpret_cast<const ushort8*>(&h[((size_t)s3 << DLOG2) + lane * 8]);
#pragma unroll
    for (int i = 0; i < 8; ++i) acc[i] += bf2f(v0[i]);
#pragma unroll
    for (int i = 0; i < 8; ++i) acc[i] += bf2f(v1[i]);
#pragma unroll
    for (int i = 0; i < 8; ++i) acc[i] += bf2f(v2[i]);
#pragma unroll
    for (int i = 0; i < 8; ++i) acc[i] += bf2f(v3[i]);
  }
  for (; j < e; ++j) {
    int s0 = esrc[j];
    ushort8 v0 = *reinterpret_cast<const ushort8*>(&h[((size_t)s0 << DLOG2) + lane * 8]);
#pragma unroll
    for (int i = 0; i < 8; ++i) acc[i] += bf2f(v0[i]);
  }
  float sc = inv[node];
  ushort8 o;
#pragma unroll
  for (int i = 0; i < 8; ++i) o[i] = f2bf(acc[i] * sc);
  *reinterpret_cast<ushort8*>(&out[((size_t)node << DLOG2) + lane * 8]) = o;
}

// ---------------- MFMA GEMM, BM=128 x BN=128, BK=64, global_load_lds staging --------
template <int K1, int K2, bool RELU, bool OUT_BF16>
__global__ __launch_bounds__(256) void gemm_gl(
    const unsigned short* __restrict__ A1, const unsigned short* __restrict__ A2,
    const unsigned short* __restrict__ Bt, const float* __restrict__ bias,
    void* __restrict__ outv, int ldo, int nrows) {
  constexpr int KTOT = K1 + K2;
  constexpr int KT = KTOT / 64;
  __shared__ char smem[32768];
  unsigned short* sA = (unsigned short*)smem;
  unsigned short* sB = sA + 8192;

  const int t = threadIdx.x;
  const int lane = t & 63;
  const int w = t >> 6;
  const int wm = (w & 1) * 64, wn = (w >> 1) * 64;
  const int row0 = blockIdx.y * 128;
  const int n0 = blockIdx.x * 128;

  const int srow = (w << 5) + (lane >> 3);
  const int schunk = (lane & 7) << 3;

  f32x4 acc[4][4] = {};

  for (int kt = 0; kt < KT; ++kt) {
    const int kbase = kt * 64;
    const unsigned short* Asrc = (kbase < K1) ? A1 : A2;
    const int kA = (kbase < K1) ? kbase : (kbase - K1);
    const int lda = (kbase < K1) ? K1 : K2;
#pragma unroll
    for (int q = 0; q < 4; ++q) {
      int rA = srow + q * 8;
      int rowg = row0 + rA;
      if (rowg >= nrows) rowg = nrows - 1;
      gload_lds16(Asrc + (size_t)rowg * lda + kA + schunk,
                  sA + ((w << 5) + q * 8) * 64);
      gload_lds16(Bt + (size_t)(n0 + rA) * KTOT + kbase + schunk,
                  sB + ((w << 5) + q * 8) * 64);
    }
    __syncthreads();
#pragma unroll
    for (int kk = 0; kk < 2; ++kk) {
      const int ko = kk * 32 + (lane >> 4) * 8;
      short8 a[4], b[4];
#pragma unroll
      for (int mi = 0; mi < 4; ++mi)
        a[mi] = *reinterpret_cast<const short8*>(&sA[(wm + mi * 16 + (lane & 15)) * 64 + ko]);
#pragma unroll
      for (int ni = 0; ni < 4; ++ni)
        b[ni] = *reinterpret_cast<const short8*>(&sB[(wn + ni * 16 + (lane & 15)) * 64 + ko]);
#pragma unroll
      for (int mi = 0; mi < 4; ++mi)
#pragma unroll
        for (int ni = 0; ni < 4; ++ni)
          acc[mi][ni] = __builtin_amdgcn_mfma_f32_16x16x32_bf16(a[mi], b[ni], acc[mi][ni], 0, 0, 0);
    }
    __syncthreads();
  }

  float* Co = (float*)smem;
#pragma unroll
  for (int h = 0; h < 2; ++h) {
    __syncthreads();
    if ((w >> 1) == h) {
#pragma unroll
      for (int mi = 0; mi < 4; ++mi)
#pragma unroll
        for (int ni = 0; ni < 4; ++ni) {
          int col = ni * 16 + (lane & 15);
          int rowb = wm + mi * 16 + (lane >> 4) * 4;
#pragma unroll
          for (int j = 0; j < 4; ++j) Co[(rowb + j) * 64 + col] = acc[mi][ni][j];
        }
    }
    __syncthreads();
    int sr = t >> 1, cb = (t & 1) * 32;
    int r = row0 + sr;
    if (r < nrows) {
      float v[32];
#pragma unroll
      for (int i = 0; i < 32; ++i) {
        v[i] = Co[sr * 64 + cb + i] + bias[n0 + h * 64 + cb + i];
        if (RELU) v[i] = fmaxf(v[i], 0.f);
      }
      if (OUT_BF16) {
        unsigned short* dst = (unsigned short*)outv + (size_t)r * ldo + n0 + h * 64 + cb;
#pragma unroll
        for (int q = 0; q < 4; ++q) {
          ushort8 o;
#pragma unroll
          for (int i = 0; i < 8; ++i) o[i] = f2bf(v[q * 8 + i]);
          *reinterpret_cast<ushort8*>(dst + q * 8) = o;
        }
      } else {
        float* dst = (float*)outv + (size_t)r * ldo + n0 + h * 64 + cb;
#pragma unroll
        for (int q = 0; q < 8; ++q) {
          float4 o = make_float4(v[4 * q], v[4 * q + 1], v[4 * q + 2], v[4 * q + 3]);
          *reinterpret_cast<float4*>(dst + 4 * q) = o;
        }
      }
    }
  }
}

// ---------------- fused tail GEMM: 4 x K=256 A-segments, N=128, f32 out ----------------
__global__ __launch_bounds__(256) void gemm_gl4(
    const unsigned short* __restrict__ A0, const unsigned short* __restrict__ A1,
    const unsigned short* __restrict__ A2, const unsigned short* __restrict__ A3,
    const unsigned short* __restrict__ Bt, const float* __restrict__ bias,
    float* __restrict__ outv, int nrows) {
  constexpr int KTOT = 1024;
  constexpr int KT = 16;
  __shared__ char smem[32768];
  unsigned short* sA = (unsigned short*)smem;
  unsigned short* sB = sA + 8192;

  const int t = threadIdx.x;
  const int lane = t & 63;
  const int w = t >> 6;
  const int wm = (w & 1) * 64, wn = (w >> 1) * 64;
  const int row0 = blockIdx.y * 128;

  const int srow = (w << 5) + (lane >> 3);
  const int schunk = (lane & 7) << 3;

  f32x4 acc[4][4] = {};

  for (int kt = 0; kt < KT; ++kt) {
    const int seg = kt >> 2;
    const unsigned short* Asrc = (seg == 0) ? A0 : (seg == 1) ? A1 : (seg == 2) ? A2 : A3;
    const int kA = (kt & 3) * 64;
#pragma unroll
    for (int q = 0; q < 4; ++q) {
      int rA = srow + q * 8;
      int rowg = row0 + rA;
      if (rowg >= nrows) rowg = nrows - 1;
      gload_lds16(Asrc + (size_t)rowg * 256 + kA + schunk,
                  sA + ((w << 5) + q * 8) * 64);
      gload_lds16(Bt + (size_t)rA * KTOT + kt * 64 + schunk,
                  sB + ((w << 5) + q * 8) * 64);
    }
    __syncthreads();
#pragma unroll
    for (int kk = 0; kk < 2; ++kk) {
      const int ko = kk * 32 + (lane >> 4) * 8;
      short8 a[4], b[4];
#pragma unroll
      for (int mi = 0; mi < 4; ++mi)
        a[mi] = *reinterpret_cast<const short8*>(&sA[(wm + mi * 16 + (lane & 15)) * 64 + ko]);
#pragma unroll
      for (int ni = 0; ni < 4; ++ni)
        b[ni] = *reinterpret_cast<const short8*>(&sB[(wn + ni * 16 + (lane & 15)) * 64 + ko]);
#pragma unroll
      for (int mi = 0; mi < 4; ++mi)
#pragma unroll
        for (int ni = 0; ni < 4; ++ni)
          acc[mi][ni] = __builtin_amdgcn_mfma_f32_16x16x32_bf16(a[mi], b[ni], acc[mi][ni], 0, 0, 0);
    }
    __syncthreads();
  }

  float* Co = (float*)smem;
#pragma unroll
  for (int h = 0; h < 2; ++h) {
    __syncthreads();
    if ((w >> 1) == h) {
#pragma unroll
      for (int mi = 0; mi < 4; ++mi)
#pragma unroll
        for (int ni = 0; ni < 4; ++ni) {
          int col = ni * 16 + (lane & 15);
          int rowb = wm + mi * 16 + (lane >> 4) * 4;
#pragma unroll
          for (int j = 0; j < 4; ++j) Co[(rowb + j) * 64 + col] = acc[mi][ni][j];
        }
    }
    __syncthreads();
    int sr = t >> 1, cb = (t & 1) * 32;
    int r = row0 + sr;
    if (r < nrows) {
      float* dst = outv + (size_t)r * MLPH + h * 64 + cb;
#pragma unroll
      for (int q = 0; q < 8; ++q) {
        float4 o;
        o.x = Co[sr * 64 + cb + 4 * q + 0] + bias[h * 64 + cb + 4 * q + 0];
        o.y = Co[sr * 64 + cb + 4 * q + 1] + bias[h * 64 + cb + 4 * q + 1];
        o.z = Co[sr * 64 + cb + 4 * q + 2] + bias[h * 64 + cb + 4 * q + 2];
        o.w = Co[sr * 64 + cb + 4 * q + 3] + bias[h * 64 + cb + 4 * q + 3];
        *reinterpret_cast<float4*>(dst + 4 * q) = o;
      }
    }
  }
}

// ---------------- BN ----------------
__global__ __launch_bounds__(256) void bn_stats_kernel(const float* __restrict__ x,
                                                       float* __restrict__ sums,
                                                       float* __restrict__ sumsq) {
  int c = threadIdx.x & 127;
  int rbase = (blockIdx.x * 256 + threadIdx.x) >> 7;
  int stride = (gridDim.x * 256) >> 7;
  float s = 0.f, s2 = 0.f;
  for (int r = rbase; r < NN; r += stride) {
    float v = x[(size_t)r * 128 + c];
    s += v;
    s2 += v * v;
  }
  __shared__ float ls[256], ls2[256];
  ls[threadIdx.x] = s;
  ls2[threadIdx.x] = s2;
  __syncthreads();
  if (threadIdx.x < 128) {
    s = ls[threadIdx.x] + ls[threadIdx.x + 128];
    s2 = ls2[threadIdx.x] + ls2[threadIdx.x + 128];
    atomicAdd(&sums[c], s);
    atomicAdd(&sumsq[c], s2);
  }
}

__global__ __launch_bounds__(128) void bn_finalize_kernel(float* __restrict__ stats,
                                                          const float* __restrict__ gamma,
                                                          const float* __restrict__ beta) {
  int c = threadIdx.x;
  float mu = stats[c] * (1.0f / NN);
  float var = stats[128 + c] * (1.0f / NN) - mu * mu;
  var = fmaxf(var, 0.f);
  float sc = gamma[c] * rsqrtf(var + BN_EPS);
  stats[256 + c] = sc;
  stats[384 + c] = beta[c] - mu * sc;
}

// ---------------- final head GEMM with fused BN+ReLU on A-load (64x64) ----------------
template <int K1, bool RELU>
__global__ __launch_bounds__(256) void gemm_mfma_bn(
    const float* __restrict__ A1v, const unsigned short* __restrict__ Bt,
    const float* __restrict__ bias, const float* __restrict__ bnscale,
    const float* __restrict__ bnshift, float* __restrict__ outv, int ldo, int nrows) {
  constexpr int KT = K1 / 64;
  constexpr int LDT = 72;
  __shared__ char smem[2 * 64 * LDT * 2];
  unsigned short* As = (unsigned short*)smem;
  unsigned short* Bs = As + 64 * LDT;
  float* Co = (float*)smem;
  constexpr int LDC = 68;

  const int t = threadIdx.x;
  const int lane = t & 63;
  const int w = t >> 6;
  const int wm = (w & 1) * 32, wn = (w >> 1) * 32;
  const int row0 = blockIdx.y * 64;
  const int n0 = blockIdx.x * 64;

  const int sr = t >> 2;
  const int skc = (t & 3) * 16;
  int rg = row0 + sr;
  if (rg >= nrows) rg = nrows - 1;

  f32x4 acc[2][2] = {};

  for (int kt = 0; kt < KT; ++kt) {
    const int kbase = kt * 64;
    {
      const float* xb = A1v + (size_t)rg * K1 + kbase + skc;
      ushort8 o0, o1;
#pragma unroll
      for (int i = 0; i < 8; ++i) {
        float v = xb[i] * bnscale[kbase + skc + i] + bnshift[kbase + skc + i];
        o0[i] = f2bf(fmaxf(v, 0.f));
      }
#pragma unroll
      for (int i = 0; i < 8; ++i) {
        float v = xb[8 + i] * bnscale[kbase + skc + 8 + i] + bnshift[kbase + skc + 8 + i];
        o1[i] = f2bf(fmaxf(v, 0.f));
      }
      *reinterpret_cast<ushort8*>(&As[sr * LDT + skc]) = o0;
      *reinterpret_cast<ushort8*>(&As[sr * LDT + skc + 8]) = o1;
    }
    {
      const unsigned short* bb = Bt + (size_t)(n0 + sr) * K1 + kbase + skc;
      int4 p0 = *reinterpret_cast<const int4*>(bb);
      int4 p1 = *reinterpret_cast<const int4*>(bb + 8);
      *reinterpret_cast<int4*>(&Bs[sr * LDT + skc]) = p0;
      *reinterpret_cast<int4*>(&Bs[sr * LDT + skc + 8]) = p1;
    }
    __syncthreads();
#pragma unroll
    for (int kk = 0; kk < 2; ++kk) {
      const int ko = kk * 32 + (lane >> 4) * 8;
      short8 a0 = *reinterpret_cast<const short8*>(&As[(wm + (lane & 15)) * LDT + ko]);
      short8 a1 = *reinterpret_cast<const short8*>(&As[(wm + 16 + (lane & 15)) * LDT + ko]);
      short8 b0 = *reinterpret_cast<const short8*>(&Bs[(wn + (lane & 15)) * LDT + ko]);
      short8 b1 = *reinterpret_cast<const short8*>(&Bs[(wn + 16 + (lane & 15)) * LDT + ko]);
      acc[0][0] = __builtin_amdgcn_mfma_f32_16x16x32_bf16(a0, b0, acc[0][0], 0, 0, 0);
      acc[0][1] = __builtin_amdgcn_mfma_f32_16x16x32_bf16(a0, b1, acc[0][1], 0, 0, 0);
      acc[1][0] = __builtin_amdgcn_mfma_f32_16x16x32_bf16(a1, b0, acc[1][0], 0, 0, 0);
      acc[1][1] = __builtin_amdgcn_mfma_f32_16x16x32_bf16(a1, b1, acc[1][1], 0, 0, 0);
    }
    __syncthreads();
  }

#pragma unroll
  for (int mi = 0; mi < 2; ++mi)
#pragma unroll
    for (int ni = 0; ni < 2; ++ni) {
      int col = wn + ni * 16 + (lane & 15);
      int rowb = wm + mi * 16 + (lane >> 4) * 4;
#pragma unroll
      for (int j = 0; j < 4; ++j) Co[(rowb + j) * LDC + col] = acc[mi][ni][j];
    }
  __syncthreads();
  {
    int r = row0 + sr;
    if (r < nrows) {
      float v[16];
#pragma unroll
      for (int i = 0; i < 16; ++i) {
        v[i] = Co[sr * LDC + skc + i] + bias[n0 + skc + i];
        if (RELU) v[i] = fmaxf(v[i], 0.f);
      }
      float* dst = outv + (size_t)r * ldo + n0 + skc;
#pragma unroll
      for (int i = 0; i < 4; ++i) {
        float4 o = make_float4(v[4 * i], v[4 * i + 1], v[4 * i + 2], v[4 * i + 3]);
        *reinterpret_cast<float4*>(dst + 4 * i) = o;
      }
    }
  }
}

// ---------------- launch ----------------
extern "C" void kernel_launch(void* const* d_in, const int* in_sizes, int n_in,
                              void* d_out, int out_size, void* d_ws, size_t ws_size,
                              hipStream_t stream) {
  const float* feat = (const float*)d_in[0];
  const int* g_src = (const int*)d_in[1];
  const int* g_dst = (const int*)d_in[2];
  const int* k_src = (const int*)d_in[3];
  const int* k_dst = (const int*)d_in[4];
  const float* lb_0 = (const float*)d_in[7];
  const float* lb_1 = (const float*)d_in[10];
  const float* lb_2 = (const float*)d_in[13];
  const float* gb_0 = (const float*)d_in[16];
  const float* gb_1 = (const float*)d_in[19];
  const float* mlp_b1 = (const float*)d_in[21];
  const float* bn_gamma = (const float*)d_in[22];
  const float* bn_beta = (const float*)d_in[23];
  const float* mlp_b2 = (const float*)d_in[25];
  float* out = (float*)d_out;

  // workspace layout (all section starts 16B-aligned)
  float* xf32 = (float*)d_ws;                         // N*128 f32
  int* cnt_g = (int*)(xf32 + (size_t)NN * 128);       // N
  int* cnt_k = cnt_g + NN;                            // N
  int* cur_g = cnt_k + NN;                            // N
  int* cur_k = cur_g + NN;                            // N
  float* stats = (float*)(cur_k + NN);                // 512 (zeroed with cnt/cur)
  float* invg = stats + 512;                          // N
  float* invk = invg + NN;                            // N
  int* off_g = (int*)(invk + NN);                     // N+4
  int* off_k = off_g + NN + 4;                        // N+4
  int* part = off_k + NN + 4;                         // 512
  unsigned short* s16g = (unsigned short*)(part + 512);  // EG
  unsigned short* d16g = s16g + EG;                   // EG
  unsigned short* s16k = d16g + EG;                   // EK
  unsigned short* d16k = s16k + EK;                   // EK
  unsigned short* e16g = d16k + EK;                   // EG
  unsigned short* e16k = e16g + EG;                   // EK
  unsigned short* featbf = e16k + EK;                 // N*128
  unsigned short* wts = featbf + (size_t)NN * IN_F;   // 598016
  unsigned short* wf = wts + 598016;                  // 131072
  float* bfused = (float*)(wf + 131072);              // 128
  unsigned short* bfA = (unsigned short*)(bfused + 128);  // N*256
  unsigned short* bfB = bfA + (size_t)NN * HF;        // N*256
  unsigned short* bfAgg = bfB + (size_t)NN * HF;      // N*256
  unsigned short* bfD = bfAgg + (size_t)NN * HF;      // N*256

  const int wL0 = 0, wL1 = 65536, wG0 = 327680, wH2 = 589824;

  dim3 blk(256);
  const int NB = (NN + 255) / 256;        // 196
  const int MB = (NN + 127) / 128;        // 391
  const dim3 gridH(2, MB);
  const dim3 grid4(1, MB);
  const int agg128_blocks = (NN + 15) / 16;
  const int agg256_blocks = (NN + 7) / 8;
  const int CNT_CHUNKS = 13;              // count_range grid = (16, 13)
  const int FILL_CHUNKS = 96;             // fill_range grid = (768, 2)

  // zero cnt_g, cnt_k, cur_g, cur_k, stats in one go
  hipMemsetAsync(cnt_g, 0, (size_t)(4 * NN) * sizeof(int) + 512 * sizeof(float), stream);

  WPack p;
  p.d[0] = {(const float*)d_in[5], 128, 8, 0, 256, wL0};
  p.d[1] = {(const float*)d_in[6], 128, 8, 128, 256, wL0};
  p.d[2] = {(const float*)d_in[8], 256, 8, 0, 512, wL1};
  p.d[3] = {(const float*)d_in[9], 256, 8, 256, 512, wL1};
  p.d[4] = {(const float*)d_in[11], 256, 8, 0, 512, 196608};  // folded; kept for layout
  p.d[5] = {(const float*)d_in[12], 256, 8, 256, 512, 196608};
  p.d[6] = {(const float*)d_in[14], 128, 8, 0, 256, wG0};
  p.d[7] = {(const float*)d_in[15], 128, 8, 128, 256, wG0};
  p.d[8] = {(const float*)d_in[17], 256, 8, 0, 512, 393216};  // folded
  p.d[9] = {(const float*)d_in[18], 256, 8, 256, 512, 393216};
  p.d[10] = {(const float*)d_in[20], 512, 7, 0, 512, 524288}; // folded
  p.d[11] = {(const float*)d_in[24], 128, 6, 0, 128, wH2};
  prep_kernel<<<4878, blk, 0, stream>>>(feat, featbf, p, wts, g_src, g_dst, k_src, k_dst,
                                        s16g, d16g, s16k, d16k);

  // fused head weights
  fuse_w_kernel<<<1025, 128, 0, stream>>>(
      (const float*)d_in[11], (const float*)d_in[12],
      (const float*)d_in[17], (const float*)d_in[18],
      (const float*)d_in[20], lb_2, gb_1, mlp_b1, wf, bfused);

  count_range<<<dim3(16, CNT_CHUNKS), blk, 0, stream>>>(d16g, d16k, cnt_g, cnt_k, CNT_CHUNKS);
  scan_partial2<<<dim3(NB, 2), blk, 0, stream>>>(cnt_g, cnt_k, part, NN);
  scan_block2<<<2, blk, 0, stream>>>(part, NB);
  scan_final2<<<dim3(NB, 2), blk, 0, stream>>>(cnt_g, cnt_k, part, off_g, off_k, invg, invk, NN);
  fill_range<<<dim3(8 * FILL_CHUNKS, 2), blk, 0, stream>>>(
      s16g, d16g, s16k, d16k, off_g, off_k, cur_g, cur_k, e16g, e16k, FILL_CHUNKS);

  // ---- local layer 0 ----
  csr_aggregate<7><<<agg128_blocks, blk, 0, stream>>>(featbf, off_g, e16g, invg, bfAgg);
  gemm_gl<128, 128, true, true><<<gridH, blk, 0, stream>>>(
      featbf, bfAgg, wts + wL0, lb_0, bfA, HF, NN);
  // ---- local layer 1 ----
  csr_aggregate<8><<<agg256_blocks, blk, 0, stream>>>(bfA, off_g, e16g, invg, bfAgg);
  gemm_gl<256, 256, true, true><<<gridH, blk, 0, stream>>>(
      bfA, bfAgg, wts + wL1, lb_1, bfB, HF, NN);
  // ---- agg for folded local layer 2 -> bfD ----
  csr_aggregate<8><<<agg256_blocks, blk, 0, stream>>>(bfB, off_g, e16g, invg, bfD);
  // ---- global layer 0 -> bfA ----
  csr_aggregate<7><<<agg128_blocks, blk, 0, stream>>>(featbf, off_k, e16k, invk, bfAgg);
  gemm_gl<128, 128, true, true><<<gridH, blk, 0, stream>>>(
      featbf, bfAgg, wts + wG0, gb_0, bfA, HF, NN);
  // ---- agg for folded global layer 1 -> bfAgg ----
  csr_aggregate<8><<<agg256_blocks, blk, 0, stream>>>(bfA, off_k, e16k, invk, bfAgg);

  // ---- fused tail GEMM ----
  gemm_gl4<<<grid4, blk, 0, stream>>>(bfB, bfD, bfA, bfAgg, wf, bfused, xf32, NN);

  // ---- BatchNorm ----
  bn_stats_kernel<<<256, blk, 0, stream>>>(xf32, stats, stats + 128);
  bn_finalize_kernel<<<1, 128, 0, stream>>>(stats, bn_gamma, bn_beta);

  // ---- head GEMM2 ----
  gemm_mfma_bn<128, false><<<dim3(1, (NN + 63) / 64), blk, 0, stream>>>(
      xf32, wts + wH2, mlp_b2, stats + 256, stats + 384, out, COUT, NN);
}

// Round 11
// 537.905 us; speedup vs baseline: 1.2644x; 1.0081x over previous
//
#include <hip/hip_runtime.h>

#define NN   50000
#define IN_F 128
#define HF   256
#define COUT 64
#define MLPH 128
#define EG   600000
#define EK   800000
#define RNG  6250    // NN / 8
#define CAPG 80000   // bucket capacity per range (EG/8 + ~19 sigma)
#define CAPK 106000
#define BN_EPS 1e-5f

typedef __attribute__((ext_vector_type(8))) short short8;
typedef __attribute__((ext_vector_type(8))) unsigned short ushort8;
typedef __attribute__((ext_vector_type(4))) float f32x4;

__device__ __forceinline__ unsigned short f2bf(float f) {
  union { float f; unsigned int u; } v; v.f = f;
  unsigned int r = v.u + 0x7FFFu + ((v.u >> 16) & 1u);
  return (unsigned short)(r >> 16);
}
__device__ __forceinline__ float bf2f(unsigned short s) {
  union { unsigned int u; float f; } v; v.u = ((unsigned int)s) << 16;
  return v.f;
}

__device__ __forceinline__ void gload_lds16(const void* g, void* l) {
  __builtin_amdgcn_global_load_lds((const __attribute__((address_space(1))) void*)g,
                                   (__attribute__((address_space(3))) void*)l, 16, 0, 0);
}

struct WDesc { const float* src; int rows; int cshift; int kofs; int ldk; int dofs; };
struct WPack { WDesc d[12]; };

// ---------------- prep: feat->bf16, weight transpose ----------------
__global__ __launch_bounds__(256) void prep_kernel(const float* __restrict__ feat,
                                                   unsigned short* __restrict__ featbf,
                                                   WPack p, unsigned short* __restrict__ wts) {
  int b = blockIdx.x;
  if (b < 3126) {
    int i = b * 256 + threadIdx.x;
    if (i < NN * IN_F / 8) {
      float4 a = *reinterpret_cast<const float4*>(&feat[i * 8]);
      float4 c = *reinterpret_cast<const float4*>(&feat[i * 8 + 4]);
      ushort8 o;
      o[0] = f2bf(a.x); o[1] = f2bf(a.y); o[2] = f2bf(a.z); o[3] = f2bf(a.w);
      o[4] = f2bf(c.x); o[5] = f2bf(c.y); o[6] = f2bf(c.z); o[7] = f2bf(c.w);
      *reinterpret_cast<ushort8*>(&featbf[i * 8]) = o;
    }
  } else {
    int wb = b - 3126;
    WDesc w = p.d[wb >> 5];
    int xb = wb & 31;
    int total = w.rows << w.cshift;
    int cmask = (1 << w.cshift) - 1;
    for (int idx = xb * 256 + threadIdx.x; idx < total; idx += 32 * 256) {
      int r = idx >> w.cshift, c = idx & cmask;
      wts[w.dofs + (size_t)c * w.ldk + w.kofs + r] = f2bf(w.src[idx]);
    }
  }
}

// ---------------- fused head weights ----------------
__global__ __launch_bounds__(128) void fuse_w_kernel(
    const float* __restrict__ wl2s, const float* __restrict__ wl2n,
    const float* __restrict__ wg1s, const float* __restrict__ wg1n,
    const float* __restrict__ w1, const float* __restrict__ bl2,
    const float* __restrict__ bg1, const float* __restrict__ b1,
    unsigned short* __restrict__ wf, float* __restrict__ bfused) {
  int b = blockIdx.x;
  int c = threadIdx.x;  // 0..127
  __shared__ float row[256];
  if (b < 1024) {
    int seg = b >> 8, i = b & 255;
    const float* W = (seg == 0) ? wl2s : (seg == 1) ? wl2n : (seg == 2) ? wg1s : wg1n;
    const float* w1b = w1 + ((seg < 2) ? 0 : 256) * MLPH;
    row[c] = W[i * 256 + c];
    row[c + 128] = W[i * 256 + 128 + c];
    __syncthreads();
    float acc = 0.f;
    for (int o = 0; o < 256; ++o) acc += row[o] * w1b[o * MLPH + c];
    wf[(size_t)c * 1024 + seg * 256 + i] = f2bf(acc);
  } else {
    float acc = b1[c];
    for (int o = 0; o < 256; ++o) acc += bl2[o] * w1[o * MLPH + c];
    for (int o = 0; o < 256; ++o) acc += bg1[o] * w1[(256 + o) * MLPH + c];
    bfused[c] = acc;
  }
}

// ---------------- edge bucketing: pack (dst<<16)|src, range-sorted per block ----------
__global__ __launch_bounds__(256) void bucket_kernel(const int* __restrict__ g_src,
                                                     const int* __restrict__ g_dst,
                                                     const int* __restrict__ k_src,
                                                     const int* __restrict__ k_dst,
                                                     int* __restrict__ gcnt,      // [16]
                                                     unsigned* __restrict__ bkt_g,
                                                     unsigned* __restrict__ bkt_k) {
  __shared__ unsigned buf[2048];
  __shared__ int rcnt[8], rbase[8], roff[8];
  const int gr = blockIdx.y;
  const int* src = gr ? k_src : g_src;
  const int* dst = gr ? k_dst : g_dst;
  unsigned* bkt = gr ? bkt_k : bkt_g;
  const int CAP = gr ? CAPK : CAPG;
  const int E = gr ? EK : EG;
  int* gc = gcnt + gr * 8;
  const int tid = threadIdx.x;
  const int e0 = blockIdx.x * 2048;
  if (e0 >= E) return;
  if (tid < 8) rcnt[tid] = 0;
  __syncthreads();
  unsigned vloc[8];
  int rloc[8], ploc[8];
#pragma unroll
  for (int i = 0; i < 8; ++i) {
    int e = e0 + i * 256 + tid;
    rloc[i] = -1;
    if (e < E) {
      int d = dst[e], s = src[e];
      int r = d / RNG;
      vloc[i] = ((unsigned)d << 16) | (unsigned)s;
      rloc[i] = r;
      ploc[i] = atomicAdd(&rcnt[r], 1);
    }
  }
  __syncthreads();
  if (tid == 0) {
    int acc = 0;
#pragma unroll
    for (int r = 0; r < 8; ++r) { roff[r] = acc; acc += rcnt[r]; }
  }
  __syncthreads();
#pragma unroll
  for (int i = 0; i < 8; ++i)
    if (rloc[i] >= 0) buf[roff[rloc[i]] + ploc[i]] = vloc[i];
  __syncthreads();
  if (tid < 8) rbase[tid] = atomicAdd(&gc[tid], rcnt[tid]);
  __syncthreads();
#pragma unroll
  for (int r = 0; r < 8; ++r) {
    int len = rcnt[r];
    unsigned* dstp = bkt + (size_t)r * CAP + rbase[r];
    for (int i = tid; i < len; i += 256) dstp[i] = buf[roff[r] + i];
  }
}

// ---------------- per-range count from bucket (LDS histogram) ----------------
__global__ __launch_bounds__(256) void count_bucket(const unsigned* __restrict__ bkt_g,
                                                    const unsigned* __restrict__ bkt_k,
                                                    const int* __restrict__ gcnt,
                                                    int* __restrict__ cnt_g,
                                                    int* __restrict__ cnt_k, int CC) {
  __shared__ int hist[RNG];
  const int r = blockIdx.x, gr = blockIdx.y, z = blockIdx.z;
  const unsigned* b = (gr ? bkt_k : bkt_g) + (size_t)r * (gr ? CAPK : CAPG);
  int* cnt = gr ? cnt_k : cnt_g;
  const int n = gcnt[gr * 8 + r];
  const unsigned lo = r * RNG;
  for (int i = threadIdx.x; i < RNG; i += 256) hist[i] = 0;
  __syncthreads();
  for (int i = z * 256 + threadIdx.x; i < n; i += CC * 256) {
    unsigned d = (b[i] >> 16) - lo;
    atomicAdd(&hist[d], 1);
  }
  __syncthreads();
  for (int i = threadIdx.x; i < RNG; i += 256) {
    int v = hist[i];
    if (v) atomicAdd(&cnt[lo + i], v);
  }
}

// ---------------- parallel scans for both graphs ----------------
__global__ __launch_bounds__(256) void scan_partial2(const int* __restrict__ cnt_g,
                                                     const int* __restrict__ cnt_k,
                                                     int* __restrict__ part, int n) {
  const int* cnt = blockIdx.y ? cnt_k : cnt_g;
  int* pp = part + blockIdx.y * 256;
  int i = blockIdx.x * 256 + threadIdx.x;
  int v = (i < n) ? cnt[i] : 0;
  __shared__ int ws[4];
  int lane = threadIdx.x & 63, wid = threadIdx.x >> 6;
  int x = v;
#pragma unroll
  for (int d = 1; d < 64; d <<= 1) { int y = __shfl_up(x, d, 64); if (lane >= d) x += y; }
  if (lane == 63) ws[wid] = x;
  __syncthreads();
  if (threadIdx.x == 0) pp[blockIdx.x] = ws[0] + ws[1] + ws[2] + ws[3];
}

__global__ __launch_bounds__(256) void scan_block2(int* __restrict__ part, int np) {
  int* pp = part + blockIdx.x * 256;
  __shared__ int ws[4];
  int tid = threadIdx.x, lane = tid & 63, wid = tid >> 6;
  int v = (tid < np) ? pp[tid] : 0;
  int x = v;
#pragma unroll
  for (int d = 1; d < 64; d <<= 1) { int y = __shfl_up(x, d, 64); if (lane >= d) x += y; }
  if (lane == 63) ws[wid] = x;
  __syncthreads();
  int add = 0;
#pragma unroll
  for (int k = 0; k < 4; ++k) if (k < wid) add += ws[k];
  if (tid < np) pp[tid] = x - v + add;
}

__global__ __launch_bounds__(256) void scan_final2(const int* __restrict__ cnt_g,
                                                   const int* __restrict__ cnt_k,
                                                   const int* __restrict__ part,
                                                   int* __restrict__ off_g,
                                                   int* __restrict__ off_k,
                                                   float* __restrict__ invg,
                                                   float* __restrict__ invk, int n) {
  const int* cnt = blockIdx.y ? cnt_k : cnt_g;
  const int* pp = part + blockIdx.y * 256;
  int* off = blockIdx.y ? off_k : off_g;
  float* inv = blockIdx.y ? invk : invg;
  int total = blockIdx.y ? EK : EG;
  int i = blockIdx.x * 256 + threadIdx.x;
  int v = (i < n) ? cnt[i] : 0;
  __shared__ int ws[4];
  int lane = threadIdx.x & 63, wid = threadIdx.x >> 6;
  int x = v;
#pragma unroll
  for (int d = 1; d < 64; d <<= 1) { int y = __shfl_up(x, d, 64); if (lane >= d) x += y; }
  if (lane == 63) ws[wid] = x;
  __syncthreads();
  int add = pp[blockIdx.x];
#pragma unroll
  for (int k = 0; k < 4; ++k) if (k < wid) add += ws[k];
  if (i < n) {
    off[i] = x - v + add;
    inv[i] = 1.0f / fmaxf((float)v, 1.0f);
  }
  if (i == 0) off[n] = total;
}

// ---------------- CSR fill from range bucket (XCD-local, all lanes active) ----------
__global__ __launch_bounds__(256) void fill_bucket(const unsigned* __restrict__ bkt_g,
                                                   const unsigned* __restrict__ bkt_k,
                                                   const int* __restrict__ gcnt,
                                                   const int* __restrict__ off_g,
                                                   const int* __restrict__ off_k,
                                                   int* __restrict__ cur_g,
                                                   int* __restrict__ cur_k,
                                                   unsigned short* __restrict__ e16g,
                                                   unsigned short* __restrict__ e16k, int FC) {
  const int r = blockIdx.x, gr = blockIdx.y, z = blockIdx.z;
  const unsigned* b = (gr ? bkt_k : bkt_g) + (size_t)r * (gr ? CAPK : CAPG);
  const int* off = gr ? off_k : off_g;
  int* cur = gr ? cur_k : cur_g;
  unsigned short* e16 = gr ? e16k : e16g;
  const int n = gcnt[gr * 8 + r];
  for (int i = z * 256 + (int)threadIdx.x; i < n; i += FC * 256) {
    unsigned v = b[i];
    int d = v >> 16;
    int pz = atomicAdd(&cur[d], 1);
    e16[off[d] + pz] = (unsigned short)(v & 0xffffu);
  }
}

// ---------------- CSR mean-aggregation (bf16 in/out, ushort esrc), unroll-4 ----------
template <int DLOG2>
__global__ __launch_bounds__(256) void csr_aggregate(const unsigned short* __restrict__ h,
                                                     const int* __restrict__ off,
                                                     const unsigned short* __restrict__ esrc,
                                                     const float* __restrict__ inv,
                                                     unsigned short* __restrict__ out) {
  constexpr int TPN = (1 << DLOG2) / 8;
  constexpr int NPB = 256 / TPN;
  int node = blockIdx.x * NPB + ((int)threadIdx.x / TPN);
  int lane = threadIdx.x & (TPN - 1);
  if (node >= NN) return;
  int s = off[node], e = off[node + 1];
  float acc[8] = {0.f, 0.f, 0.f, 0.f, 0.f, 0.f, 0.f, 0.f};
  int j = s;
  for (; j + 3 < e; j += 4) {
    int s0 = esrc[j], s1 = esrc[j + 1], s2 = esrc[j + 2], s3 = esrc[j + 3];
    ushort8 v0 = *reinterpret_cast<const ushort8*>(&h[((size_t)s0 << DLOG2) + lane * 8]);
    ushort8 v1 = *reinterpret_cast<const ushort8*>(&h[((size_t)s1 << DLOG2) + lane * 8]);
    ushort8 v2 = *reinterpret_cast<const ushort8*>(&h[((size_t)s2 << DLOG2) + lane * 8]);
    ushort8 v3 = *reinterpret_cast<const ushort8*>(&h[((size_t)s3 << DLOG2) + lane * 8]);
#pragma unroll
    for (int i = 0; i < 8; ++i) acc[i] += bf2f(v0[i]);
#pragma unroll
    for (int i = 0; i < 8; ++i) acc[i] += bf2f(v1[i]);
#pragma unroll
    for (int i = 0; i < 8; ++i) acc[i] += bf2f(v2[i]);
#pragma unroll
    for (int i = 0; i < 8; ++i) acc[i] += bf2f(v3[i]);
  }
  for (; j < e; ++j) {
    int s0 = esrc[j];
    ushort8 v0 = *reinterpret_cast<const ushort8*>(&h[((size_t)s0 << DLOG2) + lane * 8]);
#pragma unroll
    for (int i = 0; i < 8; ++i) acc[i] += bf2f(v0[i]);
  }
  float sc = inv[node];
  ushort8 o;
#pragma unroll
  for (int i = 0; i < 8; ++i) o[i] = f2bf(acc[i] * sc);
  *reinterpret_cast<ushort8*>(&out[((size_t)node << DLOG2) + lane * 8]) = o;
}

// ---------------- MFMA GEMM, BM=128 x BN=128, BK=64, global_load_lds staging --------
template <int K1, int K2, bool RELU, bool OUT_BF16>
__global__ __launch_bounds__(256) void gemm_gl(
    const unsigned short* __restrict__ A1, const unsigned short* __restrict__ A2,
    const unsigned short* __restrict__ Bt, const float* __restrict__ bias,
    void* __restrict__ outv, int ldo, int nrows) {
  constexpr int KTOT = K1 + K2;
  constexpr int KT = KTOT / 64;
  __shared__ char smem[32768];
  unsigned short* sA = (unsigned short*)smem;
  unsigned short* sB = sA + 8192;

  const int t = threadIdx.x;
  const int lane = t & 63;
  const int w = t >> 6;
  const int wm = (w & 1) * 64, wn = (w >> 1) * 64;
  const int row0 = blockIdx.y * 128;
  const int n0 = blockIdx.x * 128;

  const int srow = (w << 5) + (lane >> 3);
  const int schunk = (lane & 7) << 3;

  f32x4 acc[4][4] = {};

  for (int kt = 0; kt < KT; ++kt) {
    const int kbase = kt * 64;
    const unsigned short* Asrc = (kbase < K1) ? A1 : A2;
    const int kA = (kbase < K1) ? kbase : (kbase - K1);
    const int lda = (kbase < K1) ? K1 : K2;
#pragma unroll
    for (int q = 0; q < 4; ++q) {
      int rA = srow + q * 8;
      int rowg = row0 + rA;
      if (rowg >= nrows) rowg = nrows - 1;
      gload_lds16(Asrc + (size_t)rowg * lda + kA + schunk,
                  sA + ((w << 5) + q * 8) * 64);
      gload_lds16(Bt + (size_t)(n0 + rA) * KTOT + kbase + schunk,
                  sB + ((w << 5) + q * 8) * 64);
    }
    __syncthreads();
#pragma unroll
    for (int kk = 0; kk < 2; ++kk) {
      const int ko = kk * 32 + (lane >> 4) * 8;
      short8 a[4], b[4];
#pragma unroll
      for (int mi = 0; mi < 4; ++mi)
        a[mi] = *reinterpret_cast<const short8*>(&sA[(wm + mi * 16 + (lane & 15)) * 64 + ko]);
#pragma unroll
      for (int ni = 0; ni < 4; ++ni)
        b[ni] = *reinterpret_cast<const short8*>(&sB[(wn + ni * 16 + (lane & 15)) * 64 + ko]);
#pragma unroll
      for (int mi = 0; mi < 4; ++mi)
#pragma unroll
        for (int ni = 0; ni < 4; ++ni)
          acc[mi][ni] = __builtin_amdgcn_mfma_f32_16x16x32_bf16(a[mi], b[ni], acc[mi][ni], 0, 0, 0);
    }
    __syncthreads();
  }

  float* Co = (float*)smem;
#pragma unroll
  for (int h = 0; h < 2; ++h) {
    __syncthreads();
    if ((w >> 1) == h) {
#pragma unroll
      for (int mi = 0; mi < 4; ++mi)
#pragma unroll
        for (int ni = 0; ni < 4; ++ni) {
          int col = ni * 16 + (lane & 15);
          int rowb = wm + mi * 16 + (lane >> 4) * 4;
#pragma unroll
          for (int j = 0; j < 4; ++j) Co[(rowb + j) * 64 + col] = acc[mi][ni][j];
        }
    }
    __syncthreads();
    int sr = t >> 1, cb = (t & 1) * 32;
    int r = row0 + sr;
    if (r < nrows) {
      float v[32];
#pragma unroll
      for (int i = 0; i < 32; ++i) {
        v[i] = Co[sr * 64 + cb + i] + bias[n0 + h * 64 + cb + i];
        if (RELU) v[i] = fmaxf(v[i], 0.f);
      }
      if (OUT_BF16) {
        unsigned short* dst = (unsigned short*)outv + (size_t)r * ldo + n0 + h * 64 + cb;
#pragma unroll
        for (int q = 0; q < 4; ++q) {
          ushort8 o;
#pragma unroll
          for (int i = 0; i < 8; ++i) o[i] = f2bf(v[q * 8 + i]);
          *reinterpret_cast<ushort8*>(dst + q * 8) = o;
        }
      } else {
        float* dst = (float*)outv + (size_t)r * ldo + n0 + h * 64 + cb;
#pragma unroll
        for (int q = 0; q < 8; ++q) {
          float4 o = make_float4(v[4 * q], v[4 * q + 1], v[4 * q + 2], v[4 * q + 3]);
          *reinterpret_cast<float4*>(dst + 4 * q) = o;
        }
      }
    }
  }
}

// ---------------- fused tail GEMM: 4 x K=256 A-segments, N=128, f32 out ----------------
__global__ __launch_bounds__(256) void gemm_gl4(
    const unsigned short* __restrict__ A0, const unsigned short* __restrict__ A1,
    const unsigned short* __restrict__ A2, const unsigned short* __restrict__ A3,
    const unsigned short* __restrict__ Bt, const float* __restrict__ bias,
    float* __restrict__ outv, int nrows) {
  constexpr int KTOT = 1024;
  constexpr int KT = 16;
  __shared__ char smem[32768];
  unsigned short* sA = (unsigned short*)smem;
  unsigned short* sB = sA + 8192;

  const int t = threadIdx.x;
  const int lane = t & 63;
  const int w = t >> 6;
  const int wm = (w & 1) * 64, wn = (w >> 1) * 64;
  const int row0 = blockIdx.y * 128;

  const int srow = (w << 5) + (lane >> 3);
  const int schunk = (lane & 7) << 3;

  f32x4 acc[4][4] = {};

  for (int kt = 0; kt < KT; ++kt) {
    const int seg = kt >> 2;
    const unsigned short* Asrc = (seg == 0) ? A0 : (seg == 1) ? A1 : (seg == 2) ? A2 : A3;
    const int kA = (kt & 3) * 64;
#pragma unroll
    for (int q = 0; q < 4; ++q) {
      int rA = srow + q * 8;
      int rowg = row0 + rA;
      if (rowg >= nrows) rowg = nrows - 1;
      gload_lds16(Asrc + (size_t)rowg * 256 + kA + schunk,
                  sA + ((w << 5) + q * 8) * 64);
      gload_lds16(Bt + (size_t)rA * KTOT + kt * 64 + schunk,
                  sB + ((w << 5) + q * 8) * 64);
    }
    __syncthreads();
#pragma unroll
    for (int kk = 0; kk < 2; ++kk) {
      const int ko = kk * 32 + (lane >> 4) * 8;
      short8 a[4], b[4];
#pragma unroll
      for (int mi = 0; mi < 4; ++mi)
        a[mi] = *reinterpret_cast<const short8*>(&sA[(wm + mi * 16 + (lane & 15)) * 64 + ko]);
#pragma unroll
      for (int ni = 0; ni < 4; ++ni)
        b[ni] = *reinterpret_cast<const short8*>(&sB[(wn + ni * 16 + (lane & 15)) * 64 + ko]);
#pragma unroll
      for (int mi = 0; mi < 4; ++mi)
#pragma unroll
        for (int ni = 0; ni < 4; ++ni)
          acc[mi][ni] = __builtin_amdgcn_mfma_f32_16x16x32_bf16(a[mi], b[ni], acc[mi][ni], 0, 0, 0);
    }
    __syncthreads();
  }

  float* Co = (float*)smem;
#pragma unroll
  for (int h = 0; h < 2; ++h) {
    __syncthreads();
    if ((w >> 1) == h) {
#pragma unroll
      for (int mi = 0; mi < 4; ++mi)
#pragma unroll
        for (int ni = 0; ni < 4; ++ni) {
          int col = ni * 16 + (lane & 15);
          int rowb = wm + mi * 16 + (lane >> 4) * 4;
#pragma unroll
          for (int j = 0; j < 4; ++j) Co[(rowb + j) * 64 + col] = acc[mi][ni][j];
        }
    }
    __syncthreads();
    int sr = t >> 1, cb = (t & 1) * 32;
    int r = row0 + sr;
    if (r < nrows) {
      float* dst = outv + (size_t)r * MLPH + h * 64 + cb;
#pragma unroll
      for (int q = 0; q < 8; ++q) {
        float4 o;
        o.x = Co[sr * 64 + cb + 4 * q + 0] + bias[h * 64 + cb + 4 * q + 0];
        o.y = Co[sr * 64 + cb + 4 * q + 1] + bias[h * 64 + cb + 4 * q + 1];
        o.z = Co[sr * 64 + cb + 4 * q + 2] + bias[h * 64 + cb + 4 * q + 2];
        o.w = Co[sr * 64 + cb + 4 * q + 3] + bias[h * 64 + cb + 4 * q + 3];
        *reinterpret_cast<float4*>(dst + 4 * q) = o;
      }
    }
  }
}

// ---------------- BN ----------------
__global__ __launch_bounds__(256) void bn_stats_kernel(const float* __restrict__ x,
                                                       float* __restrict__ sums,
                                                       float* __restrict__ sumsq) {
  int c = threadIdx.x & 127;
  int rbase = (blockIdx.x * 256 + threadIdx.x) >> 7;
  int stride = (gridDim.x * 256) >> 7;
  float s = 0.f, s2 = 0.f;
  for (int r = rbase; r < NN; r += stride) {
    float v = x[(size_t)r * 128 + c];
    s += v;
    s2 += v * v;
  }
  __shared__ float ls[256], ls2[256];
  ls[threadIdx.x] = s;
  ls2[threadIdx.x] = s2;
  __syncthreads();
  if (threadIdx.x < 128) {
    s = ls[threadIdx.x] + ls[threadIdx.x + 128];
    s2 = ls2[threadIdx.x] + ls2[threadIdx.x + 128];
    atomicAdd(&sums[c], s);
    atomicAdd(&sumsq[c], s2);
  }
}

__global__ __launch_bounds__(128) void bn_finalize_kernel(float* __restrict__ stats,
                                                          const float* __restrict__ gamma,
                                                          const float* __restrict__ beta) {
  int c = threadIdx.x;
  float mu = stats[c] * (1.0f / NN);
  float var = stats[128 + c] * (1.0f / NN) - mu * mu;
  var = fmaxf(var, 0.f);
  float sc = gamma[c] * rsqrtf(var + BN_EPS);
  stats[256 + c] = sc;
  stats[384 + c] = beta[c] - mu * sc;
}

// ---------------- final head GEMM with fused BN+ReLU on A-load (64x64) ----------------
template <int K1, bool RELU>
__global__ __launch_bounds__(256) void gemm_mfma_bn(
    const float* __restrict__ A1v, const unsigned short* __restrict__ Bt,
    const float* __restrict__ bias, const float* __restrict__ bnscale,
    const float* __restrict__ bnshift, float* __restrict__ outv, int ldo, int nrows) {
  constexpr int KT = K1 / 64;
  constexpr int LDT = 72;
  __shared__ char smem[2 * 64 * LDT * 2];
  unsigned short* As = (unsigned short*)smem;
  unsigned short* Bs = As + 64 * LDT;
  float* Co = (float*)smem;
  constexpr int LDC = 68;

  const int t = threadIdx.x;
  const int lane = t & 63;
  const int w = t >> 6;
  const int wm = (w & 1) * 32, wn = (w >> 1) * 32;
  const int row0 = blockIdx.y * 64;
  const int n0 = blockIdx.x * 64;

  const int sr = t >> 2;
  const int skc = (t & 3) * 16;
  int rg = row0 + sr;
  if (rg >= nrows) rg = nrows - 1;

  f32x4 acc[2][2] = {};

  for (int kt = 0; kt < KT; ++kt) {
    const int kbase = kt * 64;
    {
      const float* xb = A1v + (size_t)rg * K1 + kbase + skc;
      ushort8 o0, o1;
#pragma unroll
      for (int i = 0; i < 8; ++i) {
        float v = xb[i] * bnscale[kbase + skc + i] + bnshift[kbase + skc + i];
        o0[i] = f2bf(fmaxf(v, 0.f));
      }
#pragma unroll
      for (int i = 0; i < 8; ++i) {
        float v = xb[8 + i] * bnscale[kbase + skc + 8 + i] + bnshift[kbase + skc + 8 + i];
        o1[i] = f2bf(fmaxf(v, 0.f));
      }
      *reinterpret_cast<ushort8*>(&As[sr * LDT + skc]) = o0;
      *reinterpret_cast<ushort8*>(&As[sr * LDT + skc + 8]) = o1;
    }
    {
      const unsigned short* bb = Bt + (size_t)(n0 + sr) * K1 + kbase + skc;
      int4 p0 = *reinterpret_cast<const int4*>(bb);
      int4 p1 = *reinterpret_cast<const int4*>(bb + 8);
      *reinterpret_cast<int4*>(&Bs[sr * LDT + skc]) = p0;
      *reinterpret_cast<int4*>(&Bs[sr * LDT + skc + 8]) = p1;
    }
    __syncthreads();
#pragma unroll
    for (int kk = 0; kk < 2; ++kk) {
      const int ko = kk * 32 + (lane >> 4) * 8;
      short8 a0 = *reinterpret_cast<const short8*>(&As[(wm + (lane & 15)) * LDT + ko]);
      short8 a1 = *reinterpret_cast<const short8*>(&As[(wm + 16 + (lane & 15)) * LDT + ko]);
      short8 b0 = *reinterpret_cast<const short8*>(&Bs[(wn + (lane & 15)) * LDT + ko]);
      short8 b1 = *reinterpret_cast<const short8*>(&Bs[(wn + 16 + (lane & 15)) * LDT + ko]);
      acc[0][0] = __builtin_amdgcn_mfma_f32_16x16x32_bf16(a0, b0, acc[0][0], 0, 0, 0);
      acc[0][1] = __builtin_amdgcn_mfma_f32_16x16x32_bf16(a0, b1, acc[0][1], 0, 0, 0);
      acc[1][0] = __builtin_amdgcn_mfma_f32_16x16x32_bf16(a1, b0, acc[1][0], 0, 0, 0);
      acc[1][1] = __builtin_amdgcn_mfma_f32_16x16x32_bf16(a1, b1, acc[1][1], 0, 0, 0);
    }
    __syncthreads();
  }

#pragma unroll
  for (int mi = 0; mi < 2; ++mi)
#pragma unroll
    for (int ni = 0; ni < 2; ++ni) {
      int col = wn + ni * 16 + (lane & 15);
      int rowb = wm + mi * 16 + (lane >> 4) * 4;
#pragma unroll
      for (int j = 0; j < 4; ++j) Co[(rowb + j) * LDC + col] = acc[mi][ni][j];
    }
  __syncthreads();
  {
    int r = row0 + sr;
    if (r < nrows) {
      float v[16];
#pragma unroll
      for (int i = 0; i < 16; ++i) {
        v[i] = Co[sr * LDC + skc + i] + bias[n0 + skc + i];
        if (RELU) v[i] = fmaxf(v[i], 0.f);
      }
      float* dst = outv + (size_t)r * ldo + n0 + skc;
#pragma unroll
      for (int i = 0; i < 4; ++i) {
        float4 o = make_float4(v[4 * i], v[4 * i + 1], v[4 * i + 2], v[4 * i + 3]);
        *reinterpret_cast<float4*>(dst + 4 * i) = o;
      }
    }
  }
}

// ---------------- launch ----------------
extern "C" void kernel_launch(void* const* d_in, const int* in_sizes, int n_in,
                              void* d_out, int out_size, void* d_ws, size_t ws_size,
                              hipStream_t stream) {
  const float* feat = (const float*)d_in[0];
  const int* g_src = (const int*)d_in[1];
  const int* g_dst = (const int*)d_in[2];
  const int* k_src = (const int*)d_in[3];
  const int* k_dst = (const int*)d_in[4];
  const float* lb_0 = (const float*)d_in[7];
  const float* lb_1 = (const float*)d_in[10];
  const float* lb_2 = (const float*)d_in[13];
  const float* gb_0 = (const float*)d_in[16];
  const float* gb_1 = (const float*)d_in[19];
  const float* mlp_b1 = (const float*)d_in[21];
  const float* bn_gamma = (const float*)d_in[22];
  const float* bn_beta = (const float*)d_in[23];
  const float* mlp_b2 = (const float*)d_in[25];
  float* out = (float*)d_out;

  // workspace layout (all section starts 16B-aligned)
  float* xf32 = (float*)d_ws;                         // N*128 f32
  int* cnt_g = (int*)(xf32 + (size_t)NN * 128);       // N
  int* cnt_k = cnt_g + NN;                            // N
  int* cur_g = cnt_k + NN;                            // N
  int* cur_k = cur_g + NN;                            // N
  float* stats = (float*)(cur_k + NN);                // 512
  int* gcnt = (int*)(stats + 512);                    // 16 (zeroed with block above)
  float* invg = (float*)(gcnt + 16);                  // N
  float* invk = invg + NN;                            // N
  int* off_g = (int*)(invk + NN);                     // N+4
  int* off_k = off_g + NN + 4;                        // N+4
  int* part = off_k + NN + 4;                         // 512
  unsigned* bkt_g = (unsigned*)(part + 512);          // 8*CAPG
  unsigned* bkt_k = bkt_g + 8 * CAPG;                 // 8*CAPK
  unsigned short* e16g = (unsigned short*)(bkt_k + 8 * CAPK);  // EG
  unsigned short* e16k = e16g + EG;                   // EK
  unsigned short* featbf = e16k + EK;                 // N*128
  unsigned short* wts = featbf + (size_t)NN * IN_F;   // 598016
  unsigned short* wf = wts + 598016;                  // 131072
  float* bfused = (float*)(wf + 131072);              // 128
  unsigned short* bfA = (unsigned short*)(bfused + 128);  // N*256
  unsigned short* bfB = bfA + (size_t)NN * HF;        // N*256
  unsigned short* bfAgg = bfB + (size_t)NN * HF;      // N*256
  unsigned short* bfD = bfAgg + (size_t)NN * HF;      // N*256

  const int wL0 = 0, wL1 = 65536, wG0 = 327680, wH2 = 589824;

  dim3 blk(256);
  const int NB = (NN + 255) / 256;        // 196
  const int MB = (NN + 127) / 128;        // 391
  const dim3 gridH(2, MB);
  const dim3 grid4(1, MB);
  const int agg128_blocks = (NN + 15) / 16;
  const int agg256_blocks = (NN + 7) / 8;
  const int BKB = (EK + 2047) / 2048;     // 391 bucket chunks (max of both graphs)
  const int CC = 8;                       // count_bucket z-chunks
  const int FC = 16;                      // fill_bucket z-chunks

  // zero cnt_g, cnt_k, cur_g, cur_k, stats, gcnt in one go
  hipMemsetAsync(cnt_g, 0, (size_t)(4 * NN) * sizeof(int) + 512 * sizeof(float) + 16 * sizeof(int),
                 stream);

  WPack p;
  p.d[0] = {(const float*)d_in[5], 128, 8, 0, 256, wL0};
  p.d[1] = {(const float*)d_in[6], 128, 8, 128, 256, wL0};
  p.d[2] = {(const float*)d_in[8], 256, 8, 0, 512, wL1};
  p.d[3] = {(const float*)d_in[9], 256, 8, 256, 512, wL1};
  p.d[4] = {(const float*)d_in[11], 256, 8, 0, 512, 196608};  // folded; kept for layout
  p.d[5] = {(const float*)d_in[12], 256, 8, 256, 512, 196608};
  p.d[6] = {(const float*)d_in[14], 128, 8, 0, 256, wG0};
  p.d[7] = {(const float*)d_in[15], 128, 8, 128, 256, wG0};
  p.d[8] = {(const float*)d_in[17], 256, 8, 0, 512, 393216};  // folded
  p.d[9] = {(const float*)d_in[18], 256, 8, 256, 512, 393216};
  p.d[10] = {(const float*)d_in[20], 512, 7, 0, 512, 524288}; // folded
  p.d[11] = {(const float*)d_in[24], 128, 6, 0, 128, wH2};
  prep_kernel<<<3510, blk, 0, stream>>>(feat, featbf, p, wts);

  // fused head weights
  fuse_w_kernel<<<1025, 128, 0, stream>>>(
      (const float*)d_in[11], (const float*)d_in[12],
      (const float*)d_in[17], (const float*)d_in[18],
      (const float*)d_in[20], lb_2, gb_1, mlp_b1, wf, bfused);

  // ---- CSR build: bucket -> count -> scan -> fill ----
  bucket_kernel<<<dim3(BKB, 2), blk, 0, stream>>>(g_src, g_dst, k_src, k_dst, gcnt, bkt_g, bkt_k);
  count_bucket<<<dim3(8, 2, CC), blk, 0, stream>>>(bkt_g, bkt_k, gcnt, cnt_g, cnt_k, CC);
  scan_partial2<<<dim3(NB, 2), blk, 0, stream>>>(cnt_g, cnt_k, part, NN);
  scan_block2<<<2, blk, 0, stream>>>(part, NB);
  scan_final2<<<dim3(NB, 2), blk, 0, stream>>>(cnt_g, cnt_k, part, off_g, off_k, invg, invk, NN);
  fill_bucket<<<dim3(8, 2, FC), blk, 0, stream>>>(bkt_g, bkt_k, gcnt, off_g, off_k,
                                                  cur_g, cur_k, e16g, e16k, FC);

  // ---- local layer 0 ----
  csr_aggregate<7><<<agg128_blocks, blk, 0, stream>>>(featbf, off_g, e16g, invg, bfAgg);
  gemm_gl<128, 128, true, true><<<gridH, blk, 0, stream>>>(
      featbf, bfAgg, wts + wL0, lb_0, bfA, HF, NN);
  // ---- local layer 1 ----
  csr_aggregate<8><<<agg256_blocks, blk, 0, stream>>>(bfA, off_g, e16g, invg, bfAgg);
  gemm_gl<256, 256, true, true><<<gridH, blk, 0, stream>>>(
      bfA, bfAgg, wts + wL1, lb_1, bfB, HF, NN);
  // ---- agg for folded local layer 2 -> bfD ----
  csr_aggregate<8><<<agg256_blocks, blk, 0, stream>>>(bfB, off_g, e16g, invg, bfD);
  // ---- global layer 0 -> bfA ----
  csr_aggregate<7><<<agg128_blocks, blk, 0, stream>>>(featbf, off_k, e16k, invk, bfAgg);
  gemm_gl<128, 128, true, true><<<gridH, blk, 0, stream>>>(
      featbf, bfAgg, wts + wG0, gb_0, bfA, HF, NN);
  // ---- agg for folded global layer 1 -> bfAgg ----
  csr_aggregate<8><<<agg256_blocks, blk, 0, stream>>>(bfA, off_k, e16k, invk, bfAgg);

  // ---- fused tail GEMM ----
  gemm_gl4<<<grid4, blk, 0, stream>>>(bfB, bfD, bfA, bfAgg, wf, bfused, xf32, NN);

  // ---- BatchNorm ----
  bn_stats_kernel<<<256, blk, 0, stream>>>(xf32, stats, stats + 128);
  bn_finalize_kernel<<<1, 128, 0, stream>>>(stats, bn_gamma, bn_beta);

  // ---- head GEMM2 ----
  gemm_mfma_bn<128, false><<<dim3(1, (NN + 63) / 64), blk, 0, stream>>>(
      xf32, wts + wH2, mlp_b2, stats + 256, stats + 384, out, COUT, NN);
}

// Round 12
// 506.762 us; speedup vs baseline: 1.3421x; 1.0615x over previous
//
#include <hip/hip_runtime.h>

#define NN   50000
#define IN_F 128
#define HF   256
#define COUT 64
#define MLPH 128
#define EG   600000
#define EK   800000
#define RNG  6250    // NN / 8
#define CAPG 80000
#define CAPK 106000
#define BN_EPS 1e-5f

typedef __attribute__((ext_vector_type(8))) short short8;
typedef __attribute__((ext_vector_type(8))) unsigned short ushort8;
typedef __attribute__((ext_vector_type(4))) float f32x4;

__device__ __forceinline__ unsigned short f2bf(float f) {
  union { float f; unsigned int u; } v; v.f = f;
  unsigned int r = v.u + 0x7FFFu + ((v.u >> 16) & 1u);
  return (unsigned short)(r >> 16);
}
__device__ __forceinline__ float bf2f(unsigned short s) {
  union { unsigned int u; float f; } v; v.u = ((unsigned int)s) << 16;
  return v.f;
}

__device__ __forceinline__ void gload_lds16(const void* g, void* l) {
  __builtin_amdgcn_global_load_lds((const __attribute__((address_space(1))) void*)g,
                                   (__attribute__((address_space(3))) void*)l, 16, 0, 0);
}

struct WDesc { const float* src; int rows; int cshift; int kofs; int ldk; int dofs; };
struct WPack { WDesc d[12]; };

// ---------------- prep: feat->bf16, weight transpose ----------------
__global__ __launch_bounds__(256) void prep_kernel(const float* __restrict__ feat,
                                                   unsigned short* __restrict__ featbf,
                                                   WPack p, unsigned short* __restrict__ wts) {
  int b = blockIdx.x;
  if (b < 3126) {
    int i = b * 256 + threadIdx.x;
    if (i < NN * IN_F / 8) {
      float4 a = *reinterpret_cast<const float4*>(&feat[i * 8]);
      float4 c = *reinterpret_cast<const float4*>(&feat[i * 8 + 4]);
      ushort8 o;
      o[0] = f2bf(a.x); o[1] = f2bf(a.y); o[2] = f2bf(a.z); o[3] = f2bf(a.w);
      o[4] = f2bf(c.x); o[5] = f2bf(c.y); o[6] = f2bf(c.z); o[7] = f2bf(c.w);
      *reinterpret_cast<ushort8*>(&featbf[i * 8]) = o;
    }
  } else {
    int wb = b - 3126;
    WDesc w = p.d[wb >> 5];
    int xb = wb & 31;
    int total = w.rows << w.cshift;
    int cmask = (1 << w.cshift) - 1;
    for (int idx = xb * 256 + threadIdx.x; idx < total; idx += 32 * 256) {
      int r = idx >> w.cshift, c = idx & cmask;
      wts[w.dofs + (size_t)c * w.ldk + w.kofs + r] = f2bf(w.src[idx]);
    }
  }
}

// ---------------- fused head weights ----------------
// wf layout: [0..65535]       wf0: final tail Bt[c][512] = [seg0 | seg2]
//            [65536..98303]   wf1: Bt[c][256] = seg1 (pre-multiply for yl)
//            [98304..131071]  wf3: Bt[c][256] = seg3 (pre-multiply for yg)
__global__ __launch_bounds__(128) void fuse_w_kernel(
    const float* __restrict__ wl2s, const float* __restrict__ wl2n,
    const float* __restrict__ wg1s, const float* __restrict__ wg1n,
    const float* __restrict__ w1, const float* __restrict__ bl2,
    const float* __restrict__ bg1, const float* __restrict__ b1,
    unsigned short* __restrict__ wf, float* __restrict__ bfused) {
  int b = blockIdx.x;
  int c = threadIdx.x;  // 0..127
  __shared__ float row[256];
  if (b < 1024) {
    int seg = b >> 8, i = b & 255;
    const float* W = (seg == 0) ? wl2s : (seg == 1) ? wl2n : (seg == 2) ? wg1s : wg1n;
    const float* w1b = w1 + ((seg < 2) ? 0 : 256) * MLPH;
    row[c] = W[i * 256 + c];
    row[c + 128] = W[i * 256 + 128 + c];
    __syncthreads();
    float acc = 0.f;
    for (int o = 0; o < 256; ++o) acc += row[o] * w1b[o * MLPH + c];
    unsigned short v = f2bf(acc);
    if (seg == 0)      wf[(size_t)c * 512 + i] = v;
    else if (seg == 2) wf[(size_t)c * 512 + 256 + i] = v;
    else if (seg == 1) wf[65536 + (size_t)c * 256 + i] = v;
    else               wf[98304 + (size_t)c * 256 + i] = v;
  } else {
    float acc = b1[c];
    for (int o = 0; o < 256; ++o) acc += bl2[o] * w1[o * MLPH + c];
    for (int o = 0; o < 256; ++o) acc += bg1[o] * w1[(256 + o) * MLPH + c];
    bfused[c] = acc;
  }
}

// ---------------- edge bucketing ----------------
__global__ __launch_bounds__(256) void bucket_kernel(const int* __restrict__ g_src,
                                                     const int* __restrict__ g_dst,
                                                     const int* __restrict__ k_src,
                                                     const int* __restrict__ k_dst,
                                                     int* __restrict__ gcnt,
                                                     unsigned* __restrict__ bkt_g,
                                                     unsigned* __restrict__ bkt_k) {
  __shared__ unsigned buf[2048];
  __shared__ int rcnt[8], rbase[8], roff[8];
  const int gr = blockIdx.y;
  const int* src = gr ? k_src : g_src;
  const int* dst = gr ? k_dst : g_dst;
  unsigned* bkt = gr ? bkt_k : bkt_g;
  const int CAP = gr ? CAPK : CAPG;
  const int E = gr ? EK : EG;
  int* gc = gcnt + gr * 8;
  const int tid = threadIdx.x;
  const int e0 = blockIdx.x * 2048;
  if (e0 >= E) return;
  if (tid < 8) rcnt[tid] = 0;
  __syncthreads();
  unsigned vloc[8];
  int rloc[8], ploc[8];
#pragma unroll
  for (int i = 0; i < 8; ++i) {
    int e = e0 + i * 256 + tid;
    rloc[i] = -1;
    if (e < E) {
      int d = dst[e], s = src[e];
      int r = d / RNG;
      vloc[i] = ((unsigned)d << 16) | (unsigned)s;
      rloc[i] = r;
      ploc[i] = atomicAdd(&rcnt[r], 1);
    }
  }
  __syncthreads();
  if (tid == 0) {
    int acc = 0;
#pragma unroll
    for (int r = 0; r < 8; ++r) { roff[r] = acc; acc += rcnt[r]; }
  }
  __syncthreads();
#pragma unroll
  for (int i = 0; i < 8; ++i)
    if (rloc[i] >= 0) buf[roff[rloc[i]] + ploc[i]] = vloc[i];
  __syncthreads();
  if (tid < 8) rbase[tid] = atomicAdd(&gc[tid], rcnt[tid]);
  __syncthreads();
#pragma unroll
  for (int r = 0; r < 8; ++r) {
    int len = rcnt[r];
    unsigned* dstp = bkt + (size_t)r * CAP + rbase[r];
    for (int i = tid; i < len; i += 256) dstp[i] = buf[roff[r] + i];
  }
}

// ---------------- per-range count (LDS histogram) ----------------
__global__ __launch_bounds__(256) void count_bucket(const unsigned* __restrict__ bkt_g,
                                                    const unsigned* __restrict__ bkt_k,
                                                    const int* __restrict__ gcnt,
                                                    int* __restrict__ cnt_g,
                                                    int* __restrict__ cnt_k, int CC) {
  __shared__ int hist[RNG];
  const int r = blockIdx.x, gr = blockIdx.y, z = blockIdx.z;
  const unsigned* b = (gr ? bkt_k : bkt_g) + (size_t)r * (gr ? CAPK : CAPG);
  int* cnt = gr ? cnt_k : cnt_g;
  const int n = gcnt[gr * 8 + r];
  const unsigned lo = r * RNG;
  for (int i = threadIdx.x; i < RNG; i += 256) hist[i] = 0;
  __syncthreads();
  for (int i = z * 256 + threadIdx.x; i < n; i += CC * 256) {
    unsigned d = (b[i] >> 16) - lo;
    atomicAdd(&hist[d], 1);
  }
  __syncthreads();
  for (int i = threadIdx.x; i < RNG; i += 256) {
    int v = hist[i];
    if (v) atomicAdd(&cnt[lo + i], v);
  }
}

// ---------------- parallel scans ----------------
__global__ __launch_bounds__(256) void scan_partial2(const int* __restrict__ cnt_g,
                                                     const int* __restrict__ cnt_k,
                                                     int* __restrict__ part, int n) {
  const int* cnt = blockIdx.y ? cnt_k : cnt_g;
  int* pp = part + blockIdx.y * 256;
  int i = blockIdx.x * 256 + threadIdx.x;
  int v = (i < n) ? cnt[i] : 0;
  __shared__ int ws[4];
  int lane = threadIdx.x & 63, wid = threadIdx.x >> 6;
  int x = v;
#pragma unroll
  for (int d = 1; d < 64; d <<= 1) { int y = __shfl_up(x, d, 64); if (lane >= d) x += y; }
  if (lane == 63) ws[wid] = x;
  __syncthreads();
  if (threadIdx.x == 0) pp[blockIdx.x] = ws[0] + ws[1] + ws[2] + ws[3];
}

__global__ __launch_bounds__(256) void scan_block2(int* __restrict__ part, int np) {
  int* pp = part + blockIdx.x * 256;
  __shared__ int ws[4];
  int tid = threadIdx.x, lane = tid & 63, wid = tid >> 6;
  int v = (tid < np) ? pp[tid] : 0;
  int x = v;
#pragma unroll
  for (int d = 1; d < 64; d <<= 1) { int y = __shfl_up(x, d, 64); if (lane >= d) x += y; }
  if (lane == 63) ws[wid] = x;
  __syncthreads();
  int add = 0;
#pragma unroll
  for (int k = 0; k < 4; ++k) if (k < wid) add += ws[k];
  if (tid < np) pp[tid] = x - v + add;
}

__global__ __launch_bounds__(256) void scan_final2(const int* __restrict__ cnt_g,
                                                   const int* __restrict__ cnt_k,
                                                   const int* __restrict__ part,
                                                   int* __restrict__ off_g,
                                                   int* __restrict__ off_k,
                                                   float* __restrict__ invg,
                                                   float* __restrict__ invk, int n) {
  const int* cnt = blockIdx.y ? cnt_k : cnt_g;
  const int* pp = part + blockIdx.y * 256;
  int* off = blockIdx.y ? off_k : off_g;
  float* inv = blockIdx.y ? invk : invg;
  int total = blockIdx.y ? EK : EG;
  int i = blockIdx.x * 256 + threadIdx.x;
  int v = (i < n) ? cnt[i] : 0;
  __shared__ int ws[4];
  int lane = threadIdx.x & 63, wid = threadIdx.x >> 6;
  int x = v;
#pragma unroll
  for (int d = 1; d < 64; d <<= 1) { int y = __shfl_up(x, d, 64); if (lane >= d) x += y; }
  if (lane == 63) ws[wid] = x;
  __syncthreads();
  int add = pp[blockIdx.x];
#pragma unroll
  for (int k = 0; k < 4; ++k) if (k < wid) add += ws[k];
  if (i < n) {
    off[i] = x - v + add;
    inv[i] = 1.0f / fmaxf((float)v, 1.0f);
  }
  if (i == 0) off[n] = total;
}

// ---------------- CSR fill from range bucket ----------------
__global__ __launch_bounds__(256) void fill_bucket(const unsigned* __restrict__ bkt_g,
                                                   const unsigned* __restrict__ bkt_k,
                                                   const int* __restrict__ gcnt,
                                                   const int* __restrict__ off_g,
                                                   const int* __restrict__ off_k,
                                                   int* __restrict__ cur_g,
                                                   int* __restrict__ cur_k,
                                                   unsigned short* __restrict__ e16g,
                                                   unsigned short* __restrict__ e16k, int FC) {
  const int r = blockIdx.x, gr = blockIdx.y, z = blockIdx.z;
  const unsigned* b = (gr ? bkt_k : bkt_g) + (size_t)r * (gr ? CAPK : CAPG);
  const int* off = gr ? off_k : off_g;
  int* cur = gr ? cur_k : cur_g;
  unsigned short* e16 = gr ? e16k : e16g;
  const int n = gcnt[gr * 8 + r];
  for (int i = z * 256 + (int)threadIdx.x; i < n; i += FC * 256) {
    unsigned v = b[i];
    int d = v >> 16;
    int pz = atomicAdd(&cur[d], 1);
    e16[off[d] + pz] = (unsigned short)(v & 0xffffu);
  }
}

// ---------------- CSR mean-aggregation (bf16 in/out, ushort esrc), unroll-4 ----------
template <int DLOG2>
__global__ __launch_bounds__(256) void csr_aggregate(const unsigned short* __restrict__ h,
                                                     const int* __restrict__ off,
                                                     const unsigned short* __restrict__ esrc,
                                                     const float* __restrict__ inv,
                                                     unsigned short* __restrict__ out) {
  constexpr int TPN = (1 << DLOG2) / 8;
  constexpr int NPB = 256 / TPN;
  int node = blockIdx.x * NPB + ((int)threadIdx.x / TPN);
  int lane = threadIdx.x & (TPN - 1);
  if (node >= NN) return;
  int s = off[node], e = off[node + 1];
  float acc[8] = {0.f, 0.f, 0.f, 0.f, 0.f, 0.f, 0.f, 0.f};
  int j = s;
  for (; j + 3 < e; j += 4) {
    int s0 = esrc[j], s1 = esrc[j + 1], s2 = esrc[j + 2], s3 = esrc[j + 3];
    ushort8 v0 = *reinterpret_cast<const ushort8*>(&h[((size_t)s0 << DLOG2) + lane * 8]);
    ushort8 v1 = *reinterpret_cast<const ushort8*>(&h[((size_t)s1 << DLOG2) + lane * 8]);
    ushort8 v2 = *reinterpret_cast<const ushort8*>(&h[((size_t)s2 << DLOG2) + lane * 8]);
    ushort8 v3 = *reinterpret_cast<const ushort8*>(&h[((size_t)s3 << DLOG2) + lane * 8]);
#pragma unroll
    for (int i = 0; i < 8; ++i) acc[i] += bf2f(v0[i]);
#pragma unroll
    for (int i = 0; i < 8; ++i) acc[i] += bf2f(v1[i]);
#pragma unroll
    for (int i = 0; i < 8; ++i) acc[i] += bf2f(v2[i]);
#pragma unroll
    for (int i = 0; i < 8; ++i) acc[i] += bf2f(v3[i]);
  }
  for (; j < e; ++j) {
    int s0 = esrc[j];
    ushort8 v0 = *reinterpret_cast<const ushort8*>(&h[((size_t)s0 << DLOG2) + lane * 8]);
#pragma unroll
    for (int i = 0; i < 8; ++i) acc[i] += bf2f(v0[i]);
  }
  float sc = inv[node];
  ushort8 o;
#pragma unroll
  for (int i = 0; i < 8; ++i) o[i] = f2bf(acc[i] * sc);
  *reinterpret_cast<ushort8*>(&out[((size_t)node << DLOG2) + lane * 8]) = o;
}

// ---------------- MFMA GEMM, BM=128 x BN=128, BK=64, global_load_lds staging --------
template <int K1, int K2, bool RELU, bool OUT_BF16>
__global__ __launch_bounds__(256) void gemm_gl(
    const unsigned short* __restrict__ A1, const unsigned short* __restrict__ A2,
    const unsigned short* __restrict__ Bt, const float* __restrict__ bias,
    void* __restrict__ outv, int ldo, int nrows) {
  constexpr int KTOT = K1 + K2;
  constexpr int KT = KTOT / 64;
  __shared__ char smem[32768];
  unsigned short* sA = (unsigned short*)smem;
  unsigned short* sB = sA + 8192;

  const int t = threadIdx.x;
  const int lane = t & 63;
  const int w = t >> 6;
  const int wm = (w & 1) * 64, wn = (w >> 1) * 64;
  const int row0 = blockIdx.y * 128;
  const int n0 = blockIdx.x * 128;

  const int srow = (w << 5) + (lane >> 3);
  const int schunk = (lane & 7) << 3;

  f32x4 acc[4][4] = {};

  for (int kt = 0; kt < KT; ++kt) {
    const int kbase = kt * 64;
    const unsigned short* Asrc = (kbase < K1) ? A1 : A2;
    const int kA = (kbase < K1) ? kbase : (kbase - K1);
    const int lda = (kbase < K1) ? K1 : K2;
#pragma unroll
    for (int q = 0; q < 4; ++q) {
      int rA = srow + q * 8;
      int rowg = row0 + rA;
      if (rowg >= nrows) rowg = nrows - 1;
      gload_lds16(Asrc + (size_t)rowg * lda + kA + schunk,
                  sA + ((w << 5) + q * 8) * 64);
      gload_lds16(Bt + (size_t)(n0 + rA) * KTOT + kbase + schunk,
                  sB + ((w << 5) + q * 8) * 64);
    }
    __syncthreads();
#pragma unroll
    for (int kk = 0; kk < 2; ++kk) {
      const int ko = kk * 32 + (lane >> 4) * 8;
      short8 a[4], b[4];
#pragma unroll
      for (int mi = 0; mi < 4; ++mi)
        a[mi] = *reinterpret_cast<const short8*>(&sA[(wm + mi * 16 + (lane & 15)) * 64 + ko]);
#pragma unroll
      for (int ni = 0; ni < 4; ++ni)
        b[ni] = *reinterpret_cast<const short8*>(&sB[(wn + ni * 16 + (lane & 15)) * 64 + ko]);
#pragma unroll
      for (int mi = 0; mi < 4; ++mi)
#pragma unroll
        for (int ni = 0; ni < 4; ++ni)
          acc[mi][ni] = __builtin_amdgcn_mfma_f32_16x16x32_bf16(a[mi], b[ni], acc[mi][ni], 0, 0, 0);
    }
    __syncthreads();
  }

  float* Co = (float*)smem;
#pragma unroll
  for (int h = 0; h < 2; ++h) {
    __syncthreads();
    if ((w >> 1) == h) {
#pragma unroll
      for (int mi = 0; mi < 4; ++mi)
#pragma unroll
        for (int ni = 0; ni < 4; ++ni) {
          int col = ni * 16 + (lane & 15);
          int rowb = wm + mi * 16 + (lane >> 4) * 4;
#pragma unroll
          for (int j = 0; j < 4; ++j) Co[(rowb + j) * 64 + col] = acc[mi][ni][j];
        }
    }
    __syncthreads();
    int sr = t >> 1, cb = (t & 1) * 32;
    int r = row0 + sr;
    if (r < nrows) {
      float v[32];
#pragma unroll
      for (int i = 0; i < 32; ++i) {
        v[i] = Co[sr * 64 + cb + i] + bias[n0 + h * 64 + cb + i];
        if (RELU) v[i] = fmaxf(v[i], 0.f);
      }
      if (OUT_BF16) {
        unsigned short* dst = (unsigned short*)outv + (size_t)r * ldo + n0 + h * 64 + cb;
#pragma unroll
        for (int q = 0; q < 4; ++q) {
          ushort8 o;
#pragma unroll
          for (int i = 0; i < 8; ++i) o[i] = f2bf(v[q * 8 + i]);
          *reinterpret_cast<ushort8*>(dst + q * 8) = o;
        }
      } else {
        float* dst = (float*)outv + (size_t)r * ldo + n0 + h * 64 + cb;
#pragma unroll
        for (int q = 0; q < 8; ++q) {
          float4 o = make_float4(v[4 * q], v[4 * q + 1], v[4 * q + 2], v[4 * q + 3]);
          *reinterpret_cast<float4*>(dst + 4 * q) = o;
        }
      }
    }
  }
}

// ---------------- tail GEMM: K=512 (h_l1|h_g0), + agg terms in epilogue, f32 out ------
__global__ __launch_bounds__(256) void gemm_tail512(
    const unsigned short* __restrict__ A0, const unsigned short* __restrict__ A1,
    const unsigned short* __restrict__ Bt, const float* __restrict__ bias,
    const unsigned short* __restrict__ aYL, const unsigned short* __restrict__ aYG,
    float* __restrict__ outv, int nrows) {
  constexpr int KTOT = 512;
  constexpr int KT = 8;
  __shared__ char smem[32768];
  unsigned short* sA = (unsigned short*)smem;
  unsigned short* sB = sA + 8192;

  const int t = threadIdx.x;
  const int lane = t & 63;
  const int w = t >> 6;
  const int wm = (w & 1) * 64, wn = (w >> 1) * 64;
  const int row0 = blockIdx.y * 128;

  const int srow = (w << 5) + (lane >> 3);
  const int schunk = (lane & 7) << 3;

  f32x4 acc[4][4] = {};

  for (int kt = 0; kt < KT; ++kt) {
    const unsigned short* Asrc = (kt < 4) ? A0 : A1;
    const int kA = (kt & 3) * 64;
#pragma unroll
    for (int q = 0; q < 4; ++q) {
      int rA = srow + q * 8;
      int rowg = row0 + rA;
      if (rowg >= nrows) rowg = nrows - 1;
      gload_lds16(Asrc + (size_t)rowg * 256 + kA + schunk,
                  sA + ((w << 5) + q * 8) * 64);
      gload_lds16(Bt + (size_t)rA * KTOT + kt * 64 + schunk,
                  sB + ((w << 5) + q * 8) * 64);
    }
    __syncthreads();
#pragma unroll
    for (int kk = 0; kk < 2; ++kk) {
      const int ko = kk * 32 + (lane >> 4) * 8;
      short8 a[4], b[4];
#pragma unroll
      for (int mi = 0; mi < 4; ++mi)
        a[mi] = *reinterpret_cast<const short8*>(&sA[(wm + mi * 16 + (lane & 15)) * 64 + ko]);
#pragma unroll
      for (int ni = 0; ni < 4; ++ni)
        b[ni] = *reinterpret_cast<const short8*>(&sB[(wn + ni * 16 + (lane & 15)) * 64 + ko]);
#pragma unroll
      for (int mi = 0; mi < 4; ++mi)
#pragma unroll
        for (int ni = 0; ni < 4; ++ni)
          acc[mi][ni] = __builtin_amdgcn_mfma_f32_16x16x32_bf16(a[mi], b[ni], acc[mi][ni], 0, 0, 0);
    }
    __syncthreads();
  }

  float* Co = (float*)smem;
#pragma unroll
  for (int h = 0; h < 2; ++h) {
    __syncthreads();
    if ((w >> 1) == h) {
#pragma unroll
      for (int mi = 0; mi < 4; ++mi)
#pragma unroll
        for (int ni = 0; ni < 4; ++ni) {
          int col = ni * 16 + (lane & 15);
          int rowb = wm + mi * 16 + (lane >> 4) * 4;
#pragma unroll
          for (int j = 0; j < 4; ++j) Co[(rowb + j) * 64 + col] = acc[mi][ni][j];
        }
    }
    __syncthreads();
    int sr = t >> 1, cb = (t & 1) * 32;
    int r = row0 + sr;
    if (r < nrows) {
      float* dst = outv + (size_t)r * MLPH + h * 64 + cb;
#pragma unroll
      for (int q = 0; q < 4; ++q) {
        ushort8 ya = *reinterpret_cast<const ushort8*>(&aYL[(size_t)r * MLPH + h * 64 + cb + q * 8]);
        ushort8 yb = *reinterpret_cast<const ushort8*>(&aYG[(size_t)r * MLPH + h * 64 + cb + q * 8]);
        float v[8];
#pragma unroll
        for (int i = 0; i < 8; ++i)
          v[i] = Co[sr * 64 + cb + q * 8 + i] + bf2f(ya[i]) + bf2f(yb[i]) +
                 bias[h * 64 + cb + q * 8 + i];
        *reinterpret_cast<float4*>(dst + q * 8) = make_float4(v[0], v[1], v[2], v[3]);
        *reinterpret_cast<float4*>(dst + q * 8 + 4) = make_float4(v[4], v[5], v[6], v[7]);
      }
    }
  }
}

// ---------------- BN ----------------
__global__ __launch_bounds__(256) void bn_stats_kernel(const float* __restrict__ x,
                                                       float* __restrict__ sums,
                                                       float* __restrict__ sumsq) {
  int c = threadIdx.x & 127;
  int rbase = (blockIdx.x * 256 + threadIdx.x) >> 7;
  int stride = (gridDim.x * 256) >> 7;
  float s = 0.f, s2 = 0.f;
  for (int r = rbase; r < NN; r += stride) {
    float v = x[(size_t)r * 128 + c];
    s += v;
    s2 += v * v;
  }
  __shared__ float ls[256], ls2[256];
  ls[threadIdx.x] = s;
  ls2[threadIdx.x] = s2;
  __syncthreads();
  if (threadIdx.x < 128) {
    s = ls[threadIdx.x] + ls[threadIdx.x + 128];
    s2 = ls2[threadIdx.x] + ls2[threadIdx.x + 128];
    atomicAdd(&sums[c], s);
    atomicAdd(&sumsq[c], s2);
  }
}

__global__ __launch_bounds__(128) void bn_finalize_kernel(float* __restrict__ stats,
                                                          const float* __restrict__ gamma,
                                                          const float* __restrict__ beta) {
  int c = threadIdx.x;
  float mu = stats[c] * (1.0f / NN);
  float var = stats[128 + c] * (1.0f / NN) - mu * mu;
  var = fmaxf(var, 0.f);
  float sc = gamma[c] * rsqrtf(var + BN_EPS);
  stats[256 + c] = sc;
  stats[384 + c] = beta[c] - mu * sc;
}

// ---------------- final head GEMM with fused BN+ReLU on A-load (64x64) ----------------
template <int K1, bool RELU>
__global__ __launch_bounds__(256) void gemm_mfma_bn(
    const float* __restrict__ A1v, const unsigned short* __restrict__ Bt,
    const float* __restrict__ bias, const float* __restrict__ bnscale,
    const float* __restrict__ bnshift, float* __restrict__ outv, int ldo, int nrows) {
  constexpr int KT = K1 / 64;
  constexpr int LDT = 72;
  __shared__ char smem[2 * 64 * LDT * 2];
  unsigned short* As = (unsigned short*)smem;
  unsigned short* Bs = As + 64 * LDT;
  float* Co = (float*)smem;
  constexpr int LDC = 68;

  const int t = threadIdx.x;
  const int lane = t & 63;
  const int w = t >> 6;
  const int wm = (w & 1) * 32, wn = (w >> 1) * 32;
  const int row0 = blockIdx.y * 64;
  const int n0 = blockIdx.x * 64;

  const int sr = t >> 2;
  const int skc = (t & 3) * 16;
  int rg = row0 + sr;
  if (rg >= nrows) rg = nrows - 1;

  f32x4 acc[2][2] = {};

  for (int kt = 0; kt < KT; ++kt) {
    const int kbase = kt * 64;
    {
      const float* xb = A1v + (size_t)rg * K1 + kbase + skc;
      ushort8 o0, o1;
#pragma unroll
      for (int i = 0; i < 8; ++i) {
        float v = xb[i] * bnscale[kbase + skc + i] + bnshift[kbase + skc + i];
        o0[i] = f2bf(fmaxf(v, 0.f));
      }
#pragma unroll
      for (int i = 0; i < 8; ++i) {
        float v = xb[8 + i] * bnscale[kbase + skc + 8 + i] + bnshift[kbase + skc + 8 + i];
        o1[i] = f2bf(fmaxf(v, 0.f));
      }
      *reinterpret_cast<ushort8*>(&As[sr * LDT + skc]) = o0;
      *reinterpret_cast<ushort8*>(&As[sr * LDT + skc + 8]) = o1;
    }
    {
      const unsigned short* bb = Bt + (size_t)(n0 + sr) * K1 + kbase + skc;
      int4 p0 = *reinterpret_cast<const int4*>(bb);
      int4 p1 = *reinterpret_cast<const int4*>(bb + 8);
      *reinterpret_cast<int4*>(&Bs[sr * LDT + skc]) = p0;
      *reinterpret_cast<int4*>(&Bs[sr * LDT + skc + 8]) = p1;
    }
    __syncthreads();
#pragma unroll
    for (int kk = 0; kk < 2; ++kk) {
      const int ko = kk * 32 + (lane >> 4) * 8;
      short8 a0 = *reinterpret_cast<const short8*>(&As[(wm + (lane & 15)) * LDT + ko]);
      short8 a1 = *reinterpret_cast<const short8*>(&As[(wm + 16 + (lane & 15)) * LDT + ko]);
      short8 b0 = *reinterpret_cast<const short8*>(&Bs[(wn + (lane & 15)) * LDT + ko]);
      short8 b1 = *reinterpret_cast<const short8*>(&Bs[(wn + 16 + (lane & 15)) * LDT + ko]);
      acc[0][0] = __builtin_amdgcn_mfma_f32_16x16x32_bf16(a0, b0, acc[0][0], 0, 0, 0);
      acc[0][1] = __builtin_amdgcn_mfma_f32_16x16x32_bf16(a0, b1, acc[0][1], 0, 0, 0);
      acc[1][0] = __builtin_amdgcn_mfma_f32_16x16x32_bf16(a1, b0, acc[1][0], 0, 0, 0);
      acc[1][1] = __builtin_amdgcn_mfma_f32_16x16x32_bf16(a1, b1, acc[1][1], 0, 0, 0);
    }
    __syncthreads();
  }

#pragma unroll
  for (int mi = 0; mi < 2; ++mi)
#pragma unroll
    for (int ni = 0; ni < 2; ++ni) {
      int col = wn + ni * 16 + (lane & 15);
      int rowb = wm + mi * 16 + (lane >> 4) * 4;
#pragma unroll
      for (int j = 0; j < 4; ++j) Co[(rowb + j) * LDC + col] = acc[mi][ni][j];
    }
  __syncthreads();
  {
    int r = row0 + sr;
    if (r < nrows) {
      float v[16];
#pragma unroll
      for (int i = 0; i < 16; ++i) {
        v[i] = Co[sr * LDC + skc + i] + bias[n0 + skc + i];
        if (RELU) v[i] = fmaxf(v[i], 0.f);
      }
      float* dst = outv + (size_t)r * ldo + n0 + skc;
#pragma unroll
      for (int i = 0; i < 4; ++i) {
        float4 o = make_float4(v[4 * i], v[4 * i + 1], v[4 * i + 2], v[4 * i + 3]);
        *reinterpret_cast<float4*>(dst + 4 * i) = o;
      }
    }
  }
}

// ---------------- launch ----------------
extern "C" void kernel_launch(void* const* d_in, const int* in_sizes, int n_in,
                              void* d_out, int out_size, void* d_ws, size_t ws_size,
                              hipStream_t stream) {
  const float* feat = (const float*)d_in[0];
  const int* g_src = (const int*)d_in[1];
  const int* g_dst = (const int*)d_in[2];
  const int* k_src = (const int*)d_in[3];
  const int* k_dst = (const int*)d_in[4];
  const float* lb_0 = (const float*)d_in[7];
  const float* lb_1 = (const float*)d_in[10];
  const float* lb_2 = (const float*)d_in[13];
  const float* gb_0 = (const float*)d_in[16];
  const float* gb_1 = (const float*)d_in[19];
  const float* mlp_b1 = (const float*)d_in[21];
  const float* bn_gamma = (const float*)d_in[22];
  const float* bn_beta = (const float*)d_in[23];
  const float* mlp_b2 = (const float*)d_in[25];
  float* out = (float*)d_out;

  // workspace layout
  float* xf32 = (float*)d_ws;                         // N*128 f32
  int* cnt_g = (int*)(xf32 + (size_t)NN * 128);       // N
  int* cnt_k = cnt_g + NN;                            // N
  int* cur_g = cnt_k + NN;                            // N
  int* cur_k = cur_g + NN;                            // N
  float* stats = (float*)(cur_k + NN);                // 512
  int* gcnt = (int*)(stats + 512);                    // 16
  float* zbias = (float*)(gcnt + 16);                 // 128 (zeroed with block above)
  float* invg = zbias + 128;                          // N
  float* invk = invg + NN;                            // N
  int* off_g = (int*)(invk + NN);                     // N+4
  int* off_k = off_g + NN + 4;                        // N+4
  int* part = off_k + NN + 4;                         // 512
  unsigned* bkt_g = (unsigned*)(part + 512);          // 8*CAPG
  unsigned* bkt_k = bkt_g + 8 * CAPG;                 // 8*CAPK
  unsigned short* e16g = (unsigned short*)(bkt_k + 8 * CAPK);  // EG
  unsigned short* e16k = e16g + EG;                   // EK
  unsigned short* featbf = e16k + EK;                 // N*128
  unsigned short* wts = featbf + (size_t)NN * IN_F;   // 598016
  unsigned short* wf = wts + 598016;                  // 131072
  float* bfused = (float*)(wf + 131072);              // 128
  unsigned short* bfA = (unsigned short*)(bfused + 128);  // N*256
  unsigned short* bfB = bfA + (size_t)NN * HF;        // N*256
  unsigned short* bfAgg = bfB + (size_t)NN * HF;      // N*256
  unsigned short* bfYL = bfAgg + (size_t)NN * HF;     // N*128
  unsigned short* bfYG = bfYL + (size_t)NN * MLPH;    // N*128
  unsigned short* bfAYL = bfYG + (size_t)NN * MLPH;   // N*128
  unsigned short* bfAYG = bfAYL + (size_t)NN * MLPH;  // N*128

  const int wL0 = 0, wL1 = 65536, wG0 = 327680, wH2 = 589824;
  const int wfYL = 65536, wfYG = 98304;

  dim3 blk(256);
  const int NB = (NN + 255) / 256;        // 196
  const int MB = (NN + 127) / 128;        // 391
  const dim3 gridH(2, MB);                // 256-col out
  const dim3 gridM(1, MB);                // 128-col out
  const int agg128_blocks = (NN + 15) / 16;
  const int agg256_blocks = (NN + 7) / 8;
  const int BKB = (EK + 2047) / 2048;
  const int CC = 8;
  const int FC = 16;

  // zero cnt_g, cnt_k, cur_g, cur_k, stats, gcnt, zbias
  hipMemsetAsync(cnt_g, 0,
                 (size_t)(4 * NN) * sizeof(int) + 512 * sizeof(float) + 16 * sizeof(int) +
                     128 * sizeof(float),
                 stream);

  WPack p;
  p.d[0] = {(const float*)d_in[5], 128, 8, 0, 256, wL0};
  p.d[1] = {(const float*)d_in[6], 128, 8, 128, 256, wL0};
  p.d[2] = {(const float*)d_in[8], 256, 8, 0, 512, wL1};
  p.d[3] = {(const float*)d_in[9], 256, 8, 256, 512, wL1};
  p.d[4] = {(const float*)d_in[11], 256, 8, 0, 512, 196608};  // folded; layout keep
  p.d[5] = {(const float*)d_in[12], 256, 8, 256, 512, 196608};
  p.d[6] = {(const float*)d_in[14], 128, 8, 0, 256, wG0};
  p.d[7] = {(const float*)d_in[15], 128, 8, 128, 256, wG0};
  p.d[8] = {(const float*)d_in[17], 256, 8, 0, 512, 393216};  // folded
  p.d[9] = {(const float*)d_in[18], 256, 8, 256, 512, 393216};
  p.d[10] = {(const float*)d_in[20], 512, 7, 0, 512, 524288}; // folded
  p.d[11] = {(const float*)d_in[24], 128, 6, 0, 128, wH2};
  prep_kernel<<<3510, blk, 0, stream>>>(feat, featbf, p, wts);

  fuse_w_kernel<<<1025, 128, 0, stream>>>(
      (const float*)d_in[11], (const float*)d_in[12],
      (const float*)d_in[17], (const float*)d_in[18],
      (const float*)d_in[20], lb_2, gb_1, mlp_b1, wf, bfused);

  // ---- CSR build ----
  bucket_kernel<<<dim3(BKB, 2), blk, 0, stream>>>(g_src, g_dst, k_src, k_dst, gcnt, bkt_g, bkt_k);
  count_bucket<<<dim3(8, 2, CC), blk, 0, stream>>>(bkt_g, bkt_k, gcnt, cnt_g, cnt_k, CC);
  scan_partial2<<<dim3(NB, 2), blk, 0, stream>>>(cnt_g, cnt_k, part, NN);
  scan_block2<<<2, blk, 0, stream>>>(part, NB);
  scan_final2<<<dim3(NB, 2), blk, 0, stream>>>(cnt_g, cnt_k, part, off_g, off_k, invg, invk, NN);
  fill_bucket<<<dim3(8, 2, FC), blk, 0, stream>>>(bkt_g, bkt_k, gcnt, off_g, off_k,
                                                  cur_g, cur_k, e16g, e16k, FC);

  // ---- local layer 0: h_l0 = relu([feat|agg_g(feat)] @ WL0) -> bfA ----
  csr_aggregate<7><<<agg128_blocks, blk, 0, stream>>>(featbf, off_g, e16g, invg, bfAgg);
  gemm_gl<128, 128, true, true><<<gridH, blk, 0, stream>>>(
      featbf, bfAgg, wts + wL0, lb_0, bfA, HF, NN);
  // ---- local layer 1: h_l1 = relu([h_l0|agg_g(h_l0)] @ WL1) -> bfB ----
  csr_aggregate<8><<<agg256_blocks, blk, 0, stream>>>(bfA, off_g, e16g, invg, bfAgg);
  gemm_gl<256, 256, true, true><<<gridH, blk, 0, stream>>>(
      bfA, bfAgg, wts + wL1, lb_1, bfB, HF, NN);
  // ---- yl = h_l1 @ Wf1 -> bfYL [N,128]; aggYL = agg_g(yl) D=128 ----
  gemm_gl<256, 0, false, true><<<gridM, blk, 0, stream>>>(
      bfB, nullptr, wf + wfYL, zbias, bfYL, MLPH, NN);
  csr_aggregate<7><<<agg128_blocks, blk, 0, stream>>>(bfYL, off_g, e16g, invg, bfAYL);
  // ---- global layer 0: h_g0 = relu([feat|agg_k(feat)] @ WG0) -> bfA ----
  csr_aggregate<7><<<agg128_blocks, blk, 0, stream>>>(featbf, off_k, e16k, invk, bfAgg);
  gemm_gl<128, 128, true, true><<<gridH, blk, 0, stream>>>(
      featbf, bfAgg, wts + wG0, gb_0, bfA, HF, NN);
  // ---- yg = h_g0 @ Wf3 -> bfYG; aggYG = agg_k(yg) D=128 ----
  gemm_gl<256, 0, false, true><<<gridM, blk, 0, stream>>>(
      bfA, nullptr, wf + wfYG, zbias, bfYG, MLPH, NN);
  csr_aggregate<7><<<agg128_blocks, blk, 0, stream>>>(bfYG, off_k, e16k, invk, bfAYG);

  // ---- tail: x = h_l1@wf[0:256] + h_g0@wf[256:512] + aggYL + aggYG + bfused ----
  gemm_tail512<<<gridM, blk, 0, stream>>>(bfB, bfA, wf, bfused, bfAYL, bfAYG, xf32, NN);

  // ---- BatchNorm ----
  bn_stats_kernel<<<256, blk, 0, stream>>>(xf32, stats, stats + 128);
  bn_finalize_kernel<<<1, 128, 0, stream>>>(stats, bn_gamma, bn_beta);

  // ---- head GEMM2 ----
  gemm_mfma_bn<128, false><<<dim3(1, (NN + 63) / 64), blk, 0, stream>>>(
      xf32, wts + wH2, mlp_b2, stats + 256, stats + 384, out, COUT, NN);
}

// Round 13
// 486.824 us; speedup vs baseline: 1.3970x; 1.0410x over previous
//
#include <hip/hip_runtime.h>

#define NN   50000
#define IN_F 128
#define HF   256
#define COUT 64
#define MLPH 128
#define EG   600000
#define EK   800000
#define RNG  6250    // NN / 8
#define SUBR 1563    // ceil(RNG / 4)
#define CAPG 80000
#define CAPK 106000
#define BN_EPS 1e-5f

typedef __attribute__((ext_vector_type(8))) short short8;
typedef __attribute__((ext_vector_type(8))) unsigned short ushort8;
typedef __attribute__((ext_vector_type(4))) float f32x4;

__device__ __forceinline__ unsigned short f2bf(float f) {
  union { float f; unsigned int u; } v; v.f = f;
  unsigned int r = v.u + 0x7FFFu + ((v.u >> 16) & 1u);
  return (unsigned short)(r >> 16);
}
__device__ __forceinline__ float bf2f(unsigned short s) {
  union { unsigned int u; float f; } v; v.u = ((unsigned int)s) << 16;
  return v.f;
}

__device__ __forceinline__ void gload_lds16(const void* g, void* l) {
  __builtin_amdgcn_global_load_lds((const __attribute__((address_space(1))) void*)g,
                                   (__attribute__((address_space(3))) void*)l, 16, 0, 0);
}

struct WDesc { const float* src; int rows; int cshift; int kofs; int ldk; int dofs; };
struct WPack { WDesc d[12]; };

// ---------------- prep: feat->bf16, weight transpose ----------------
__global__ __launch_bounds__(256) void prep_kernel(const float* __restrict__ feat,
                                                   unsigned short* __restrict__ featbf,
                                                   WPack p, unsigned short* __restrict__ wts) {
  int b = blockIdx.x;
  if (b < 3126) {
    int i = b * 256 + threadIdx.x;
    if (i < NN * IN_F / 8) {
      float4 a = *reinterpret_cast<const float4*>(&feat[i * 8]);
      float4 c = *reinterpret_cast<const float4*>(&feat[i * 8 + 4]);
      ushort8 o;
      o[0] = f2bf(a.x); o[1] = f2bf(a.y); o[2] = f2bf(a.z); o[3] = f2bf(a.w);
      o[4] = f2bf(c.x); o[5] = f2bf(c.y); o[6] = f2bf(c.z); o[7] = f2bf(c.w);
      *reinterpret_cast<ushort8*>(&featbf[i * 8]) = o;
    }
  } else {
    int wb = b - 3126;
    WDesc w = p.d[wb >> 5];
    int xb = wb & 31;
    int total = w.rows << w.cshift;
    int cmask = (1 << w.cshift) - 1;
    for (int idx = xb * 256 + threadIdx.x; idx < total; idx += 32 * 256) {
      int r = idx >> w.cshift, c = idx & cmask;
      wts[w.dofs + (size_t)c * w.ldk + w.kofs + r] = f2bf(w.src[idx]);
    }
  }
}

// ---------------- fused head weights ----------------
// wf layout: [0..65535] wf0 tail Bt[c][512]=[seg0|seg2]; [65536..98303] wf1 (yl);
//            [98304..131071] wf3 (yg)
__global__ __launch_bounds__(128) void fuse_w_kernel(
    const float* __restrict__ wl2s, const float* __restrict__ wl2n,
    const float* __restrict__ wg1s, const float* __restrict__ wg1n,
    const float* __restrict__ w1, const float* __restrict__ bl2,
    const float* __restrict__ bg1, const float* __restrict__ b1,
    unsigned short* __restrict__ wf, float* __restrict__ bfused) {
  int b = blockIdx.x;
  int c = threadIdx.x;  // 0..127
  __shared__ float row[256];
  if (b < 1024) {
    int seg = b >> 8, i = b & 255;
    const float* W = (seg == 0) ? wl2s : (seg == 1) ? wl2n : (seg == 2) ? wg1s : wg1n;
    const float* w1b = w1 + ((seg < 2) ? 0 : 256) * MLPH;
    row[c] = W[i * 256 + c];
    row[c + 128] = W[i * 256 + 128 + c];
    __syncthreads();
    float acc = 0.f;
    for (int o = 0; o < 256; ++o) acc += row[o] * w1b[o * MLPH + c];
    unsigned short v = f2bf(acc);
    if (seg == 0)      wf[(size_t)c * 512 + i] = v;
    else if (seg == 2) wf[(size_t)c * 512 + 256 + i] = v;
    else if (seg == 1) wf[65536 + (size_t)c * 256 + i] = v;
    else               wf[98304 + (size_t)c * 256 + i] = v;
  } else {
    float acc = b1[c];
    for (int o = 0; o < 256; ++o) acc += bl2[o] * w1[o * MLPH + c];
    for (int o = 0; o < 256; ++o) acc += bg1[o] * w1[(256 + o) * MLPH + c];
    bfused[c] = acc;
  }
}

// ---------------- edge bucketing ----------------
__global__ __launch_bounds__(256) void bucket_kernel(const int* __restrict__ g_src,
                                                     const int* __restrict__ g_dst,
                                                     const int* __restrict__ k_src,
                                                     const int* __restrict__ k_dst,
                                                     int* __restrict__ gcnt,
                                                     unsigned* __restrict__ bkt_g,
                                                     unsigned* __restrict__ bkt_k) {
  __shared__ unsigned buf[2048];
  __shared__ int rcnt[8], rbase[8], roff[8];
  const int gr = blockIdx.y;
  const int* src = gr ? k_src : g_src;
  const int* dst = gr ? k_dst : g_dst;
  unsigned* bkt = gr ? bkt_k : bkt_g;
  const int CAP = gr ? CAPK : CAPG;
  const int E = gr ? EK : EG;
  int* gc = gcnt + gr * 8;
  const int tid = threadIdx.x;
  const int e0 = blockIdx.x * 2048;
  if (e0 >= E) return;
  if (tid < 8) rcnt[tid] = 0;
  __syncthreads();
  unsigned vloc[8];
  int rloc[8], ploc[8];
#pragma unroll
  for (int i = 0; i < 8; ++i) {
    int e = e0 + i * 256 + tid;
    rloc[i] = -1;
    if (e < E) {
      int d = dst[e], s = src[e];
      int r = d / RNG;
      vloc[i] = ((unsigned)d << 16) | (unsigned)s;
      rloc[i] = r;
      ploc[i] = atomicAdd(&rcnt[r], 1);
    }
  }
  __syncthreads();
  if (tid == 0) {
    int acc = 0;
#pragma unroll
    for (int r = 0; r < 8; ++r) { roff[r] = acc; acc += rcnt[r]; }
  }
  __syncthreads();
#pragma unroll
  for (int i = 0; i < 8; ++i)
    if (rloc[i] >= 0) buf[roff[rloc[i]] + ploc[i]] = vloc[i];
  __syncthreads();
  if (tid < 8) rbase[tid] = atomicAdd(&gc[tid], rcnt[tid]);
  __syncthreads();
#pragma unroll
  for (int r = 0; r < 8; ++r) {
    int len = rcnt[r];
    unsigned* dstp = bkt + (size_t)r * CAP + rbase[r];
    for (int i = tid; i < len; i += 256) dstp[i] = buf[roff[r] + i];
  }
}

// ---------------- per-range count (LDS histogram) ----------------
__global__ __launch_bounds__(256) void count_bucket(const unsigned* __restrict__ bkt_g,
                                                    const unsigned* __restrict__ bkt_k,
                                                    const int* __restrict__ gcnt,
                                                    int* __restrict__ cnt_g,
                                                    int* __restrict__ cnt_k, int CC) {
  __shared__ int hist[RNG];
  const int r = blockIdx.x, gr = blockIdx.y, z = blockIdx.z;
  const unsigned* b = (gr ? bkt_k : bkt_g) + (size_t)r * (gr ? CAPK : CAPG);
  int* cnt = gr ? cnt_k : cnt_g;
  const int n = gcnt[gr * 8 + r];
  const unsigned lo = r * RNG;
  for (int i = threadIdx.x; i < RNG; i += 256) hist[i] = 0;
  __syncthreads();
  for (int i = z * 256 + threadIdx.x; i < n; i += CC * 256) {
    unsigned d = (b[i] >> 16) - lo;
    atomicAdd(&hist[d], 1);
  }
  __syncthreads();
  for (int i = threadIdx.x; i < RNG; i += 256) {
    int v = hist[i];
    if (v) atomicAdd(&cnt[lo + i], v);
  }
}

// ---------------- parallel scans ----------------
__global__ __launch_bounds__(256) void scan_partial2(const int* __restrict__ cnt_g,
                                                     const int* __restrict__ cnt_k,
                                                     int* __restrict__ part, int n) {
  const int* cnt = blockIdx.y ? cnt_k : cnt_g;
  int* pp = part + blockIdx.y * 256;
  int i = blockIdx.x * 256 + threadIdx.x;
  int v = (i < n) ? cnt[i] : 0;
  __shared__ int ws[4];
  int lane = threadIdx.x & 63, wid = threadIdx.x >> 6;
  int x = v;
#pragma unroll
  for (int d = 1; d < 64; d <<= 1) { int y = __shfl_up(x, d, 64); if (lane >= d) x += y; }
  if (lane == 63) ws[wid] = x;
  __syncthreads();
  if (threadIdx.x == 0) pp[blockIdx.x] = ws[0] + ws[1] + ws[2] + ws[3];
}

__global__ __launch_bounds__(256) void scan_block2(int* __restrict__ part, int np) {
  int* pp = part + blockIdx.x * 256;
  __shared__ int ws[4];
  int tid = threadIdx.x, lane = tid & 63, wid = tid >> 6;
  int v = (tid < np) ? pp[tid] : 0;
  int x = v;
#pragma unroll
  for (int d = 1; d < 64; d <<= 1) { int y = __shfl_up(x, d, 64); if (lane >= d) x += y; }
  if (lane == 63) ws[wid] = x;
  __syncthreads();
  int add = 0;
#pragma unroll
  for (int k = 0; k < 4; ++k) if (k < wid) add += ws[k];
  if (tid < np) pp[tid] = x - v + add;
}

__global__ __launch_bounds__(256) void scan_final2(const int* __restrict__ cnt_g,
                                                   const int* __restrict__ cnt_k,
                                                   const int* __restrict__ part,
                                                   int* __restrict__ off_g,
                                                   int* __restrict__ off_k,
                                                   float* __restrict__ invg,
                                                   float* __restrict__ invk, int n) {
  const int* cnt = blockIdx.y ? cnt_k : cnt_g;
  const int* pp = part + blockIdx.y * 256;
  int* off = blockIdx.y ? off_k : off_g;
  float* inv = blockIdx.y ? invk : invg;
  int total = blockIdx.y ? EK : EG;
  int i = blockIdx.x * 256 + threadIdx.x;
  int v = (i < n) ? cnt[i] : 0;
  __shared__ int ws[4];
  int lane = threadIdx.x & 63, wid = threadIdx.x >> 6;
  int x = v;
#pragma unroll
  for (int d = 1; d < 64; d <<= 1) { int y = __shfl_up(x, d, 64); if (lane >= d) x += y; }
  if (lane == 63) ws[wid] = x;
  __syncthreads();
  int add = pp[blockIdx.x];
#pragma unroll
  for (int k = 0; k < 4; ++k) if (k < wid) add += ws[k];
  if (i < n) {
    off[i] = x - v + add;
    inv[i] = 1.0f / fmaxf((float)v, 1.0f);
  }
  if (i == 0) off[n] = total;
}

// ---------------- CSR fill: sub-range partition, LDS cursors ----------------
// 64 blocks: gr = b>>5, r = (b>>2)&7, s = b&3. Each block scans its range bucket,
// scatters only nodes in its 1563-node sub-range via LDS atomic cursors.
__global__ __launch_bounds__(1024) void fill_sub(const unsigned* __restrict__ bkt_g,
                                                 const unsigned* __restrict__ bkt_k,
                                                 const int* __restrict__ gcnt,
                                                 const int* __restrict__ off_g,
                                                 const int* __restrict__ off_k,
                                                 unsigned short* __restrict__ e16g,
                                                 unsigned short* __restrict__ e16k) {
  __shared__ int curs[SUBR];
  const int b = blockIdx.x;
  const int s = b & 3, r = (b >> 2) & 7, gr = b >> 5;
  const unsigned* bkt = (gr ? bkt_k : bkt_g) + (size_t)r * (gr ? CAPK : CAPG);
  const int* off = gr ? off_k : off_g;
  unsigned short* e16 = gr ? e16k : e16g;
  const int n = gcnt[gr * 8 + r];
  const int lo = r * RNG;
  const int slo = s * SUBR;
  int send = slo + SUBR;
  if (send > RNG) send = RNG;
  const int swid = send - slo;
  for (int i = threadIdx.x; i < swid; i += 1024) curs[i] = off[lo + slo + i];
  __syncthreads();
  for (int i = threadIdx.x; i < n; i += 1024) {
    unsigned v = bkt[i];
    int d = (int)(v >> 16) - lo - slo;
    if ((unsigned)d < (unsigned)swid) {
      int pz = atomicAdd(&curs[d], 1);
      e16[pz] = (unsigned short)(v & 0xffffu);
    }
  }
}

// ---------------- CSR mean-aggregation (bf16 in/out, ushort esrc), unroll-4 ----------
template <int DLOG2>
__global__ __launch_bounds__(256) void csr_aggregate(const unsigned short* __restrict__ h,
                                                     const int* __restrict__ off,
                                                     const unsigned short* __restrict__ esrc,
                                                     const float* __restrict__ inv,
                                                     unsigned short* __restrict__ out) {
  constexpr int TPN = (1 << DLOG2) / 8;
  constexpr int NPB = 256 / TPN;
  int node = blockIdx.x * NPB + ((int)threadIdx.x / TPN);
  int lane = threadIdx.x & (TPN - 1);
  if (node >= NN) return;
  int s = off[node], e = off[node + 1];
  float acc[8] = {0.f, 0.f, 0.f, 0.f, 0.f, 0.f, 0.f, 0.f};
  int j = s;
  for (; j + 3 < e; j += 4) {
    int s0 = esrc[j], s1 = esrc[j + 1], s2 = esrc[j + 2], s3 = esrc[j + 3];
    ushort8 v0 = *reinterpret_cast<const ushort8*>(&h[((size_t)s0 << DLOG2) + lane * 8]);
    ushort8 v1 = *reinterpret_cast<const ushort8*>(&h[((size_t)s1 << DLOG2) + lane * 8]);
    ushort8 v2 = *reinterpret_cast<const ushort8*>(&h[((size_t)s2 << DLOG2) + lane * 8]);
    ushort8 v3 = *reinterpret_cast<const ushort8*>(&h[((size_t)s3 << DLOG2) + lane * 8]);
#pragma unroll
    for (int i = 0; i < 8; ++i) acc[i] += bf2f(v0[i]);
#pragma unroll
    for (int i = 0; i < 8; ++i) acc[i] += bf2f(v1[i]);
#pragma unroll
    for (int i = 0; i < 8; ++i) acc[i] += bf2f(v2[i]);
#pragma unroll
    for (int i = 0; i < 8; ++i) acc[i] += bf2f(v3[i]);
  }
  for (; j < e; ++j) {
    int s0 = esrc[j];
    ushort8 v0 = *reinterpret_cast<const ushort8*>(&h[((size_t)s0 << DLOG2) + lane * 8]);
#pragma unroll
    for (int i = 0; i < 8; ++i) acc[i] += bf2f(v0[i]);
  }
  float sc = inv[node];
  ushort8 o;
#pragma unroll
  for (int i = 0; i < 8; ++i) o[i] = f2bf(acc[i] * sc);
  *reinterpret_cast<ushort8*>(&out[((size_t)node << DLOG2) + lane * 8]) = o;
}

// ---------------- MFMA GEMM, BM=128 x BN=128, BK=64, global_load_lds staging --------
template <int K1, int K2, bool RELU, bool OUT_BF16>
__global__ __launch_bounds__(256) void gemm_gl(
    const unsigned short* __restrict__ A1, const unsigned short* __restrict__ A2,
    const unsigned short* __restrict__ Bt, const float* __restrict__ bias,
    void* __restrict__ outv, int ldo, int nrows) {
  constexpr int KTOT = K1 + K2;
  constexpr int KT = KTOT / 64;
  __shared__ char smem[32768];
  unsigned short* sA = (unsigned short*)smem;
  unsigned short* sB = sA + 8192;

  const int t = threadIdx.x;
  const int lane = t & 63;
  const int w = t >> 6;
  const int wm = (w & 1) * 64, wn = (w >> 1) * 64;
  const int row0 = blockIdx.y * 128;
  const int n0 = blockIdx.x * 128;

  const int srow = (w << 5) + (lane >> 3);
  const int schunk = (lane & 7) << 3;

  f32x4 acc[4][4] = {};

  for (int kt = 0; kt < KT; ++kt) {
    const int kbase = kt * 64;
    const unsigned short* Asrc = (kbase < K1) ? A1 : A2;
    const int kA = (kbase < K1) ? kbase : (kbase - K1);
    const int lda = (kbase < K1) ? K1 : K2;
#pragma unroll
    for (int q = 0; q < 4; ++q) {
      int rA = srow + q * 8;
      int rowg = row0 + rA;
      if (rowg >= nrows) rowg = nrows - 1;
      gload_lds16(Asrc + (size_t)rowg * lda + kA + schunk,
                  sA + ((w << 5) + q * 8) * 64);
      gload_lds16(Bt + (size_t)(n0 + rA) * KTOT + kbase + schunk,
                  sB + ((w << 5) + q * 8) * 64);
    }
    __syncthreads();
#pragma unroll
    for (int kk = 0; kk < 2; ++kk) {
      const int ko = kk * 32 + (lane >> 4) * 8;
      short8 a[4], b[4];
#pragma unroll
      for (int mi = 0; mi < 4; ++mi)
        a[mi] = *reinterpret_cast<const short8*>(&sA[(wm + mi * 16 + (lane & 15)) * 64 + ko]);
#pragma unroll
      for (int ni = 0; ni < 4; ++ni)
        b[ni] = *reinterpret_cast<const short8*>(&sB[(wn + ni * 16 + (lane & 15)) * 64 + ko]);
#pragma unroll
      for (int mi = 0; mi < 4; ++mi)
#pragma unroll
        for (int ni = 0; ni < 4; ++ni)
          acc[mi][ni] = __builtin_amdgcn_mfma_f32_16x16x32_bf16(a[mi], b[ni], acc[mi][ni], 0, 0, 0);
    }
    __syncthreads();
  }

  float* Co = (float*)smem;
#pragma unroll
  for (int h = 0; h < 2; ++h) {
    __syncthreads();
    if ((w >> 1) == h) {
#pragma unroll
      for (int mi = 0; mi < 4; ++mi)
#pragma unroll
        for (int ni = 0; ni < 4; ++ni) {
          int col = ni * 16 + (lane & 15);
          int rowb = wm + mi * 16 + (lane >> 4) * 4;
#pragma unroll
          for (int j = 0; j < 4; ++j) Co[(rowb + j) * 64 + col] = acc[mi][ni][j];
        }
    }
    __syncthreads();
    int sr = t >> 1, cb = (t & 1) * 32;
    int r = row0 + sr;
    if (r < nrows) {
      float v[32];
#pragma unroll
      for (int i = 0; i < 32; ++i) {
        v[i] = Co[sr * 64 + cb + i] + bias[n0 + h * 64 + cb + i];
        if (RELU) v[i] = fmaxf(v[i], 0.f);
      }
      if (OUT_BF16) {
        unsigned short* dst = (unsigned short*)outv + (size_t)r * ldo + n0 + h * 64 + cb;
#pragma unroll
        for (int q = 0; q < 4; ++q) {
          ushort8 o;
#pragma unroll
          for (int i = 0; i < 8; ++i) o[i] = f2bf(v[q * 8 + i]);
          *reinterpret_cast<ushort8*>(dst + q * 8) = o;
        }
      } else {
        float* dst = (float*)outv + (size_t)r * ldo + n0 + h * 64 + cb;
#pragma unroll
        for (int q = 0; q < 8; ++q) {
          float4 o = make_float4(v[4 * q], v[4 * q + 1], v[4 * q + 2], v[4 * q + 3]);
          *reinterpret_cast<float4*>(dst + 4 * q) = o;
        }
      }
    }
  }
}

// ---------------- tail GEMM: K=512 (h_l1|h_g0), + agg terms in epilogue, f32 out ------
__global__ __launch_bounds__(256) void gemm_tail512(
    const unsigned short* __restrict__ A0, const unsigned short* __restrict__ A1,
    const unsigned short* __restrict__ Bt, const float* __restrict__ bias,
    const unsigned short* __restrict__ aYL, const unsigned short* __restrict__ aYG,
    float* __restrict__ outv, int nrows) {
  constexpr int KTOT = 512;
  constexpr int KT = 8;
  __shared__ char smem[32768];
  unsigned short* sA = (unsigned short*)smem;
  unsigned short* sB = sA + 8192;

  const int t = threadIdx.x;
  const int lane = t & 63;
  const int w = t >> 6;
  const int wm = (w & 1) * 64, wn = (w >> 1) * 64;
  const int row0 = blockIdx.y * 128;

  const int srow = (w << 5) + (lane >> 3);
  const int schunk = (lane & 7) << 3;

  f32x4 acc[4][4] = {};

  for (int kt = 0; kt < KT; ++kt) {
    const unsigned short* Asrc = (kt < 4) ? A0 : A1;
    const int kA = (kt & 3) * 64;
#pragma unroll
    for (int q = 0; q < 4; ++q) {
      int rA = srow + q * 8;
      int rowg = row0 + rA;
      if (rowg >= nrows) rowg = nrows - 1;
      gload_lds16(Asrc + (size_t)rowg * 256 + kA + schunk,
                  sA + ((w << 5) + q * 8) * 64);
      gload_lds16(Bt + (size_t)rA * KTOT + kt * 64 + schunk,
                  sB + ((w << 5) + q * 8) * 64);
    }
    __syncthreads();
#pragma unroll
    for (int kk = 0; kk < 2; ++kk) {
      const int ko = kk * 32 + (lane >> 4) * 8;
      short8 a[4], b[4];
#pragma unroll
      for (int mi = 0; mi < 4; ++mi)
        a[mi] = *reinterpret_cast<const short8*>(&sA[(wm + mi * 16 + (lane & 15)) * 64 + ko]);
#pragma unroll
      for (int ni = 0; ni < 4; ++ni)
        b[ni] = *reinterpret_cast<const short8*>(&sB[(wn + ni * 16 + (lane & 15)) * 64 + ko]);
#pragma unroll
      for (int mi = 0; mi < 4; ++mi)
#pragma unroll
        for (int ni = 0; ni < 4; ++ni)
          acc[mi][ni] = __builtin_amdgcn_mfma_f32_16x16x32_bf16(a[mi], b[ni], acc[mi][ni], 0, 0, 0);
    }
    __syncthreads();
  }

  float* Co = (float*)smem;
#pragma unroll
  for (int h = 0; h < 2; ++h) {
    __syncthreads();
    if ((w >> 1) == h) {
#pragma unroll
      for (int mi = 0; mi < 4; ++mi)
#pragma unroll
        for (int ni = 0; ni < 4; ++ni) {
          int col = ni * 16 + (lane & 15);
          int rowb = wm + mi * 16 + (lane >> 4) * 4;
#pragma unroll
          for (int j = 0; j < 4; ++j) Co[(rowb + j) * 64 + col] = acc[mi][ni][j];
        }
    }
    __syncthreads();
    int sr = t >> 1, cb = (t & 1) * 32;
    int r = row0 + sr;
    if (r < nrows) {
      float* dst = outv + (size_t)r * MLPH + h * 64 + cb;
#pragma unroll
      for (int q = 0; q < 4; ++q) {
        ushort8 ya = *reinterpret_cast<const ushort8*>(&aYL[(size_t)r * MLPH + h * 64 + cb + q * 8]);
        ushort8 yb = *reinterpret_cast<const ushort8*>(&aYG[(size_t)r * MLPH + h * 64 + cb + q * 8]);
        float v[8];
#pragma unroll
        for (int i = 0; i < 8; ++i)
          v[i] = Co[sr * 64 + cb + q * 8 + i] + bf2f(ya[i]) + bf2f(yb[i]) +
                 bias[h * 64 + cb + q * 8 + i];
        *reinterpret_cast<float4*>(dst + q * 8) = make_float4(v[0], v[1], v[2], v[3]);
        *reinterpret_cast<float4*>(dst + q * 8 + 4) = make_float4(v[4], v[5], v[6], v[7]);
      }
    }
  }
}

// ---------------- BN ----------------
__global__ __launch_bounds__(256) void bn_stats_kernel(const float* __restrict__ x,
                                                       float* __restrict__ sums,
                                                       float* __restrict__ sumsq) {
  int c = threadIdx.x & 127;
  int rbase = (blockIdx.x * 256 + threadIdx.x) >> 7;
  int stride = (gridDim.x * 256) >> 7;
  float s = 0.f, s2 = 0.f;
  for (int r = rbase; r < NN; r += stride) {
    float v = x[(size_t)r * 128 + c];
    s += v;
    s2 += v * v;
  }
  __shared__ float ls[256], ls2[256];
  ls[threadIdx.x] = s;
  ls2[threadIdx.x] = s2;
  __syncthreads();
  if (threadIdx.x < 128) {
    s = ls[threadIdx.x] + ls[threadIdx.x + 128];
    s2 = ls2[threadIdx.x] + ls2[threadIdx.x + 128];
    atomicAdd(&sums[c], s);
    atomicAdd(&sumsq[c], s2);
  }
}

__global__ __launch_bounds__(128) void bn_finalize_kernel(float* __restrict__ stats,
                                                          const float* __restrict__ gamma,
                                                          const float* __restrict__ beta) {
  int c = threadIdx.x;
  float mu = stats[c] * (1.0f / NN);
  float var = stats[128 + c] * (1.0f / NN) - mu * mu;
  var = fmaxf(var, 0.f);
  float sc = gamma[c] * rsqrtf(var + BN_EPS);
  stats[256 + c] = sc;
  stats[384 + c] = beta[c] - mu * sc;
}

// ---------------- final head GEMM with fused BN+ReLU on A-load (64x64) ----------------
template <int K1, bool RELU>
__global__ __launch_bounds__(256) void gemm_mfma_bn(
    const float* __restrict__ A1v, const unsigned short* __restrict__ Bt,
    const float* __restrict__ bias, const float* __restrict__ bnscale,
    const float* __restrict__ bnshift, float* __restrict__ outv, int ldo, int nrows) {
  constexpr int KT = K1 / 64;
  constexpr int LDT = 72;
  __shared__ char smem[2 * 64 * LDT * 2];
  unsigned short* As = (unsigned short*)smem;
  unsigned short* Bs = As + 64 * LDT;
  float* Co = (float*)smem;
  constexpr int LDC = 68;

  const int t = threadIdx.x;
  const int lane = t & 63;
  const int w = t >> 6;
  const int wm = (w & 1) * 32, wn = (w >> 1) * 32;
  const int row0 = blockIdx.y * 64;
  const int n0 = blockIdx.x * 64;

  const int sr = t >> 2;
  const int skc = (t & 3) * 16;
  int rg = row0 + sr;
  if (rg >= nrows) rg = nrows - 1;

  f32x4 acc[2][2] = {};

  for (int kt = 0; kt < KT; ++kt) {
    const int kbase = kt * 64;
    {
      const float* xb = A1v + (size_t)rg * K1 + kbase + skc;
      ushort8 o0, o1;
#pragma unroll
      for (int i = 0; i < 8; ++i) {
        float v = xb[i] * bnscale[kbase + skc + i] + bnshift[kbase + skc + i];
        o0[i] = f2bf(fmaxf(v, 0.f));
      }
#pragma unroll
      for (int i = 0; i < 8; ++i) {
        float v = xb[8 + i] * bnscale[kbase + skc + 8 + i] + bnshift[kbase + skc + 8 + i];
        o1[i] = f2bf(fmaxf(v, 0.f));
      }
      *reinterpret_cast<ushort8*>(&As[sr * LDT + skc]) = o0;
      *reinterpret_cast<ushort8*>(&As[sr * LDT + skc + 8]) = o1;
    }
    {
      const unsigned short* bb = Bt + (size_t)(n0 + sr) * K1 + kbase + skc;
      int4 p0 = *reinterpret_cast<const int4*>(bb);
      int4 p1 = *reinterpret_cast<const int4*>(bb + 8);
      *reinterpret_cast<int4*>(&Bs[sr * LDT + skc]) = p0;
      *reinterpret_cast<int4*>(&Bs[sr * LDT + skc + 8]) = p1;
    }
    __syncthreads();
#pragma unroll
    for (int kk = 0; kk < 2; ++kk) {
      const int ko = kk * 32 + (lane >> 4) * 8;
      short8 a0 = *reinterpret_cast<const short8*>(&As[(wm + (lane & 15)) * LDT + ko]);
      short8 a1 = *reinterpret_cast<const short8*>(&As[(wm + 16 + (lane & 15)) * LDT + ko]);
      short8 b0 = *reinterpret_cast<const short8*>(&Bs[(wn + (lane & 15)) * LDT + ko]);
      short8 b1 = *reinterpret_cast<const short8*>(&Bs[(wn + 16 + (lane & 15)) * LDT + ko]);
      acc[0][0] = __builtin_amdgcn_mfma_f32_16x16x32_bf16(a0, b0, acc[0][0], 0, 0, 0);
      acc[0][1] = __builtin_amdgcn_mfma_f32_16x16x32_bf16(a0, b1, acc[0][1], 0, 0, 0);
      acc[1][0] = __builtin_amdgcn_mfma_f32_16x16x32_bf16(a1, b0, acc[1][0], 0, 0, 0);
      acc[1][1] = __builtin_amdgcn_mfma_f32_16x16x32_bf16(a1, b1, acc[1][1], 0, 0, 0);
    }
    __syncthreads();
  }

#pragma unroll
  for (int mi = 0; mi < 2; ++mi)
#pragma unroll
    for (int ni = 0; ni < 2; ++ni) {
      int col = wn + ni * 16 + (lane & 15);
      int rowb = wm + mi * 16 + (lane >> 4) * 4;
#pragma unroll
      for (int j = 0; j < 4; ++j) Co[(rowb + j) * LDC + col] = acc[mi][ni][j];
    }
  __syncthreads();
  {
    int r = row0 + sr;
    if (r < nrows) {
      float v[16];
#pragma unroll
      for (int i = 0; i < 16; ++i) {
        v[i] = Co[sr * LDC + skc + i] + bias[n0 + skc + i];
        if (RELU) v[i] = fmaxf(v[i], 0.f);
      }
      float* dst = outv + (size_t)r * ldo + n0 + skc;
#pragma unroll
      for (int i = 0; i < 4; ++i) {
        float4 o = make_float4(v[4 * i], v[4 * i + 1], v[4 * i + 2], v[4 * i + 3]);
        *reinterpret_cast<float4*>(dst + 4 * i) = o;
      }
    }
  }
}

// ---------------- launch ----------------
extern "C" void kernel_launch(void* const* d_in, const int* in_sizes, int n_in,
                              void* d_out, int out_size, void* d_ws, size_t ws_size,
                              hipStream_t stream) {
  const float* feat = (const float*)d_in[0];
  const int* g_src = (const int*)d_in[1];
  const int* g_dst = (const int*)d_in[2];
  const int* k_src = (const int*)d_in[3];
  const int* k_dst = (const int*)d_in[4];
  const float* lb_0 = (const float*)d_in[7];
  const float* lb_1 = (const float*)d_in[10];
  const float* lb_2 = (const float*)d_in[13];
  const float* gb_0 = (const float*)d_in[16];
  const float* gb_1 = (const float*)d_in[19];
  const float* mlp_b1 = (const float*)d_in[21];
  const float* bn_gamma = (const float*)d_in[22];
  const float* bn_beta = (const float*)d_in[23];
  const float* mlp_b2 = (const float*)d_in[25];
  float* out = (float*)d_out;

  // workspace layout
  float* xf32 = (float*)d_ws;                         // N*128 f32
  int* cnt_g = (int*)(xf32 + (size_t)NN * 128);       // N
  int* cnt_k = cnt_g + NN;                            // N
  float* stats = (float*)(cnt_k + NN);                // 512
  int* gcnt = (int*)(stats + 512);                    // 16
  float* zbias = (float*)(gcnt + 16);                 // 128 (zeroed with block above)
  float* invg = zbias + 128;                          // N
  float* invk = invg + NN;                            // N
  int* off_g = (int*)(invk + NN);                     // N+4
  int* off_k = off_g + NN + 4;                        // N+4
  int* part = off_k + NN + 4;                         // 512
  unsigned* bkt_g = (unsigned*)(part + 512);          // 8*CAPG
  unsigned* bkt_k = bkt_g + 8 * CAPG;                 // 8*CAPK
  unsigned short* e16g = (unsigned short*)(bkt_k + 8 * CAPK);  // EG
  unsigned short* e16k = e16g + EG;                   // EK
  unsigned short* featbf = e16k + EK;                 // N*128
  unsigned short* wts = featbf + (size_t)NN * IN_F;   // 598016
  unsigned short* wf = wts + 598016;                  // 131072
  float* bfused = (float*)(wf + 131072);              // 128
  unsigned short* bfA = (unsigned short*)(bfused + 128);  // N*256
  unsigned short* bfB = bfA + (size_t)NN * HF;        // N*256
  unsigned short* bfAgg = bfB + (size_t)NN * HF;      // N*256
  unsigned short* bfYL = bfAgg + (size_t)NN * HF;     // N*128
  unsigned short* bfYG = bfYL + (size_t)NN * MLPH;    // N*128
  unsigned short* bfAYL = bfYG + (size_t)NN * MLPH;   // N*128
  unsigned short* bfAYG = bfAYL + (size_t)NN * MLPH;  // N*128

  const int wL0 = 0, wL1 = 65536, wG0 = 327680, wH2 = 589824;
  const int wfYL = 65536, wfYG = 98304;

  dim3 blk(256);
  const int NB = (NN + 255) / 256;        // 196
  const int MB = (NN + 127) / 128;        // 391
  const dim3 gridH(2, MB);                // 256-col out
  const dim3 gridM(1, MB);                // 128-col out
  const int agg128_blocks = (NN + 15) / 16;
  const int agg256_blocks = (NN + 7) / 8;
  const int BKB = (EK + 2047) / 2048;
  const int CC = 8;

  // zero cnt_g, cnt_k, stats, gcnt, zbias
  hipMemsetAsync(cnt_g, 0,
                 (size_t)(2 * NN) * sizeof(int) + 512 * sizeof(float) + 16 * sizeof(int) +
                     128 * sizeof(float),
                 stream);

  WPack p;
  p.d[0] = {(const float*)d_in[5], 128, 8, 0, 256, wL0};
  p.d[1] = {(const float*)d_in[6], 128, 8, 128, 256, wL0};
  p.d[2] = {(const float*)d_in[8], 256, 8, 0, 512, wL1};
  p.d[3] = {(const float*)d_in[9], 256, 8, 256, 512, wL1};
  p.d[4] = {(const float*)d_in[11], 256, 8, 0, 512, 196608};  // folded; layout keep
  p.d[5] = {(const float*)d_in[12], 256, 8, 256, 512, 196608};
  p.d[6] = {(const float*)d_in[14], 128, 8, 0, 256, wG0};
  p.d[7] = {(const float*)d_in[15], 128, 8, 128, 256, wG0};
  p.d[8] = {(const float*)d_in[17], 256, 8, 0, 512, 393216};  // folded
  p.d[9] = {(const float*)d_in[18], 256, 8, 256, 512, 393216};
  p.d[10] = {(const float*)d_in[20], 512, 7, 0, 512, 524288}; // folded
  p.d[11] = {(const float*)d_in[24], 128, 6, 0, 128, wH2};
  prep_kernel<<<3510, blk, 0, stream>>>(feat, featbf, p, wts);

  fuse_w_kernel<<<1025, 128, 0, stream>>>(
      (const float*)d_in[11], (const float*)d_in[12],
      (const float*)d_in[17], (const float*)d_in[18],
      (const float*)d_in[20], lb_2, gb_1, mlp_b1, wf, bfused);

  // ---- CSR build ----
  bucket_kernel<<<dim3(BKB, 2), blk, 0, stream>>>(g_src, g_dst, k_src, k_dst, gcnt, bkt_g, bkt_k);
  count_bucket<<<dim3(8, 2, CC), blk, 0, stream>>>(bkt_g, bkt_k, gcnt, cnt_g, cnt_k, CC);
  scan_partial2<<<dim3(NB, 2), blk, 0, stream>>>(cnt_g, cnt_k, part, NN);
  scan_block2<<<2, blk, 0, stream>>>(part, NB);
  scan_final2<<<dim3(NB, 2), blk, 0, stream>>>(cnt_g, cnt_k, part, off_g, off_k, invg, invk, NN);
  fill_sub<<<64, 1024, 0, stream>>>(bkt_g, bkt_k, gcnt, off_g, off_k, e16g, e16k);

  // ---- local layer 0: h_l0 = relu([feat|agg_g(feat)] @ WL0) -> bfA ----
  csr_aggregate<7><<<agg128_blocks, blk, 0, stream>>>(featbf, off_g, e16g, invg, bfAgg);
  gemm_gl<128, 128, true, true><<<gridH, blk, 0, stream>>>(
      featbf, bfAgg, wts + wL0, lb_0, bfA, HF, NN);
  // ---- local layer 1: h_l1 = relu([h_l0|agg_g(h_l0)] @ WL1) -> bfB ----
  csr_aggregate<8><<<agg256_blocks, blk, 0, stream>>>(bfA, off_g, e16g, invg, bfAgg);
  gemm_gl<256, 256, true, true><<<gridH, blk, 0, stream>>>(
      bfA, bfAgg, wts + wL1, lb_1, bfB, HF, NN);
  // ---- yl = h_l1 @ Wf1 -> bfYL; aggYL = agg_g(yl) D=128 ----
  gemm_gl<256, 0, false, true><<<gridM, blk, 0, stream>>>(
      bfB, nullptr, wf + wfYL, zbias, bfYL, MLPH, NN);
  csr_aggregate<7><<<agg128_blocks, blk, 0, stream>>>(bfYL, off_g, e16g, invg, bfAYL);
  // ---- global layer 0: h_g0 = relu([feat|agg_k(feat)] @ WG0) -> bfA ----
  csr_aggregate<7><<<agg128_blocks, blk, 0, stream>>>(featbf, off_k, e16k, invk, bfAgg);
  gemm_gl<128, 128, true, true><<<gridH, blk, 0, stream>>>(
      featbf, bfAgg, wts + wG0, gb_0, bfA, HF, NN);
  // ---- yg = h_g0 @ Wf3 -> bfYG; aggYG = agg_k(yg) D=128 ----
  gemm_gl<256, 0, false, true><<<gridM, blk, 0, stream>>>(
      bfA, nullptr, wf + wfYG, zbias, bfYG, MLPH, NN);
  csr_aggregate<7><<<agg128_blocks, blk, 0, stream>>>(bfYG, off_k, e16k, invk, bfAYG);

  // ---- tail: x = h_l1@wf[0:256] + h_g0@wf[256:512] + aggYL + aggYG + bfused ----
  gemm_tail512<<<gridM, blk, 0, stream>>>(bfB, bfA, wf, bfused, bfAYL, bfAYG, xf32, NN);

  // ---- BatchNorm ----
  bn_stats_kernel<<<256, blk, 0, stream>>>(xf32, stats, stats + 128);
  bn_finalize_kernel<<<1, 128, 0, stream>>>(stats, bn_gamma, bn_beta);

  // ---- head GEMM2 ----
  gemm_mfma_bn<128, false><<<dim3(1, (NN + 63) / 64), blk, 0, stream>>>(
      xf32, wts + wH2, mlp_b2, stats + 256, stats + 384, out, COUT, NN);
}

// Round 15
// 461.249 us; speedup vs baseline: 1.4745x; 1.0554x over previous
//
#include <hip/hip_runtime.h>

#define NN   50000
#define IN_F 128
#define HF   256
#define COUT 64
#define MLPH 128
#define EG   600000
#define EK   800000
#define RNG  6250    // NN / 8
#define SUBR 782     // ceil(RNG / 8)
#define CAPG 80000
#define CAPK 106000
#define BN_EPS 1e-5f

typedef __attribute__((ext_vector_type(8))) short short8;
typedef __attribute__((ext_vector_type(8))) unsigned short ushort8;
typedef __attribute__((ext_vector_type(4))) float f32x4;

__device__ __forceinline__ unsigned short f2bf(float f) {
  union { float f; unsigned int u; } v; v.f = f;
  unsigned int r = v.u + 0x7FFFu + ((v.u >> 16) & 1u);
  return (unsigned short)(r >> 16);
}
__device__ __forceinline__ float bf2f(unsigned short s) {
  union { unsigned int u; float f; } v; v.u = ((unsigned int)s) << 16;
  return v.f;
}

__device__ __forceinline__ void gload_lds16(const void* g, void* l) {
  __builtin_amdgcn_global_load_lds((const __attribute__((address_space(1))) void*)g,
                                   (__attribute__((address_space(3))) void*)l, 16, 0, 0);
}

struct WDesc { const float* src; int rows; int cshift; int kofs; int ldk; int dofs; };
struct WPack { WDesc d[12]; };

// ---------------- prep: feat->bf16, weight transpose ----------------
__global__ __launch_bounds__(256) void prep_kernel(const float* __restrict__ feat,
                                                   unsigned short* __restrict__ featbf,
                                                   WPack p, unsigned short* __restrict__ wts) {
  int b = blockIdx.x;
  if (b < 3126) {
    int i = b * 256 + threadIdx.x;
    if (i < NN * IN_F / 8) {
      float4 a = *reinterpret_cast<const float4*>(&feat[i * 8]);
      float4 c = *reinterpret_cast<const float4*>(&feat[i * 8 + 4]);
      ushort8 o;
      o[0] = f2bf(a.x); o[1] = f2bf(a.y); o[2] = f2bf(a.z); o[3] = f2bf(a.w);
      o[4] = f2bf(c.x); o[5] = f2bf(c.y); o[6] = f2bf(c.z); o[7] = f2bf(c.w);
      *reinterpret_cast<ushort8*>(&featbf[i * 8]) = o;
    }
  } else {
    int wb = b - 3126;
    WDesc w = p.d[wb >> 5];
    int xb = wb & 31;
    int total = w.rows << w.cshift;
    int cmask = (1 << w.cshift) - 1;
    for (int idx = xb * 256 + threadIdx.x; idx < total; idx += 32 * 256) {
      int r = idx >> w.cshift, c = idx & cmask;
      wts[w.dofs + (size_t)c * w.ldk + w.kofs + r] = f2bf(w.src[idx]);
    }
  }
}

// ---------------- fused head weights ----------------
// wf: [0..65535] wf0 tail Bt[c][512]=[seg0|seg2]; [65536..98303] wf1 (yl);
//     [98304..131071] wf3 (yg)
__global__ __launch_bounds__(128) void fuse_w_kernel(
    const float* __restrict__ wl2s, const float* __restrict__ wl2n,
    const float* __restrict__ wg1s, const float* __restrict__ wg1n,
    const float* __restrict__ w1, const float* __restrict__ bl2,
    const float* __restrict__ bg1, const float* __restrict__ b1,
    unsigned short* __restrict__ wf, float* __restrict__ bfused) {
  int b = blockIdx.x;
  int c = threadIdx.x;
  __shared__ float row[256];
  if (b < 1024) {
    int seg = b >> 8, i = b & 255;
    const float* W = (seg == 0) ? wl2s : (seg == 1) ? wl2n : (seg == 2) ? wg1s : wg1n;
    const float* w1b = w1 + ((seg < 2) ? 0 : 256) * MLPH;
    row[c] = W[i * 256 + c];
    row[c + 128] = W[i * 256 + 128 + c];
    __syncthreads();
    float acc = 0.f;
    for (int o = 0; o < 256; ++o) acc += row[o] * w1b[o * MLPH + c];
    unsigned short v = f2bf(acc);
    if (seg == 0)      wf[(size_t)c * 512 + i] = v;
    else if (seg == 2) wf[(size_t)c * 512 + 256 + i] = v;
    else if (seg == 1) wf[65536 + (size_t)c * 256 + i] = v;
    else               wf[98304 + (size_t)c * 256 + i] = v;
  } else {
    float acc = b1[c];
    for (int o = 0; o < 256; ++o) acc += bl2[o] * w1[o * MLPH + c];
    for (int o = 0; o < 256; ++o) acc += bg1[o] * w1[(256 + o) * MLPH + c];
    bfused[c] = acc;
  }
}

// ---------------- edge bucketing ----------------
__global__ __launch_bounds__(256) void bucket_kernel(const int* __restrict__ g_src,
                                                     const int* __restrict__ g_dst,
                                                     const int* __restrict__ k_src,
                                                     const int* __restrict__ k_dst,
                                                     int* __restrict__ gcnt,
                                                     unsigned* __restrict__ bkt_g,
                                                     unsigned* __restrict__ bkt_k) {
  __shared__ unsigned buf[2048];
  __shared__ int rcnt[8], rbase[8], roff[8];
  const int gr = blockIdx.y;
  const int* src = gr ? k_src : g_src;
  const int* dst = gr ? k_dst : g_dst;
  unsigned* bkt = gr ? bkt_k : bkt_g;
  const int CAP = gr ? CAPK : CAPG;
  const int E = gr ? EK : EG;
  int* gc = gcnt + gr * 8;
  const int tid = threadIdx.x;
  const int e0 = blockIdx.x * 2048;
  if (e0 >= E) return;
  if (tid < 8) rcnt[tid] = 0;
  __syncthreads();
  unsigned vloc[8];
  int rloc[8], ploc[8];
#pragma unroll
  for (int i = 0; i < 8; ++i) {
    int e = e0 + i * 256 + tid;
    rloc[i] = -1;
    if (e < E) {
      int d = dst[e], s = src[e];
      int r = d / RNG;
      vloc[i] = ((unsigned)d << 16) | (unsigned)s;
      rloc[i] = r;
      ploc[i] = atomicAdd(&rcnt[r], 1);
    }
  }
  __syncthreads();
  if (tid == 0) {
    int acc = 0;
#pragma unroll
    for (int r = 0; r < 8; ++r) { roff[r] = acc; acc += rcnt[r]; }
  }
  __syncthreads();
#pragma unroll
  for (int i = 0; i < 8; ++i)
    if (rloc[i] >= 0) buf[roff[rloc[i]] + ploc[i]] = vloc[i];
  __syncthreads();
  if (tid < 8) rbase[tid] = atomicAdd(&gc[tid], rcnt[tid]);
  __syncthreads();
#pragma unroll
  for (int r = 0; r < 8; ++r) {
    int len = rcnt[r];
    unsigned* dstp = bkt + (size_t)r * CAP + rbase[r];
    for (int i = tid; i < len; i += 256) dstp[i] = buf[roff[r] + i];
  }
}

// ---------------- per-range count (LDS histogram) ----------------
__global__ __launch_bounds__(256) void count_bucket(const unsigned* __restrict__ bkt_g,
                                                    const unsigned* __restrict__ bkt_k,
                                                    const int* __restrict__ gcnt,
                                                    int* __restrict__ cnt_g,
                                                    int* __restrict__ cnt_k, int CC) {
  __shared__ int hist[RNG];
  const int r = blockIdx.x, gr = blockIdx.y, z = blockIdx.z;
  const unsigned* b = (gr ? bkt_k : bkt_g) + (size_t)r * (gr ? CAPK : CAPG);
  int* cnt = gr ? cnt_k : cnt_g;
  const int n = gcnt[gr * 8 + r];
  const unsigned lo = r * RNG;
  for (int i = threadIdx.x; i < RNG; i += 256) hist[i] = 0;
  __syncthreads();
  for (int i = z * 256 + threadIdx.x; i < n; i += CC * 256) {
    unsigned d = (b[i] >> 16) - lo;
    atomicAdd(&hist[d], 1);
  }
  __syncthreads();
  for (int i = threadIdx.x; i < RNG; i += 256) {
    int v = hist[i];
    if (v) atomicAdd(&cnt[lo + i], v);
  }
}

// ---------------- parallel scans ----------------
__global__ __launch_bounds__(256) void scan_partial2(const int* __restrict__ cnt_g,
                                                     const int* __restrict__ cnt_k,
                                                     int* __restrict__ part, int n) {
  const int* cnt = blockIdx.y ? cnt_k : cnt_g;
  int* pp = part + blockIdx.y * 256;
  int i = blockIdx.x * 256 + threadIdx.x;
  int v = (i < n) ? cnt[i] : 0;
  __shared__ int ws[4];
  int lane = threadIdx.x & 63, wid = threadIdx.x >> 6;
  int x = v;
#pragma unroll
  for (int d = 1; d < 64; d <<= 1) { int y = __shfl_up(x, d, 64); if (lane >= d) x += y; }
  if (lane == 63) ws[wid] = x;
  __syncthreads();
  if (threadIdx.x == 0) pp[blockIdx.x] = ws[0] + ws[1] + ws[2] + ws[3];
}

__global__ __launch_bounds__(256) void scan_block2(int* __restrict__ part, int np) {
  int* pp = part + blockIdx.x * 256;
  __shared__ int ws[4];
  int tid = threadIdx.x, lane = tid & 63, wid = tid >> 6;
  int v = (tid < np) ? pp[tid] : 0;
  int x = v;
#pragma unroll
  for (int d = 1; d < 64; d <<= 1) { int y = __shfl_up(x, d, 64); if (lane >= d) x += y; }
  if (lane == 63) ws[wid] = x;
  __syncthreads();
  int add = 0;
#pragma unroll
  for (int k = 0; k < 4; ++k) if (k < wid) add += ws[k];
  if (tid < np) pp[tid] = x - v + add;
}

__global__ __launch_bounds__(256) void scan_final2(const int* __restrict__ cnt_g,
                                                   const int* __restrict__ cnt_k,
                                                   const int* __restrict__ part,
                                                   int* __restrict__ off_g,
                                                   int* __restrict__ off_k,
                                                   float* __restrict__ invg,
                                                   float* __restrict__ invk, int n) {
  const int* cnt = blockIdx.y ? cnt_k : cnt_g;
  const int* pp = part + blockIdx.y * 256;
  int* off = blockIdx.y ? off_k : off_g;
  float* inv = blockIdx.y ? invk : invg;
  int total = blockIdx.y ? EK : EG;
  int i = blockIdx.x * 256 + threadIdx.x;
  int v = (i < n) ? cnt[i] : 0;
  __shared__ int ws[4];
  int lane = threadIdx.x & 63, wid = threadIdx.x >> 6;
  int x = v;
#pragma unroll
  for (int d = 1; d < 64; d <<= 1) { int y = __shfl_up(x, d, 64); if (lane >= d) x += y; }
  if (lane == 63) ws[wid] = x;
  __syncthreads();
  int add = pp[blockIdx.x];
#pragma unroll
  for (int k = 0; k < 4; ++k) if (k < wid) add += ws[k];
  if (i < n) {
    off[i] = x - v + add;
    inv[i] = 1.0f / fmaxf((float)v, 1.0f);
  }
  if (i == 0) off[n] = total;
}

// ---------------- CSR fill: 8 sub-ranges, LDS cursors ----------------
__global__ __launch_bounds__(1024) void fill_sub(const unsigned* __restrict__ bkt_g,
                                                 const unsigned* __restrict__ bkt_k,
                                                 const int* __restrict__ gcnt,
                                                 const int* __restrict__ off_g,
                                                 const int* __restrict__ off_k,
                                                 unsigned short* __restrict__ e16g,
                                                 unsigned short* __restrict__ e16k) {
  __shared__ int curs[SUBR];
  const int b = blockIdx.x;               // 128 blocks
  const int s = b & 7, r = (b >> 3) & 7, gr = b >> 6;
  const unsigned* bkt = (gr ? bkt_k : bkt_g) + (size_t)r * (gr ? CAPK : CAPG);
  const int* off = gr ? off_k : off_g;
  unsigned short* e16 = gr ? e16k : e16g;
  const int n = gcnt[gr * 8 + r];
  const int lo = r * RNG;
  const int slo = s * SUBR;
  int send = slo + SUBR;
  if (send > RNG) send = RNG;
  const int swid = send - slo;
  if (swid <= 0) return;
  for (int i = threadIdx.x; i < swid; i += 1024) curs[i] = off[lo + slo + i];
  __syncthreads();
  for (int i = threadIdx.x; i < n; i += 1024) {
    unsigned v = bkt[i];
    int d = (int)(v >> 16) - lo - slo;
    if ((unsigned)d < (unsigned)swid) {
      int pz = atomicAdd(&curs[d], 1);
      e16[pz] = (unsigned short)(v & 0xffffu);
    }
  }
}

// ---------------- CSR mean-aggregation (bf16, ushort esrc), unroll-8 ----------
template <int DLOG2>
__device__ __forceinline__ void agg_node(const unsigned short* __restrict__ h,
                                         const int* __restrict__ off,
                                         const unsigned short* __restrict__ esrc,
                                         const float* __restrict__ inv,
                                         unsigned short* __restrict__ out,
                                         int node, int lane) {
  int s = off[node], e = off[node + 1];
  float acc[8] = {0.f, 0.f, 0.f, 0.f, 0.f, 0.f, 0.f, 0.f};
  int j = s;
  for (; j + 7 < e; j += 8) {
    ushort8 v[8];
#pragma unroll
    for (int q = 0; q < 8; ++q) {
      int sq = esrc[j + q];
      v[q] = *reinterpret_cast<const ushort8*>(&h[((size_t)sq << DLOG2) + lane * 8]);
    }
#pragma unroll
    for (int q = 0; q < 8; ++q)
#pragma unroll
      for (int i = 0; i < 8; ++i) acc[i] += bf2f(v[q][i]);
  }
  for (; j + 3 < e; j += 4) {
    ushort8 v[4];
#pragma unroll
    for (int q = 0; q < 4; ++q) {
      int sq = esrc[j + q];
      v[q] = *reinterpret_cast<const ushort8*>(&h[((size_t)sq << DLOG2) + lane * 8]);
    }
#pragma unroll
    for (int q = 0; q < 4; ++q)
#pragma unroll
      for (int i = 0; i < 8; ++i) acc[i] += bf2f(v[q][i]);
  }
  for (; j < e; ++j) {
    int s0 = esrc[j];
    ushort8 v0 = *reinterpret_cast<const ushort8*>(&h[((size_t)s0 << DLOG2) + lane * 8]);
#pragma unroll
    for (int i = 0; i < 8; ++i) acc[i] += bf2f(v0[i]);
  }
  float sc = inv[node];
  ushort8 o;
#pragma unroll
  for (int i = 0; i < 8; ++i) o[i] = f2bf(acc[i] * sc);
  *reinterpret_cast<ushort8*>(&out[((size_t)node << DLOG2) + lane * 8]) = o;
}

template <int DLOG2>
__global__ __launch_bounds__(256) void csr_aggregate(const unsigned short* __restrict__ h,
                                                     const int* __restrict__ off,
                                                     const unsigned short* __restrict__ esrc,
                                                     const float* __restrict__ inv,
                                                     unsigned short* __restrict__ out) {
  constexpr int TPN = (1 << DLOG2) / 8;
  constexpr int NPB = 256 / TPN;
  int node = blockIdx.x * NPB + ((int)threadIdx.x / TPN);
  int lane = threadIdx.x & (TPN - 1);
  if (node >= NN) return;
  agg_node<DLOG2>(h, off, esrc, inv, out, node, lane);
}

// dual-graph D=128 aggregate
__global__ __launch_bounds__(256) void csr_aggregate2(
    const unsigned short* __restrict__ h0, const int* __restrict__ off0,
    const unsigned short* __restrict__ e0, const float* __restrict__ inv0,
    unsigned short* __restrict__ out0,
    const unsigned short* __restrict__ h1, const int* __restrict__ off1,
    const unsigned short* __restrict__ e1, const float* __restrict__ inv1,
    unsigned short* __restrict__ out1) {
  constexpr int TPN = 16, NPB = 16;
  int node = blockIdx.x * NPB + ((int)threadIdx.x / TPN);
  int lane = threadIdx.x & (TPN - 1);
  if (node >= NN) return;
  if (blockIdx.y == 0)
    agg_node<7>(h0, off0, e0, inv0, out0, node, lane);
  else
    agg_node<7>(h1, off1, e1, inv1, out1, node, lane);
}

// ---------------- MFMA GEMM, BM=128 x BN=128, BK=64, global_load_lds staging --------
template <int K1, int K2, bool RELU, bool OUT_BF16>
__global__ __launch_bounds__(256) void gemm_gl(
    const unsigned short* __restrict__ A1, const unsigned short* __restrict__ A2,
    const unsigned short* __restrict__ Bt, const float* __restrict__ bias,
    void* __restrict__ outv, int ldo, int nrows) {
  constexpr int KTOT = K1 + K2;
  constexpr int KT = KTOT / 64;
  __shared__ char smem[32768];
  unsigned short* sA = (unsigned short*)smem;
  unsigned short* sB = sA + 8192;

  const int t = threadIdx.x;
  const int lane = t & 63;
  const int w = t >> 6;
  const int wm = (w & 1) * 64, wn = (w >> 1) * 64;
  const int row0 = blockIdx.y * 128;
  const int n0 = blockIdx.x * 128;

  const int srow = (w << 5) + (lane >> 3);
  const int schunk = (lane & 7) << 3;

  f32x4 acc[4][4] = {};

  for (int kt = 0; kt < KT; ++kt) {
    const int kbase = kt * 64;
    const unsigned short* Asrc = (kbase < K1) ? A1 : A2;
    const int kA = (kbase < K1) ? kbase : (kbase - K1);
    const int lda = (kbase < K1) ? K1 : K2;
#pragma unroll
    for (int q = 0; q < 4; ++q) {
      int rA = srow + q * 8;
      int rowg = row0 + rA;
      if (rowg >= nrows) rowg = nrows - 1;
      gload_lds16(Asrc + (size_t)rowg * lda + kA + schunk,
                  sA + ((w << 5) + q * 8) * 64);
      gload_lds16(Bt + (size_t)(n0 + rA) * KTOT + kbase + schunk,
                  sB + ((w << 5) + q * 8) * 64);
    }
    __syncthreads();
#pragma unroll
    for (int kk = 0; kk < 2; ++kk) {
      const int ko = kk * 32 + (lane >> 4) * 8;
      short8 a[4], b[4];
#pragma unroll
      for (int mi = 0; mi < 4; ++mi)
        a[mi] = *reinterpret_cast<const short8*>(&sA[(wm + mi * 16 + (lane & 15)) * 64 + ko]);
#pragma unroll
      for (int ni = 0; ni < 4; ++ni)
        b[ni] = *reinterpret_cast<const short8*>(&sB[(wn + ni * 16 + (lane & 15)) * 64 + ko]);
#pragma unroll
      for (int mi = 0; mi < 4; ++mi)
#pragma unroll
        for (int ni = 0; ni < 4; ++ni)
          acc[mi][ni] = __builtin_amdgcn_mfma_f32_16x16x32_bf16(a[mi], b[ni], acc[mi][ni], 0, 0, 0);
    }
    __syncthreads();
  }

  float* Co = (float*)smem;
#pragma unroll
  for (int h = 0; h < 2; ++h) {
    __syncthreads();
    if ((w >> 1) == h) {
#pragma unroll
      for (int mi = 0; mi < 4; ++mi)
#pragma unroll
        for (int ni = 0; ni < 4; ++ni) {
          int col = ni * 16 + (lane & 15);
          int rowb = wm + mi * 16 + (lane >> 4) * 4;
#pragma unroll
          for (int j = 0; j < 4; ++j) Co[(rowb + j) * 64 + col] = acc[mi][ni][j];
        }
    }
    __syncthreads();
    int sr = t >> 1, cb = (t & 1) * 32;
    int r = row0 + sr;
    if (r < nrows) {
      float v[32];
#pragma unroll
      for (int i = 0; i < 32; ++i) {
        v[i] = Co[sr * 64 + cb + i] + bias[n0 + h * 64 + cb + i];
        if (RELU) v[i] = fmaxf(v[i], 0.f);
      }
      if (OUT_BF16) {
        unsigned short* dst = (unsigned short*)outv + (size_t)r * ldo + n0 + h * 64 + cb;
#pragma unroll
        for (int q = 0; q < 4; ++q) {
          ushort8 o;
#pragma unroll
          for (int i = 0; i < 8; ++i) o[i] = f2bf(v[q * 8 + i]);
          *reinterpret_cast<ushort8*>(dst + q * 8) = o;
        }
      } else {
        float* dst = (float*)outv + (size_t)r * ldo + n0 + h * 64 + cb;
#pragma unroll
        for (int q = 0; q < 8; ++q) {
          float4 o = make_float4(v[4 * q], v[4 * q + 1], v[4 * q + 2], v[4 * q + 3]);
          *reinterpret_cast<float4*>(dst + 4 * q) = o;
        }
      }
    }
  }
}

// ---------------- tail GEMM K=512 + agg adds + fused BN partial stats ----------------
__global__ __launch_bounds__(256) void gemm_tail512(
    const unsigned short* __restrict__ A0, const unsigned short* __restrict__ A1,
    const unsigned short* __restrict__ Bt, const float* __restrict__ bias,
    const unsigned short* __restrict__ aYL, const unsigned short* __restrict__ aYG,
    float* __restrict__ outv, float* __restrict__ bnsums, int nrows) {
  constexpr int KTOT = 512;
  constexpr int KT = 8;
  __shared__ char smem[32768];
  __shared__ float psum[4][64], psum2[4][64];
  unsigned short* sA = (unsigned short*)smem;
  unsigned short* sB = sA + 8192;

  const int t = threadIdx.x;
  const int lane = t & 63;
  const int w = t >> 6;
  const int wm = (w & 1) * 64, wn = (w >> 1) * 64;
  const int row0 = blockIdx.y * 128;

  const int srow = (w << 5) + (lane >> 3);
  const int schunk = (lane & 7) << 3;

  f32x4 acc[4][4] = {};

  for (int kt = 0; kt < KT; ++kt) {
    const unsigned short* Asrc = (kt < 4) ? A0 : A1;
    const int kA = (kt & 3) * 64;
#pragma unroll
    for (int q = 0; q < 4; ++q) {
      int rA = srow + q * 8;
      int rowg = row0 + rA;
      if (rowg >= nrows) rowg = nrows - 1;
      gload_lds16(Asrc + (size_t)rowg * 256 + kA + schunk,
                  sA + ((w << 5) + q * 8) * 64);
      gload_lds16(Bt + (size_t)rA * KTOT + kt * 64 + schunk,
                  sB + ((w << 5) + q * 8) * 64);
    }
    __syncthreads();
#pragma unroll
    for (int kk = 0; kk < 2; ++kk) {
      const int ko = kk * 32 + (lane >> 4) * 8;
      short8 a[4], b[4];
#pragma unroll
      for (int mi = 0; mi < 4; ++mi)
        a[mi] = *reinterpret_cast<const short8*>(&sA[(wm + mi * 16 + (lane & 15)) * 64 + ko]);
#pragma unroll
      for (int ni = 0; ni < 4; ++ni)
        b[ni] = *reinterpret_cast<const short8*>(&sB[(wn + ni * 16 + (lane & 15)) * 64 + ko]);
#pragma unroll
      for (int mi = 0; mi < 4; ++mi)
#pragma unroll
        for (int ni = 0; ni < 4; ++ni)
          acc[mi][ni] = __builtin_amdgcn_mfma_f32_16x16x32_bf16(a[mi], b[ni], acc[mi][ni], 0, 0, 0);
    }
    __syncthreads();
  }

  float* Co = (float*)smem;
#pragma unroll
  for (int h = 0; h < 2; ++h) {
    __syncthreads();
    if ((w >> 1) == h) {
#pragma unroll
      for (int mi = 0; mi < 4; ++mi)
#pragma unroll
        for (int ni = 0; ni < 4; ++ni) {
          int col = ni * 16 + (lane & 15);
          int rowb = wm + mi * 16 + (lane >> 4) * 4;
#pragma unroll
          for (int j = 0; j < 4; ++j) Co[(rowb + j) * 64 + col] = acc[mi][ni][j];
        }
    }
    __syncthreads();
    int sr = t >> 1, cb = (t & 1) * 32;
    int r = row0 + sr;
    if (r < nrows) {
      float* dst = outv + (size_t)r * MLPH + h * 64 + cb;
#pragma unroll
      for (int q = 0; q < 4; ++q) {
        ushort8 ya = *reinterpret_cast<const ushort8*>(&aYL[(size_t)r * MLPH + h * 64 + cb + q * 8]);
        ushort8 yb = *reinterpret_cast<const ushort8*>(&aYG[(size_t)r * MLPH + h * 64 + cb + q * 8]);
        float v[8];
#pragma unroll
        for (int i = 0; i < 8; ++i) {
          v[i] = Co[sr * 64 + cb + q * 8 + i] + bf2f(ya[i]) + bf2f(yb[i]) +
                 bias[h * 64 + cb + q * 8 + i];
          Co[sr * 64 + cb + q * 8 + i] = v[i];
        }
        *reinterpret_cast<float4*>(dst + q * 8) = make_float4(v[0], v[1], v[2], v[3]);
        *reinterpret_cast<float4*>(dst + q * 8 + 4) = make_float4(v[4], v[5], v[6], v[7]);
      }
    }
    __syncthreads();
    {
      int c = t & 63, rq = t >> 6;
      float s = 0.f, s2 = 0.f;
      int rbeg = rq * 32;
      for (int rr = rbeg; rr < rbeg + 32; ++rr) {
        if (row0 + rr < nrows) {
          float v = Co[rr * 64 + c];
          s += v;
          s2 += v * v;
        }
      }
      psum[rq][c] = s;
      psum2[rq][c] = s2;
    }
    __syncthreads();
    if (t < 64) {
      float s = psum[0][t] + psum[1][t] + psum[2][t] + psum[3][t];
      float s2 = psum2[0][t] + psum2[1][t] + psum2[2][t] + psum2[3][t];
      atomicAdd(&bnsums[h * 64 + t], s);
      atomicAdd(&bnsums[128 + h * 64 + t], s2);
    }
    __syncthreads();
  }
}

// ---------------- BN finalize ----------------
__global__ __launch_bounds__(128) void bn_finalize_kernel(float* __restrict__ stats,
                                                          const float* __restrict__ gamma,
                                                          const float* __restrict__ beta) {
  int c = threadIdx.x;
  float mu = stats[c] * (1.0f / NN);
  float var = stats[128 + c] * (1.0f / NN) - mu * mu;
  var = fmaxf(var, 0.f);
  float sc = gamma[c] * rsqrtf(var + BN_EPS);
  stats[256 + c] = sc;
  stats[384 + c] = beta[c] - mu * sc;
}

// ---------------- final head GEMM with fused BN+ReLU on A-load (64x64) ----------------
template <int K1, bool RELU>
__global__ __launch_bounds__(256) void gemm_mfma_bn(
    const float* __restrict__ A1v, const unsigned short* __restrict__ Bt,
    const float* __restrict__ bias, const float* __restrict__ bnscale,
    const float* __restrict__ bnshift, float* __restrict__ outv, int ldo, int nrows) {
  constexpr int KT = K1 / 64;
  constexpr int LDT = 72;
  __shared__ char smem[2 * 64 * LDT * 2];
  unsigned short* As = (unsigned short*)smem;
  unsigned short* Bs = As + 64 * LDT;
  float* Co = (float*)smem;
  constexpr int LDC = 68;

  const int t = threadIdx.x;
  const int lane = t & 63;
  const int w = t >> 6;
  const int wm = (w & 1) * 32, wn = (w >> 1) * 32;
  const int row0 = blockIdx.y * 64;
  const int n0 = blockIdx.x * 64;

  const int sr = t >> 2;
  const int skc = (t & 3) * 16;
  int rg = row0 + sr;
  if (rg >= nrows) rg = nrows - 1;

  f32x4 acc[2][2] = {};

  for (int kt = 0; kt < KT; ++kt) {
    const int kbase = kt * 64;
    {
      const float* xb = A1v + (size_t)rg * K1 + kbase + skc;
      ushort8 o0, o1;
#pragma unroll
      for (int i = 0; i < 8; ++i) {
        float v = xb[i] * bnscale[kbase + skc + i] + bnshift[kbase + skc + i];
        o0[i] = f2bf(fmaxf(v, 0.f));
      }
#pragma unroll
      for (int i = 0; i < 8; ++i) {
        float v = xb[8 + i] * bnscale[kbase + skc + 8 + i] + bnshift[kbase + skc + 8 + i];
        o1[i] = f2bf(fmaxf(v, 0.f));
      }
      *reinterpret_cast<ushort8*>(&As[sr * LDT + skc]) = o0;
      *reinterpret_cast<ushort8*>(&As[sr * LDT + skc + 8]) = o1;
    }
    {
      const unsigned short* bb = Bt + (size_t)(n0 + sr) * K1 + kbase + skc;
      int4 p0 = *reinterpret_cast<const int4*>(bb);
      int4 p1 = *reinterpret_cast<const int4*>(bb + 8);
      *reinterpret_cast<int4*>(&Bs[sr * LDT + skc]) = p0;
      *reinterpret_cast<int4*>(&Bs[sr * LDT + skc + 8]) = p1;
    }
    __syncthreads();
#pragma unroll
    for (int kk = 0; kk < 2; ++kk) {
      const int ko = kk * 32 + (lane >> 4) * 8;
      short8 a0 = *reinterpret_cast<const short8*>(&As[(wm + (lane & 15)) * LDT + ko]);
      short8 a1 = *reinterpret_cast<const short8*>(&As[(wm + 16 + (lane & 15)) * LDT + ko]);
      short8 b0 = *reinterpret_cast<const short8*>(&Bs[(wn + (lane & 15)) * LDT + ko]);
      short8 b1 = *reinterpret_cast<const short8*>(&Bs[(wn + 16 + (lane & 15)) * LDT + ko]);
      acc[0][0] = __builtin_amdgcn_mfma_f32_16x16x32_bf16(a0, b0, acc[0][0], 0, 0, 0);
      acc[0][1] = __builtin_amdgcn_mfma_f32_16x16x32_bf16(a0, b1, acc[0][1], 0, 0, 0);
      acc[1][0] = __builtin_amdgcn_mfma_f32_16x16x32_bf16(a1, b0, acc[1][0], 0, 0, 0);
      acc[1][1] = __builtin_amdgcn_mfma_f32_16x16x32_bf16(a1, b1, acc[1][1], 0, 0, 0);
    }
    __syncthreads();
  }

#pragma unroll
  for (int mi = 0; mi < 2; ++mi)
#pragma unroll
    for (int ni = 0; ni < 2; ++ni) {
      int col = wn + ni * 16 + (lane & 15);
      int rowb = wm + mi * 16 + (lane >> 4) * 4;
#pragma unroll
      for (int j = 0; j < 4; ++j) Co[(rowb + j) * LDC + col] = acc[mi][ni][j];
    }
  __syncthreads();
  {
    int r = row0 + sr;
    if (r < nrows) {
      float v[16];
#pragma unroll
      for (int i = 0; i < 16; ++i) {
        v[i] = Co[sr * LDC + skc + i] + bias[n0 + skc + i];
        if (RELU) v[i] = fmaxf(v[i], 0.f);
      }
      float* dst = outv + (size_t)r * ldo + n0 + skc;
#pragma unroll
      for (int i = 0; i < 4; ++i) {
        float4 o = make_float4(v[4 * i], v[4 * i + 1], v[4 * i + 2], v[4 * i + 3]);
        *reinterpret_cast<float4*>(dst + 4 * i) = o;
      }
    }
  }
}

// ---------------- launch ----------------
extern "C" void kernel_launch(void* const* d_in, const int* in_sizes, int n_in,
                              void* d_out, int out_size, void* d_ws, size_t ws_size,
                              hipStream_t stream) {
  const float* feat = (const float*)d_in[0];
  const int* g_src = (const int*)d_in[1];
  const int* g_dst = (const int*)d_in[2];
  const int* k_src = (const int*)d_in[3];
  const int* k_dst = (const int*)d_in[4];
  const float* lb_0 = (const float*)d_in[7];
  const float* lb_1 = (const float*)d_in[10];
  const float* lb_2 = (const float*)d_in[13];
  const float* gb_0 = (const float*)d_in[16];
  const float* gb_1 = (const float*)d_in[19];
  const float* mlp_b1 = (const float*)d_in[21];
  const float* bn_gamma = (const float*)d_in[22];
  const float* bn_beta = (const float*)d_in[23];
  const float* mlp_b2 = (const float*)d_in[25];
  float* out = (float*)d_out;

  // workspace layout
  float* xf32 = (float*)d_ws;                         // N*128 f32
  int* cnt_g = (int*)(xf32 + (size_t)NN * 128);       // N
  int* cnt_k = cnt_g + NN;                            // N
  float* stats = (float*)(cnt_k + NN);                // 512
  int* gcnt = (int*)(stats + 512);                    // 16
  float* zbias = (float*)(gcnt + 16);                 // 128 (zeroed with block above)
  float* invg = zbias + 128;                          // N
  float* invk = invg + NN;                            // N
  int* off_g = (int*)(invk + NN);                     // N+4
  int* off_k = off_g + NN + 4;                        // N+4
  int* part = off_k + NN + 4;                         // 512
  unsigned* bkt_g = (unsigned*)(part + 512);          // 8*CAPG
  unsigned* bkt_k = bkt_g + 8 * CAPG;                 // 8*CAPK
  unsigned short* e16g = (unsigned short*)(bkt_k + 8 * CAPK);  // EG
  unsigned short* e16k = e16g + EG;                   // EK
  unsigned short* featbf = e16k + EK;                 // N*128
  unsigned short* wts = featbf + (size_t)NN * IN_F;   // 598016
  unsigned short* wf = wts + 598016;                  // 131072
  float* bfused = (float*)(wf + 131072);              // 128
  unsigned short* hL0 = (unsigned short*)(bfused + 128);  // N*256
  unsigned short* hG0 = hL0 + (size_t)NN * HF;        // N*256
  unsigned short* hL1 = hG0 + (size_t)NN * HF;        // N*256
  unsigned short* aggT = hL1 + (size_t)NN * HF;       // N*256
  unsigned short* aggFG = aggT + (size_t)NN * HF;     // N*128
  unsigned short* aggFK = aggFG + (size_t)NN * MLPH;  // N*128
  unsigned short* bfYL = aggFK + (size_t)NN * MLPH;   // N*128
  unsigned short* bfYG = bfYL + (size_t)NN * MLPH;    // N*128
  unsigned short* bfAYL = bfYG + (size_t)NN * MLPH;   // N*128
  unsigned short* bfAYG = bfAYL + (size_t)NN * MLPH;  // N*128

  const int wL0 = 0, wL1 = 65536, wG0 = 327680, wH2 = 589824;
  const int wfYL = 65536, wfYG = 98304;

  dim3 blk(256);
  const int NB = (NN + 255) / 256;        // 196
  const int MB = (NN + 127) / 128;        // 391
  const dim3 gridH(2, MB);                // 256-col out
  const dim3 gridM(1, MB);                // 128-col out
  const int agg128_blocks = (NN + 15) / 16;
  const int agg256_blocks = (NN + 7) / 8;
  const int BKB = (EK + 2047) / 2048;
  const int CC = 8;

  // zero cnt_g, cnt_k, stats, gcnt, zbias
  hipMemsetAsync(cnt_g, 0,
                 (size_t)(2 * NN) * sizeof(int) + 512 * sizeof(float) + 16 * sizeof(int) +
                     128 * sizeof(float),
                 stream);

  WPack p;
  p.d[0] = {(const float*)d_in[5], 128, 8, 0, 256, wL0};
  p.d[1] = {(const float*)d_in[6], 128, 8, 128, 256, wL0};
  p.d[2] = {(const float*)d_in[8], 256, 8, 0, 512, wL1};
  p.d[3] = {(const float*)d_in[9], 256, 8, 256, 512, wL1};
  p.d[4] = {(const float*)d_in[11], 256, 8, 0, 512, 196608};  // folded; layout keep
  p.d[5] = {(const float*)d_in[12], 256, 8, 256, 512, 196608};
  p.d[6] = {(const float*)d_in[14], 128, 8, 0, 256, wG0};
  p.d[7] = {(const float*)d_in[15], 128, 8, 128, 256, wG0};
  p.d[8] = {(const float*)d_in[17], 256, 8, 0, 512, 393216};  // folded
  p.d[9] = {(const float*)d_in[18], 256, 8, 256, 512, 393216};
  p.d[10] = {(const float*)d_in[20], 512, 7, 0, 512, 524288}; // folded
  p.d[11] = {(const float*)d_in[24], 128, 6, 0, 128, wH2};
  prep_kernel<<<3510, blk, 0, stream>>>(feat, featbf, p, wts);

  fuse_w_kernel<<<1025, 128, 0, stream>>>(
      (const float*)d_in[11], (const float*)d_in[12],
      (const float*)d_in[17], (const float*)d_in[18],
      (const float*)d_in[20], lb_2, gb_1, mlp_b1, wf, bfused);

  // ---- CSR build ----
  bucket_kernel<<<dim3(BKB, 2), blk, 0, stream>>>(g_src, g_dst, k_src, k_dst, gcnt, bkt_g, bkt_k);
  count_bucket<<<dim3(8, 2, CC), blk, 0, stream>>>(bkt_g, bkt_k, gcnt, cnt_g, cnt_k, CC);
  scan_partial2<<<dim3(NB, 2), blk, 0, stream>>>(cnt_g, cnt_k, part, NN);
  scan_block2<<<2, blk, 0, stream>>>(part, NB);
  scan_final2<<<dim3(NB, 2), blk, 0, stream>>>(cnt_g, cnt_k, part, off_g, off_k, invg, invk, NN);
  fill_sub<<<128, 1024, 0, stream>>>(bkt_g, bkt_k, gcnt, off_g, off_k, e16g, e16k);

  // ---- both feat aggregates (D=128, graphs g & k) in one dispatch ----
  csr_aggregate2<<<dim3(agg128_blocks, 2), blk, 0, stream>>>(
      featbf, off_g, e16g, invg, aggFG, featbf, off_k, e16k, invk, aggFK);
  // ---- l0 and g0 GEMMs ----
  gemm_gl<128, 128, true, true><<<gridH, blk, 0, stream>>>(
      featbf, aggFG, wts + wL0, lb_0, hL0, HF, NN);
  gemm_gl<128, 128, true, true><<<gridH, blk, 0, stream>>>(
      featbf, aggFK, wts + wG0, gb_0, hG0, HF, NN);
  // ---- l1 agg (D=256) + l1 GEMM ----
  csr_aggregate<8><<<agg256_blocks, blk, 0, stream>>>(hL0, off_g, e16g, invg, aggT);
  gemm_gl<256, 256, true, true><<<gridH, blk, 0, stream>>>(
      hL0, aggT, wts + wL1, lb_1, hL1, HF, NN);
  // ---- yl = hL1 @ Wf1, yg = hG0 @ Wf3 (proven gemm_gl path) ----
  gemm_gl<256, 0, false, true><<<gridM, blk, 0, stream>>>(
      hL1, nullptr, wf + wfYL, zbias, bfYL, MLPH, NN);
  gemm_gl<256, 0, false, true><<<gridM, blk, 0, stream>>>(
      hG0, nullptr, wf + wfYG, zbias, bfYG, MLPH, NN);
  // ---- agg yl over g, yg over k (one dispatch) ----
  csr_aggregate2<<<dim3(agg128_blocks, 2), blk, 0, stream>>>(
      bfYL, off_g, e16g, invg, bfAYL, bfYG, off_k, e16k, invk, bfAYG);

  // ---- tail GEMM + fused BN stats ----
  gemm_tail512<<<gridM, blk, 0, stream>>>(hL1, hG0, wf, bfused, bfAYL, bfAYG, xf32, stats, NN);

  // ---- BN finalize + head GEMM2 ----
  bn_finalize_kernel<<<1, 128, 0, stream>>>(stats, bn_gamma, bn_beta);
  gemm_mfma_bn<128, false><<<dim3(1, (NN + 63) / 64), blk, 0, stream>>>(
      xf32, wts + wH2, mlp_b2, stats + 256, stats + 384, out, COUT, NN);
}